// Round 2
// baseline (2513.990 us; speedup 1.0000x reference)
//
#include <hip/hip_runtime.h>
#include <math.h>

// ---- problem constants ----
#define BB 64
#define DD0 768
#define NN 196
#define LIN 1536
#define CIN 196
#define COUT 196
#define TT 32
#define DM 384
#define DDB 96
#define EPS 1e-5f

// ---- workspace layout (float offsets) ----
// region A (19,267,584 f): vtc -> later vq1 -> c_q -> y2 (non-overlapping lifetimes)
#define OFF_VTC   0LL
// region B (9,633,792 f): vtf -> later out_tmp
#define OFF_VTF   19267584LL
// region C: xT (9,633,792 f)
#define OFF_XT    28901376LL
// region D: rep (1,572,864 f)
#define OFF_REP   38535168LL
// region E: y1 (1,204,224 f)
#define OFF_Y1    40108032LL
// smalls
#define OFF_SM    41312256LL
#define OFF_AUDIO (OFF_SM)
#define OFF_AQ1   (OFF_SM+49152)
#define OFF_MVQ   (OFF_SM+98304)
#define OFF_AVQ   (OFF_SM+147456)
#define OFF_CHATT (OFF_SM+172032)
#define OFF_AQ2   (OFF_SM+221184)
#define OFF_SSIG  (OFF_SM+245760)
#define OFF_STATS (OFF_SM+258304)   // bn1 sum[96],sq[96], bn2 sum[768],sq[768] = 1728 f

// ---------------- reduction helpers (256-thread blocks) ----------------
__device__ __forceinline__ float warp_sum(float v) {
    for (int o = 32; o; o >>= 1) v += __shfl_down(v, o, 64);
    return v;
}
__device__ __forceinline__ float warp_max(float v) {
    for (int o = 32; o; o >>= 1) v = fmaxf(v, __shfl_down(v, o, 64));
    return v;
}
__device__ __forceinline__ float block_sum256(float v, float* sb) {
    v = warp_sum(v);
    __syncthreads();
    if ((threadIdx.x & 63) == 0) sb[threadIdx.x >> 6] = v;
    __syncthreads();
    return sb[0] + sb[1] + sb[2] + sb[3];
}
__device__ __forceinline__ float block_max256(float v, float* sb) {
    v = warp_max(v);
    __syncthreads();
    if ((threadIdx.x & 63) == 0) sb[threadIdx.x >> 6] = v;
    __syncthreads();
    return fmaxf(fmaxf(sb[0], sb[1]), fmaxf(sb[2], sb[3]));
}

// ---------------- generic NT GEMM: C[m][n] = epi(sum_k A[m][k]*B[n][k] + bias) -----
// EPI: 0 none, 1 relu, 2 sigmoid. KSC: scale A's k-element by (ksc[k]+1). BIASM: bias on m.
template<int EPI, bool KSC, bool BIASM>
__global__ __launch_bounds__(256)
void gemm_nt(const float* __restrict__ A, long long sAb, int lda,
             const float* __restrict__ Bm, long long sBb, int ldb,
             const float* __restrict__ bias,
             const float* __restrict__ ksc, long long sKb,
             float* __restrict__ C, long long sCb, int ldc,
             int M, int N, int K)
{
    A  += (long long)blockIdx.z * sAb;
    Bm += (long long)blockIdx.z * sBb;
    C  += (long long)blockIdx.z * sCb;
    if (KSC) ksc += (long long)blockIdx.z * sKb;
    const int m0 = blockIdx.y * 64, n0 = blockIdx.x * 64;
    __shared__ float As[16][68];
    __shared__ float Bs[16][68];
    const int tid = threadIdx.x;
    const int lr = tid >> 2, lk = (tid & 3) << 2;
    const int tm = (tid >> 4) << 2, tn = (tid & 15) << 2;
    float acc[4][4] = {};
    for (int k0 = 0; k0 < K; k0 += 16) {
        float4 av = make_float4(0.f, 0.f, 0.f, 0.f);
        {
            int m = m0 + lr;
            if (m < M) {
                const float* ap = A + (long long)m * lda + k0 + lk;
                if (k0 + lk + 4 <= K) av = *(const float4*)ap;
                else {
                    if (k0 + lk + 0 < K) av.x = ap[0];
                    if (k0 + lk + 1 < K) av.y = ap[1];
                    if (k0 + lk + 2 < K) av.z = ap[2];
                    if (k0 + lk + 3 < K) av.w = ap[3];
                }
            }
            if (KSC) {
                if (k0 + lk + 0 < K) av.x *= ksc[k0 + lk + 0] + 1.f;
                if (k0 + lk + 1 < K) av.y *= ksc[k0 + lk + 1] + 1.f;
                if (k0 + lk + 2 < K) av.z *= ksc[k0 + lk + 2] + 1.f;
                if (k0 + lk + 3 < K) av.w *= ksc[k0 + lk + 3] + 1.f;
            }
        }
        float4 bv = make_float4(0.f, 0.f, 0.f, 0.f);
        {
            int n = n0 + lr;
            if (n < N) {
                const float* bp = Bm + (long long)n * ldb + k0 + lk;
                if (k0 + lk + 4 <= K) bv = *(const float4*)bp;
                else {
                    if (k0 + lk + 0 < K) bv.x = bp[0];
                    if (k0 + lk + 1 < K) bv.y = bp[1];
                    if (k0 + lk + 2 < K) bv.z = bp[2];
                    if (k0 + lk + 3 < K) bv.w = bp[3];
                }
            }
        }
        As[lk + 0][lr] = av.x; As[lk + 1][lr] = av.y; As[lk + 2][lr] = av.z; As[lk + 3][lr] = av.w;
        Bs[lk + 0][lr] = bv.x; Bs[lk + 1][lr] = bv.y; Bs[lk + 2][lr] = bv.z; Bs[lk + 3][lr] = bv.w;
        __syncthreads();
        #pragma unroll
        for (int kk = 0; kk < 16; kk++) {
            float a0 = As[kk][tm + 0], a1 = As[kk][tm + 1], a2 = As[kk][tm + 2], a3 = As[kk][tm + 3];
            float b0 = Bs[kk][tn + 0], b1 = Bs[kk][tn + 1], b2 = Bs[kk][tn + 2], b3 = Bs[kk][tn + 3];
            acc[0][0] += a0 * b0; acc[0][1] += a0 * b1; acc[0][2] += a0 * b2; acc[0][3] += a0 * b3;
            acc[1][0] += a1 * b0; acc[1][1] += a1 * b1; acc[1][2] += a1 * b2; acc[1][3] += a1 * b3;
            acc[2][0] += a2 * b0; acc[2][1] += a2 * b1; acc[2][2] += a2 * b2; acc[2][3] += a2 * b3;
            acc[3][0] += a3 * b0; acc[3][1] += a3 * b1; acc[3][2] += a3 * b2; acc[3][3] += a3 * b3;
        }
        __syncthreads();
    }
    #pragma unroll
    for (int i = 0; i < 4; i++) {
        int m = m0 + tm + i; if (m >= M) continue;
        #pragma unroll
        for (int j = 0; j < 4; j++) {
            int n = n0 + tn + j; if (n >= N) continue;
            float v = acc[i][j];
            if (bias) v += BIASM ? bias[m] : bias[n];
            if (EPI == 1) v = fmaxf(v, 0.f);
            if (EPI == 2) v = 1.f / (1.f + expf(-v));
            C[(long long)m * ldc + n] = v;
        }
    }
}

// ---------------- transpose: in[b][D][N] -> out[b][N][D] ----------------
__global__ void transpose_kernel(const float* __restrict__ in, float* __restrict__ out,
                                 int D, int N)
{
    __shared__ float tile[32][33];
    int b = blockIdx.z;
    int d0 = blockIdx.y * 32, n0 = blockIdx.x * 32;
    int tx = threadIdx.x, ty = threadIdx.y;
    for (int i = 0; i < 32; i += 8) {
        int d = d0 + ty + i, n = n0 + tx;
        if (d < D && n < N) tile[ty + i][tx] = in[((long long)b * D + d) * N + n];
    }
    __syncthreads();
    for (int i = 0; i < 32; i += 8) {
        int n = n0 + ty + i, d = d0 + tx;
        if (n < N && d < D) out[((long long)b * N + n) * D + d] = tile[tx][ty + i];
    }
}

// ---------------- audio[b][d] = mean_m vtf[b][m][d] ----------------
__global__ void audio_kernel(const float* __restrict__ vtf, float* __restrict__ audio)
{
    int b = blockIdx.x, tid = threadIdx.x;
    for (int d = tid; d < DD0; d += 256) {
        float s = 0.f;
        for (int m = 0; m < COUT; m++) s += vtf[((long long)b * COUT + m) * DD0 + d];
        audio[b * DD0 + d] = s * (1.f / (float)COUT);
    }
}

// ---------------- token<-vis attention: rep[b][t][:] ----------------
__global__ __launch_bounds__(256)
void att1_kernel(const float* __restrict__ vtf, const float* __restrict__ mt,
                 float* __restrict__ rep)
{
    int b = blockIdx.y, t = blockIdx.x, tid = threadIdx.x;
    __shared__ float mts[DD0];
    __shared__ float sc[COUT];
    __shared__ float sb[4];
    for (int d = tid; d < DD0; d += 256) mts[d] = mt[t * DD0 + d];
    __syncthreads();
    for (int m = tid; m < COUT; m += 256) {
        const float* vr = vtf + ((long long)b * COUT + m) * DD0;
        float s = 0.f;
        for (int d = 0; d < DD0; d++) s += mts[d] * vr[d];
        sc[m] = s;
    }
    __syncthreads();
    float lm = -1e30f;
    for (int m = tid; m < COUT; m += 256) lm = fmaxf(lm, sc[m]);
    float mx = block_max256(lm, sb);
    float ls = 0.f;
    for (int m = tid; m < COUT; m += 256) { float e = expf(sc[m] - mx); sc[m] = e; ls += e; }
    float ssum = block_sum256(ls, sb);
    float inv = 1.f / ssum;
    __syncthreads();
    for (int d = tid; d < DD0; d += 256) {
        float a = 0.f;
        for (int m = 0; m < COUT; m++) a += sc[m] * vtf[((long long)b * COUT + m) * DD0 + d];
        rep[((long long)b * TT + t) * DD0 + d] = mts[d] + a * inv;
    }
}

// ---------------- x<-token attention, update xT in place ----------------
__global__ __launch_bounds__(256)
void att2_kernel(const float* __restrict__ rep, const float* __restrict__ gav,
                 float* __restrict__ xT)
{
    int b = blockIdx.y, n = blockIdx.x, tid = threadIdx.x;
    __shared__ float xrow[DD0];
    __shared__ float p[TT];
    float* xr = xT + ((long long)b * NN + n) * DD0;
    for (int d = tid; d < DD0; d += 256) xrow[d] = xr[d];
    __syncthreads();
    int w = tid >> 6, l = tid & 63;
    for (int t = w * 8; t < w * 8 + 8; t++) {
        const float* rr = rep + ((long long)b * TT + t) * DD0;
        float s = 0.f;
        for (int d = l; d < DD0; d += 64) s += xrow[d] * rr[d];
        s = warp_sum(s);
        if (l == 0) p[t] = s;
    }
    __syncthreads();
    if (tid == 0) {
        float mx = -1e30f;
        for (int t = 0; t < TT; t++) mx = fmaxf(mx, p[t]);
        float s = 0.f;
        for (int t = 0; t < TT; t++) { p[t] = expf(p[t] - mx); s += p[t]; }
        float inv = 1.f / s;
        for (int t = 0; t < TT; t++) p[t] *= inv;
    }
    __syncthreads();
    float ga = gav[0];
    for (int d = tid; d < DD0; d += 256) {
        float a = 0.f;
        for (int t = 0; t < TT; t++) a += p[t] * rep[((long long)b * TT + t) * DD0 + d];
        xr[d] = xrow[d] + ga * a;
    }
}

// ---------------- mvq[b][d'] = aq1[b][d'] * mean_n vq1[b][n][d'] ----------------
__global__ void mvq_kernel(const float* __restrict__ vq1, const float* __restrict__ aq1,
                           float* __restrict__ mvq)
{
    int b = blockIdx.x, tid = threadIdx.x;
    for (int d = tid; d < DD0; d += 256) {
        float s = 0.f;
        for (int n = 0; n < NN; n++) s += vq1[((long long)b * NN + n) * DD0 + d];
        mvq[b * DD0 + d] = aq1[b * DD0 + d] * s * (1.f / (float)NN);
    }
}

// ---------------- s_tmp -> s_sig + sp_att (output 2) ----------------
__global__ __launch_bounds__(256)
void stmp_kernel(const float* __restrict__ cq, const float* __restrict__ aq2,
                 const float* __restrict__ vsw, const float* __restrict__ vsb,
                 float* __restrict__ ssig, float* __restrict__ spatt)
{
    int b = blockIdx.x, tid = threadIdx.x;
    __shared__ float wv[DM];
    __shared__ float st[NN];
    __shared__ float sb[4];
    for (int i = tid; i < DM; i += 256) wv[i] = aq2[b * DM + i] * vsw[i];
    __syncthreads();
    float vb = vsb[0];
    for (int n = tid; n < NN; n += 256) {
        const float* cr = cq + ((long long)b * NN + n) * DM;
        float s = vb;
        for (int d = 0; d < DM; d++) s += cr[d] * wv[d];
        st[n] = tanhf(s);
        ssig[b * NN + n] = 1.f / (1.f + expf(-s));
    }
    __syncthreads();
    float lm = -1e30f;
    for (int n = tid; n < NN; n += 256) lm = fmaxf(lm, st[n]);
    float mx = block_max256(lm, sb);
    float ls = 0.f;
    for (int n = tid; n < NN; n += 256) { float e = expf(st[n] - mx); st[n] = e; ls += e; }
    float s = block_sum256(ls, sb);
    float inv = 1.f / s;
    for (int n = tid; n < NN; n += 256) spatt[b * NN + n] = st[n] * inv;
}

// ---------------- gating scale + LayerNorm (lnb) in place on xT ----------------
__global__ __launch_bounds__(256)
void scale_ln_kernel(float* __restrict__ xT, const float* __restrict__ chatt,
                     const float* __restrict__ ssig, const float* __restrict__ g,
                     const float* __restrict__ bb)
{
    int b = blockIdx.y, n = blockIdx.x, tid = threadIdx.x;
    __shared__ float sb[4];
    float* xr = xT + ((long long)b * NN + n) * DD0;
    float ss = ssig[b * NN + n];
    float v[3];
    float lsum = 0.f;
    #pragma unroll
    for (int i = 0; i < 3; i++) {
        int d = tid + i * 256;
        float sc = 0.3f * chatt[b * DD0 + d] + 0.05f * ss + 0.7f;
        v[i] = xr[d] * sc;
        lsum += v[i];
    }
    float mean = block_sum256(lsum, sb) * (1.f / (float)DD0);
    float lvar = 0.f;
    #pragma unroll
    for (int i = 0; i < 3; i++) { float dd = v[i] - mean; lvar += dd * dd; }
    float var = block_sum256(lvar, sb) * (1.f / (float)DD0);
    float inv = rsqrtf(var + EPS);
    #pragma unroll
    for (int i = 0; i < 3; i++) {
        int d = tid + i * 256;
        xr[d] = (v[i] - mean) * inv * g[d] + bb[d];
    }
}

// ---------------- BN stats ----------------
__global__ void bn1stats_kernel(const float* __restrict__ y1, float* __restrict__ stats)
{
    int b = blockIdx.x, tid = threadIdx.x;
    if (tid < DDB) {
        float s = 0.f, q = 0.f;
        for (int n = 0; n < NN; n++) {
            float v = y1[((long long)b * NN + n) * DDB + tid];
            s += v; q += v * v;
        }
        atomicAdd(&stats[tid], s);
        atomicAdd(&stats[DDB + tid], q);
    }
}

__global__ void bn1apply_kernel(float* __restrict__ y1, const float* __restrict__ stats,
                                const float* __restrict__ g, const float* __restrict__ bb)
{
    long long i = (long long)blockIdx.x * 256 + threadIdx.x;
    if (i >= (long long)BB * NN * DDB) return;
    int e = (int)(i % DDB);
    const float cnt = (float)(BB * NN);
    float mu = stats[e] / cnt;
    float var = stats[DDB + e] / cnt - mu * mu;
    float v = (y1[i] - mu) * rsqrtf(var + EPS) * g[e] + bb[e];
    y1[i] = fmaxf(v, 0.f);
}

__global__ void bn2stats_kernel(const float* __restrict__ y2, float* __restrict__ stats)
{
    int b = blockIdx.x, tid = threadIdx.x;
    #pragma unroll
    for (int i = 0; i < 3; i++) {
        int d = tid + i * 256;
        float s = 0.f, q = 0.f;
        for (int n = 0; n < NN; n++) {
            float v = y2[((long long)b * NN + n) * DD0 + d];
            s += v; q += v * v;
        }
        atomicAdd(&stats[d], s);
        atomicAdd(&stats[DD0 + d], q);
    }
}

// ---------------- BN2 + LN(lnp) + gate -> out_tmp[b][n][d] ----------------
__global__ __launch_bounds__(256)
void final_kernel(const float* __restrict__ y2, const float* __restrict__ stats2,
                  const float* __restrict__ g2, const float* __restrict__ b2,
                  const float* __restrict__ lg, const float* __restrict__ lb,
                  const float* __restrict__ gate, float* __restrict__ out_tmp)
{
    int b = blockIdx.y, n = blockIdx.x, tid = threadIdx.x;
    __shared__ float sb[4];
    const float* yr = y2 + ((long long)b * NN + n) * DD0;
    const float cnt = (float)(BB * NN);
    float v[3];
    float lsum = 0.f;
    #pragma unroll
    for (int i = 0; i < 3; i++) {
        int d = tid + i * 256;
        float mu = stats2[d] / cnt;
        float var = stats2[DD0 + d] / cnt - mu * mu;
        v[i] = (yr[d] - mu) * rsqrtf(var + EPS) * g2[d] + b2[d];
        lsum += v[i];
    }
    float mean = block_sum256(lsum, sb) * (1.f / (float)DD0);
    float lvar = 0.f;
    #pragma unroll
    for (int i = 0; i < 3; i++) { float dd = v[i] - mean; lvar += dd * dd; }
    float var = block_sum256(lvar, sb) * (1.f / (float)DD0);
    float inv = rsqrtf(var + EPS);
    float gt = gate[0];
    float* orow = out_tmp + ((long long)b * NN + n) * DD0;
    #pragma unroll
    for (int i = 0; i < 3; i++) {
        int d = tid + i * 256;
        orow[d] = ((v[i] - mean) * inv * lg[d] + lb[d]) * gt;
    }
}

// ======================= launch =======================
extern "C" void kernel_launch(void* const* d_in, const int* in_sizes, int n_in,
                              void* d_out, int out_size, void* d_ws, size_t ws_size,
                              hipStream_t stream)
{
    const float* x       = (const float*)d_in[0];
    const float* vis     = (const float*)d_in[1];
    const float* conv_w  = (const float*)d_in[2];
    const float* conv_b  = (const float*)d_in[3];
    const float* fc_w    = (const float*)d_in[4];
    const float* fc_b    = (const float*)d_in[5];
    const float* a1_w    = (const float*)d_in[6];
    const float* a1_b    = (const float*)d_in[7];
    const float* v1_w    = (const float*)d_in[8];
    const float* v1_b    = (const float*)d_in[9];
    const float* btl_w   = (const float*)d_in[10];
    const float* btl_b   = (const float*)d_in[11];
    const float* v2_w    = (const float*)d_in[12];
    const float* v2_b    = (const float*)d_in[13];
    const float* a2_w    = (const float*)d_in[14];
    const float* a2_b    = (const float*)d_in[15];
    const float* vs_w    = (const float*)d_in[16];
    const float* vs_b    = (const float*)d_in[17];
    const float* vc_w    = (const float*)d_in[18];
    const float* vc_b    = (const float*)d_in[19];
    const float* my_tok  = (const float*)d_in[20];
    const float* gate_av = (const float*)d_in[21];
    const float* gate    = (const float*)d_in[22];
    const float* down_w  = (const float*)d_in[23];
    const float* up_w    = (const float*)d_in[24];
    const float* bn1_g   = (const float*)d_in[25];
    const float* bn1_b   = (const float*)d_in[26];
    const float* bn2_g   = (const float*)d_in[27];
    const float* bn2_b   = (const float*)d_in[28];
    const float* lnb_g   = (const float*)d_in[29];
    const float* lnb_b   = (const float*)d_in[30];
    const float* lnp_g   = (const float*)d_in[31];
    const float* lnp_b   = (const float*)d_in[32];

    float* ws = (float*)d_ws;
    float* vtc     = ws + OFF_VTC;
    float* vtf     = ws + OFF_VTF;
    float* xT      = ws + OFF_XT;
    float* rep     = ws + OFF_REP;
    float* y1      = ws + OFF_Y1;
    float* vq1     = ws + OFF_VTC;   // reuse region A
    float* cq      = ws + OFF_VTC;   // reuse region A
    float* y2      = ws + OFF_VTC;   // reuse region A
    float* out_tmp = ws + OFF_VTF;   // reuse region B
    float* audio   = ws + OFF_AUDIO;
    float* aq1b    = ws + OFF_AQ1;
    float* mvqb    = ws + OFF_MVQ;
    float* avqb    = ws + OFF_AVQ;
    float* chattb  = ws + OFF_CHATT;
    float* aq2b    = ws + OFF_AQ2;
    float* ssigb   = ws + OFF_SSIG;
    float* stats1  = ws + OFF_STATS;
    float* stats2  = ws + OFF_STATS + 2 * DDB;

    float* out   = (float*)d_out;
    float* spatt = out + (long long)BB * DD0 * NN;

    // zero BN stats accumulators (ws is poisoned each call)
    hipMemsetAsync(stats1, 0, (2 * DDB + 2 * DD0) * sizeof(float), stream);

    // 1. x [B,768,196] -> xT [B,196,768]
    transpose_kernel<<<dim3(7, 24, BB), dim3(32, 8), 0, stream>>>(x, xT, DD0, NN);
    // 2. vtc[b][o][l] = conv: M=196(o), N=1536(l), K=196(c), bias on M
    gemm_nt<0, false, true><<<dim3(24, 4, BB), 256, 0, stream>>>(
        conv_w, 0, CIN, vis, (long long)LIN * CIN, CIN, conv_b, nullptr, 0,
        vtc, (long long)COUT * LIN, LIN, COUT, LIN, CIN);
    // 3. vtf[b][m][d]: M=196, N=768, K=1536, bias fc_b on N
    gemm_nt<0, false, false><<<dim3(12, 4, BB), 256, 0, stream>>>(
        vtc, (long long)COUT * LIN, LIN, fc_w, 0, LIN, fc_b, nullptr, 0,
        vtf, (long long)COUT * DD0, DD0, COUT, DD0, LIN);
    // 4. audio
    audio_kernel<<<BB, 256, 0, stream>>>(vtf, audio);
    // 5. token<-vis attention -> rep
    att1_kernel<<<dim3(TT, BB), 256, 0, stream>>>(vtf, my_tok, rep);
    // 6. x<-token attention, xT updated in place
    att2_kernel<<<dim3(NN, BB), 256, 0, stream>>>(rep, gate_av, xT);
    // 7. aq1 = relu(audio@a1^T+b): M=64, N=768, K=768
    gemm_nt<1, false, false><<<dim3(12, 1, 1), 256, 0, stream>>>(
        audio, 0, DD0, a1_w, 0, DD0, a1_b, nullptr, 0, aq1b, 0, DD0, BB, DD0, DD0);
    // 8. vq1 = relu(xT@v1^T+b): per batch
    gemm_nt<1, false, false><<<dim3(12, 4, BB), 256, 0, stream>>>(
        xT, (long long)NN * DD0, DD0, v1_w, 0, DD0, v1_b, nullptr, 0,
        vq1, (long long)NN * DD0, DD0, NN, DD0, DD0);
    // 9. mvq = aq1 * mean_n vq1
    mvq_kernel<<<BB, 256, 0, stream>>>(vq1, aq1b, mvqb);
    // 10. avq = relu(mvq@btl^T+b): M=64, N=384, K=768
    gemm_nt<1, false, false><<<dim3(6, 1, 1), 256, 0, stream>>>(
        mvqb, 0, DD0, btl_w, 0, DD0, btl_b, nullptr, 0, avqb, 0, DM, BB, DM, DD0);
    // 11. ch_att = sigmoid(avq@vc^T+b): M=64, N=768, K=384
    gemm_nt<2, false, false><<<dim3(12, 1, 1), 256, 0, stream>>>(
        avqb, 0, DM, vc_w, 0, DM, vc_b, nullptr, 0, chattb, 0, DD0, BB, DD0, DM);
    // 12. aq2 = relu(audio@a2^T+b): M=64, N=384, K=768
    gemm_nt<1, false, false><<<dim3(6, 1, 1), 256, 0, stream>>>(
        audio, 0, DD0, a2_w, 0, DD0, a2_b, nullptr, 0, aq2b, 0, DM, BB, DM, DD0);
    // 13. c_q = relu((xT*(ch_att+1))@v2^T+b): per batch, kscale=ch_att
    gemm_nt<1, true, false><<<dim3(6, 4, BB), 256, 0, stream>>>(
        xT, (long long)NN * DD0, DD0, v2_w, 0, DD0, v2_b, chattb, DD0,
        cq, (long long)NN * DM, DM, NN, DM, DD0);
    // 14. s_tmp / s_sig / sp_att
    stmp_kernel<<<BB, 256, 0, stream>>>(cq, aq2b, vs_w, vs_b, ssigb, spatt);
    // 15. gating scale + ln_before (in place on xT)
    scale_ln_kernel<<<dim3(NN, BB), 256, 0, stream>>>(xT, chattb, ssigb, lnb_g, lnb_b);
    // 16. down: y1 = xT@down^T: M=196, N=96, K=768 (pre-BN)
    gemm_nt<0, false, false><<<dim3(2, 4, BB), 256, 0, stream>>>(
        xT, (long long)NN * DD0, DD0, down_w, 0, DD0, nullptr, nullptr, 0,
        y1, (long long)NN * DDB, DDB, NN, DDB, DD0);
    // 17-18. BN1 stats + apply(relu) in place
    bn1stats_kernel<<<BB, 128, 0, stream>>>(y1, stats1);
    bn1apply_kernel<<<(BB * NN * DDB + 255) / 256, 256, 0, stream>>>(y1, stats1, bn1_g, bn1_b);
    // 19. up: y2 = z@up^T: M=196, N=768, K=96 (pre-BN)
    gemm_nt<0, false, false><<<dim3(12, 4, BB), 256, 0, stream>>>(
        y1, (long long)NN * DDB, DDB, up_w, 0, DDB, nullptr, nullptr, 0,
        y2, (long long)NN * DD0, DD0, NN, DD0, DDB);
    // 20. BN2 stats
    bn2stats_kernel<<<BB, 256, 0, stream>>>(y2, stats2);
    // 21. BN2 + LN(lnp) + gate -> out_tmp [b][n][d]
    final_kernel<<<dim3(NN, BB), 256, 0, stream>>>(y2, stats2, bn2_g, bn2_b,
                                                   lnp_g, lnp_b, gate, out_tmp);
    // 22. out_tmp [B,196,768] -> out [B,768,196]
    transpose_kernel<<<dim3(24, 7, BB), dim3(32, 8), 0, stream>>>(out_tmp, out, NN, DD0);
}

// Round 3
// 1569.694 us; speedup vs baseline: 1.6016x; 1.6016x over previous
//
#include <hip/hip_runtime.h>
#include <math.h>

// ---- problem constants ----
#define BB 64
#define DD0 768
#define NN 196
#define LIN 1536
#define CIN 196
#define COUT 196
#define TT 32
#define DM 384
#define DDB 96
#define EPS 1e-5f
#define MFLAT (BB * NN)          // 12544, batch-flattened M for fc/vq1/cq
#define NCONV (BB * LIN)         // 98304, batch-flattened N for conv

// ---- workspace layout (float offsets) ----
// region A (9,633,792 f): vtc_bf16 (as 19,267,584 ushort) -> vq1 f32 -> cq f32 -> y2 f32
#define OFF_A     0LL
// region B: vtf f32 -> out_tmp f32
#define OFF_B     9633792LL
// region C: xT f32
#define OFF_XT    19267584LL
// region D: rep f32
#define OFF_REP   28901376LL
// region E: y1 f32
#define OFF_Y1    30474240LL
// bf16 weights
#define OFF_WCONV 31678464LL     // 196x200 ushort padded (19,600 f)
#define OFF_WFC   31698064LL     // 768x1536 ushort (589,824 f)
#define OFF_WV1   32287888LL     // 768x768  ushort (294,912 f)
#define OFF_WV2   32582800LL     // 384x768  ushort (147,456 f)
// smalls
#define OFF_SM    32730256LL
#define OFF_AUDIO (OFF_SM)
#define OFF_AQ1   (OFF_SM+49152)
#define OFF_MVQ   (OFF_SM+98304)
#define OFF_AVQ   (OFF_SM+147456)
#define OFF_CHATT (OFF_SM+172032)
#define OFF_AQ2   (OFF_SM+221184)
#define OFF_SSIG  (OFF_SM+245760)
#define OFF_STATS (OFF_SM+258304)

typedef __attribute__((ext_vector_type(8))) short short8;
typedef __attribute__((ext_vector_type(4))) float f32x4;

__device__ __forceinline__ unsigned short f2bf(float f) {
    union { float f; unsigned u; } v; v.f = f;
    unsigned r = v.u + 0x7fffu + ((v.u >> 16) & 1u);
    return (unsigned short)(r >> 16);
}

// ---------------- reduction helpers ----------------
__device__ __forceinline__ float warp_sum(float v) {
    for (int o = 32; o; o >>= 1) v += __shfl_down(v, o, 64);
    return v;
}
__device__ __forceinline__ float warp_max(float v) {
    for (int o = 32; o; o >>= 1) v = fmaxf(v, __shfl_down(v, o, 64));
    return v;
}
__device__ __forceinline__ float block_sum256(float v, float* sb) {
    v = warp_sum(v);
    __syncthreads();
    if ((threadIdx.x & 63) == 0) sb[threadIdx.x >> 6] = v;
    __syncthreads();
    return sb[0] + sb[1] + sb[2] + sb[3];
}
__device__ __forceinline__ float block_max256(float v, float* sb) {
    v = warp_max(v);
    __syncthreads();
    if ((threadIdx.x & 63) == 0) sb[threadIdx.x >> 6] = v;
    __syncthreads();
    return fmaxf(fmaxf(sb[0], sb[1]), fmaxf(sb[2], sb[3]));
}

// ================= bf16 MFMA GEMM: C[m][n] = epi(sum_k A[m][k]*B[n][k] + bias) =====
// Tile 128x128xBK64, 256 threads = 4 waves (2x2), 16x16x32 MFMA, fp32 accum.
// MODE 0: direct fp32 C [M][N], bias on N (M % 128 == 0, N % 128 == 0).
// MODE 1: conv scatter  - C bf16 at [(n/1536)*196 + m][1536] + n%1536, bias on M, guard m<M.
// ABF/BBF: operand source is bf16 (ushort) else fp32 (converted at stage time).
// KSC: A[m][k] *= (ksc[(m/196)*768 + k] + 1)   (fp32 A path only).
// EPI: 0 none, 1 relu.
template<int MODE, bool ABF, bool BBF, bool KSC, int EPI>
__global__ __launch_bounds__(256)
void gemm_mfma(const void* __restrict__ Ap, int lda,
               const void* __restrict__ Bp, int ldb,
               const float* __restrict__ bias, const float* __restrict__ ksc,
               void* __restrict__ Cp, int M, int N, int K)
{
    __shared__ unsigned short Asm[128][72];   // +8 bf16 pad: 16B -> conflict-minimal b128 reads
    __shared__ unsigned short Bsm[128][72];
    const int tid = threadIdx.x;
    const int m0 = blockIdx.y * 128, n0 = blockIdx.x * 128;
    const int w = tid >> 6, lane = tid & 63;
    const int wr = w >> 1, wc = w & 1;
    const int sr = tid >> 1, skh = (tid & 1) << 5;   // staging: row, k-half (32 elems)

    f32x4 acc[4][4];
    #pragma unroll
    for (int i = 0; i < 4; i++)
        #pragma unroll
        for (int j = 0; j < 4; j++) acc[i][j] = (f32x4){0.f, 0.f, 0.f, 0.f};

    const int nkt = (K + 63) >> 6;
    for (int kt = 0; kt < nkt; kt++) {
        const int k0 = kt << 6;
        // ---- stage A ----
        {
            const int gm = m0 + sr;
            const bool rok = (MODE == 1) ? (gm < M) : true;
            unsigned short tmp[32];
            if (ABF) {
                const unsigned short* Arow = (const unsigned short*)Ap + (long long)gm * lda + k0 + skh;
                #pragma unroll
                for (int q = 0; q < 4; q++) {
                    uint4 u = make_uint4(0u, 0u, 0u, 0u);
                    if (rok && (k0 + skh + q * 8) < K) u = *(const uint4*)(Arow + q * 8);
                    *(uint4*)&tmp[q * 8] = u;
                }
            } else {
                const float* Arow = (const float*)Ap + (long long)gm * lda + k0 + skh;
                const float* kc = nullptr;
                if (KSC) kc = ksc + (gm / 196) * 768 + k0 + skh;
                #pragma unroll
                for (int q = 0; q < 8; q++) {
                    float4 v = make_float4(0.f, 0.f, 0.f, 0.f);
                    if (rok && (k0 + skh + q * 4) < K) v = *(const float4*)(Arow + q * 4);
                    if (KSC) {
                        v.x *= kc[q * 4 + 0] + 1.f; v.y *= kc[q * 4 + 1] + 1.f;
                        v.z *= kc[q * 4 + 2] + 1.f; v.w *= kc[q * 4 + 3] + 1.f;
                    }
                    tmp[q * 4 + 0] = f2bf(v.x); tmp[q * 4 + 1] = f2bf(v.y);
                    tmp[q * 4 + 2] = f2bf(v.z); tmp[q * 4 + 3] = f2bf(v.w);
                }
            }
            #pragma unroll
            for (int q = 0; q < 4; q++) *(uint4*)&Asm[sr][skh + q * 8] = *(const uint4*)&tmp[q * 8];
        }
        // ---- stage B ----
        {
            const int gn = n0 + sr;   // all N tiles exact (N % 128 == 0)
            unsigned short tmp[32];
            if (BBF) {
                const unsigned short* Brow = (const unsigned short*)Bp + (long long)gn * ldb + k0 + skh;
                #pragma unroll
                for (int q = 0; q < 4; q++) {
                    uint4 u = make_uint4(0u, 0u, 0u, 0u);
                    if ((k0 + skh + q * 8) < K) u = *(const uint4*)(Brow + q * 8);
                    *(uint4*)&tmp[q * 8] = u;
                }
            } else {
                const float* Brow = (const float*)Bp + (long long)gn * ldb + k0 + skh;
                #pragma unroll
                for (int q = 0; q < 8; q++) {
                    float4 v = make_float4(0.f, 0.f, 0.f, 0.f);
                    if ((k0 + skh + q * 4) < K) v = *(const float4*)(Brow + q * 4);
                    tmp[q * 4 + 0] = f2bf(v.x); tmp[q * 4 + 1] = f2bf(v.y);
                    tmp[q * 4 + 2] = f2bf(v.z); tmp[q * 4 + 3] = f2bf(v.w);
                }
            }
            #pragma unroll
            for (int q = 0; q < 4; q++) *(uint4*)&Bsm[sr][skh + q * 8] = *(const uint4*)&tmp[q * 8];
        }
        __syncthreads();
        // ---- MFMA ----
        #pragma unroll
        for (int kk = 0; kk < 2; kk++) {
            short8 af[4], bfr[4];
            const int koff = kk * 32 + (lane >> 4) * 8;
            #pragma unroll
            for (int i = 0; i < 4; i++)
                af[i] = *(const short8*)&Asm[wr * 64 + i * 16 + (lane & 15)][koff];
            #pragma unroll
            for (int j = 0; j < 4; j++)
                bfr[j] = *(const short8*)&Bsm[wc * 64 + j * 16 + (lane & 15)][koff];
            #pragma unroll
            for (int i = 0; i < 4; i++)
                #pragma unroll
                for (int j = 0; j < 4; j++)
                    acc[i][j] = __builtin_amdgcn_mfma_f32_16x16x32_bf16(af[i], bfr[j], acc[i][j], 0, 0, 0);
        }
        __syncthreads();
    }
    // ---- epilogue: D row = (lane>>4)*4 + rr, col = lane&15 (m89-verified layout) ----
    const int cmb = wr * 64 + ((lane >> 4) << 2);
    const int cnb = wc * 64 + (lane & 15);
    #pragma unroll
    for (int i = 0; i < 4; i++) {
        #pragma unroll
        for (int j = 0; j < 4; j++) {
            const int gn = n0 + cnb + j * 16;
            #pragma unroll
            for (int rr = 0; rr < 4; rr++) {
                const int gm = m0 + cmb + i * 16 + rr;
                float v = acc[i][j][rr];
                if (MODE == 0) {
                    v += bias[gn];
                    if (EPI == 1) v = fmaxf(v, 0.f);
                    ((float*)Cp)[(long long)gm * N + gn] = v;
                } else {
                    if (gm < M) {
                        v += bias[gm];
                        const int b = gn / LIN, l = gn - b * LIN;
                        ((unsigned short*)Cp)[((long long)b * COUT + gm) * LIN + l] = f2bf(v);
                    }
                }
            }
        }
    }
}

// ---------------- weight f32 -> bf16 converters ----------------
__global__ void cvt_f2bf(const float* __restrict__ in, unsigned short* __restrict__ out, int n)
{
    int i = (blockIdx.x * 256 + threadIdx.x) * 4;
    if (i + 4 <= n) {
        float4 v = *(const float4*)(in + i);
        ushort4 o; o.x = f2bf(v.x); o.y = f2bf(v.y); o.z = f2bf(v.z); o.w = f2bf(v.w);
        *(ushort4*)(out + i) = o;
    }
}
__global__ void cvt_f2bf_pad(const float* __restrict__ in, unsigned short* __restrict__ out,
                             int rows, int cols, int ldo)
{
    int i = blockIdx.x * 256 + threadIdx.x;
    if (i < rows * ldo) {
        int r = i / ldo, c = i - r * ldo;
        out[i] = (c < cols) ? f2bf(in[r * cols + c]) : (unsigned short)0;
    }
}

// ---------------- fp32 NT GEMM (small/precision-critical GEMMs) ----------------
template<int EPI>
__global__ __launch_bounds__(256)
void gemm_nt(const float* __restrict__ A, long long sAb, int lda,
             const float* __restrict__ Bm, int ldb,
             const float* __restrict__ bias,
             float* __restrict__ C, long long sCb, int ldc,
             int M, int N, int K)
{
    A += (long long)blockIdx.z * sAb;
    C += (long long)blockIdx.z * sCb;
    const int m0 = blockIdx.y * 64, n0 = blockIdx.x * 64;
    __shared__ float As[16][68];
    __shared__ float Bs[16][68];
    const int tid = threadIdx.x;
    const int lr = tid >> 2, lk = (tid & 3) << 2;
    const int tm = (tid >> 4) << 2, tn = (tid & 15) << 2;
    float acc[4][4] = {};
    for (int k0 = 0; k0 < K; k0 += 16) {
        float4 av = make_float4(0.f, 0.f, 0.f, 0.f);
        {
            int m = m0 + lr;
            if (m < M && k0 + lk < K) av = *(const float4*)(A + (long long)m * lda + k0 + lk);
        }
        float4 bv = make_float4(0.f, 0.f, 0.f, 0.f);
        {
            int n = n0 + lr;
            if (n < N && k0 + lk < K) bv = *(const float4*)(Bm + (long long)n * ldb + k0 + lk);
        }
        As[lk + 0][lr] = av.x; As[lk + 1][lr] = av.y; As[lk + 2][lr] = av.z; As[lk + 3][lr] = av.w;
        Bs[lk + 0][lr] = bv.x; Bs[lk + 1][lr] = bv.y; Bs[lk + 2][lr] = bv.z; Bs[lk + 3][lr] = bv.w;
        __syncthreads();
        #pragma unroll
        for (int kk = 0; kk < 16; kk++) {
            float a0 = As[kk][tm + 0], a1 = As[kk][tm + 1], a2 = As[kk][tm + 2], a3 = As[kk][tm + 3];
            float b0 = Bs[kk][tn + 0], b1 = Bs[kk][tn + 1], b2 = Bs[kk][tn + 2], b3 = Bs[kk][tn + 3];
            acc[0][0] += a0 * b0; acc[0][1] += a0 * b1; acc[0][2] += a0 * b2; acc[0][3] += a0 * b3;
            acc[1][0] += a1 * b0; acc[1][1] += a1 * b1; acc[1][2] += a1 * b2; acc[1][3] += a1 * b3;
            acc[2][0] += a2 * b0; acc[2][1] += a2 * b1; acc[2][2] += a2 * b2; acc[2][3] += a2 * b3;
            acc[3][0] += a3 * b0; acc[3][1] += a3 * b1; acc[3][2] += a3 * b2; acc[3][3] += a3 * b3;
        }
        __syncthreads();
    }
    #pragma unroll
    for (int i = 0; i < 4; i++) {
        int m = m0 + tm + i; if (m >= M) continue;
        #pragma unroll
        for (int j = 0; j < 4; j++) {
            int n = n0 + tn + j; if (n >= N) continue;
            float v = acc[i][j];
            if (bias) v += bias[n];
            if (EPI == 1) v = fmaxf(v, 0.f);
            if (EPI == 2) v = 1.f / (1.f + expf(-v));
            C[(long long)m * ldc + n] = v;
        }
    }
}

// ---------------- transpose: in[b][D][N] -> out[b][N][D] ----------------
__global__ void transpose_kernel(const float* __restrict__ in, float* __restrict__ out,
                                 int D, int N)
{
    __shared__ float tile[32][33];
    int b = blockIdx.z;
    int d0 = blockIdx.y * 32, n0 = blockIdx.x * 32;
    int tx = threadIdx.x, ty = threadIdx.y;
    for (int i = 0; i < 32; i += 8) {
        int d = d0 + ty + i, n = n0 + tx;
        if (d < D && n < N) tile[ty + i][tx] = in[((long long)b * D + d) * N + n];
    }
    __syncthreads();
    for (int i = 0; i < 32; i += 8) {
        int n = n0 + ty + i, d = d0 + tx;
        if (n < N && d < D) out[((long long)b * N + n) * D + d] = tile[tx][ty + i];
    }
}

// ---------------- audio[b][d] = mean_m vtf[b][m][d] ----------------
__global__ void audio_kernel(const float* __restrict__ vtf, float* __restrict__ audio)
{
    int b = blockIdx.x, tid = threadIdx.x;
    for (int d = tid; d < DD0; d += 256) {
        float s = 0.f;
        for (int m = 0; m < COUT; m++) s += vtf[((long long)b * COUT + m) * DD0 + d];
        audio[b * DD0 + d] = s * (1.f / (float)COUT);
    }
}

// ---------------- token<-vis attention (coalesced score pass) ----------------
__global__ __launch_bounds__(256)
void att1_kernel(const float* __restrict__ vtf, const float* __restrict__ mt,
                 float* __restrict__ rep)
{
    int b = blockIdx.y, t = blockIdx.x, tid = threadIdx.x;
    __shared__ float mts[DD0];
    __shared__ float sc[COUT];
    __shared__ float sb[4];
    for (int d = tid; d < DD0; d += 256) mts[d] = mt[t * DD0 + d];
    __syncthreads();
    // wave-per-row scores: lanes stride d => coalesced vtf reads
    int w = tid >> 6, l = tid & 63;
    for (int m = w; m < COUT; m += 4) {
        const float* vr = vtf + ((long long)b * COUT + m) * DD0;
        float s = 0.f;
        for (int d = l; d < DD0; d += 64) s += mts[d] * vr[d];
        s = warp_sum(s);
        if (l == 0) sc[m] = s;
    }
    __syncthreads();
    float lm = -1e30f;
    for (int m = tid; m < COUT; m += 256) lm = fmaxf(lm, sc[m]);
    float mx = block_max256(lm, sb);
    float ls = 0.f;
    for (int m = tid; m < COUT; m += 256) { float e = expf(sc[m] - mx); sc[m] = e; ls += e; }
    float ssum = block_sum256(ls, sb);
    float inv = 1.f / ssum;
    __syncthreads();
    for (int d = tid; d < DD0; d += 256) {
        float a = 0.f;
        for (int m = 0; m < COUT; m++) a += sc[m] * vtf[((long long)b * COUT + m) * DD0 + d];
        rep[((long long)b * TT + t) * DD0 + d] = mts[d] + a * inv;
    }
}

// ---------------- x<-token attention, update xT in place ----------------
__global__ __launch_bounds__(256)
void att2_kernel(const float* __restrict__ rep, const float* __restrict__ gav,
                 float* __restrict__ xT)
{
    int b = blockIdx.y, n = blockIdx.x, tid = threadIdx.x;
    __shared__ float xrow[DD0];
    __shared__ float p[TT];
    float* xr = xT + ((long long)b * NN + n) * DD0;
    for (int d = tid; d < DD0; d += 256) xrow[d] = xr[d];
    __syncthreads();
    int w = tid >> 6, l = tid & 63;
    for (int t = w * 8; t < w * 8 + 8; t++) {
        const float* rr = rep + ((long long)b * TT + t) * DD0;
        float s = 0.f;
        for (int d = l; d < DD0; d += 64) s += xrow[d] * rr[d];
        s = warp_sum(s);
        if (l == 0) p[t] = s;
    }
    __syncthreads();
    if (tid == 0) {
        float mx = -1e30f;
        for (int t = 0; t < TT; t++) mx = fmaxf(mx, p[t]);
        float s = 0.f;
        for (int t = 0; t < TT; t++) { p[t] = expf(p[t] - mx); s += p[t]; }
        float inv = 1.f / s;
        for (int t = 0; t < TT; t++) p[t] *= inv;
    }
    __syncthreads();
    float ga = gav[0];
    for (int d = tid; d < DD0; d += 256) {
        float a = 0.f;
        for (int t = 0; t < TT; t++) a += p[t] * rep[((long long)b * TT + t) * DD0 + d];
        xr[d] = xrow[d] + ga * a;
    }
}

// ---------------- mvq[b][d'] = aq1[b][d'] * mean_n vq1[b][n][d'] ----------------
__global__ void mvq_kernel(const float* __restrict__ vq1, const float* __restrict__ aq1,
                           float* __restrict__ mvq)
{
    int b = blockIdx.x, tid = threadIdx.x;
    for (int d = tid; d < DD0; d += 256) {
        float s = 0.f;
        for (int n = 0; n < NN; n++) s += vq1[((long long)b * NN + n) * DD0 + d];
        mvq[b * DD0 + d] = aq1[b * DD0 + d] * s * (1.f / (float)NN);
    }
}

// ---------------- s_tmp -> s_sig + sp_att ----------------
__global__ __launch_bounds__(256)
void stmp_kernel(const float* __restrict__ cq, const float* __restrict__ aq2,
                 const float* __restrict__ vsw, const float* __restrict__ vsb,
                 float* __restrict__ ssig, float* __restrict__ spatt)
{
    int b = blockIdx.x, tid = threadIdx.x;
    __shared__ float wv[DM];
    __shared__ float st[NN];
    __shared__ float sb[4];
    for (int i = tid; i < DM; i += 256) wv[i] = aq2[b * DM + i] * vsw[i];
    __syncthreads();
    float vb = vsb[0];
    for (int n = tid; n < NN; n += 256) {
        const float* cr = cq + ((long long)b * NN + n) * DM;
        float s = vb;
        for (int d = 0; d < DM; d++) s += cr[d] * wv[d];
        st[n] = tanhf(s);
        ssig[b * NN + n] = 1.f / (1.f + expf(-s));
    }
    __syncthreads();
    float lm = -1e30f;
    for (int n = tid; n < NN; n += 256) lm = fmaxf(lm, st[n]);
    float mx = block_max256(lm, sb);
    float ls = 0.f;
    for (int n = tid; n < NN; n += 256) { float e = expf(st[n] - mx); st[n] = e; ls += e; }
    float s = block_sum256(ls, sb);
    float inv = 1.f / s;
    for (int n = tid; n < NN; n += 256) spatt[b * NN + n] = st[n] * inv;
}

// ---------------- gating scale + LayerNorm (lnb) in place on xT ----------------
__global__ __launch_bounds__(256)
void scale_ln_kernel(float* __restrict__ xT, const float* __restrict__ chatt,
                     const float* __restrict__ ssig, const float* __restrict__ g,
                     const float* __restrict__ bb)
{
    int b = blockIdx.y, n = blockIdx.x, tid = threadIdx.x;
    __shared__ float sb[4];
    float* xr = xT + ((long long)b * NN + n) * DD0;
    float ss = ssig[b * NN + n];
    float v[3];
    float lsum = 0.f;
    #pragma unroll
    for (int i = 0; i < 3; i++) {
        int d = tid + i * 256;
        float sc = 0.3f * chatt[b * DD0 + d] + 0.05f * ss + 0.7f;
        v[i] = xr[d] * sc;
        lsum += v[i];
    }
    float mean = block_sum256(lsum, sb) * (1.f / (float)DD0);
    float lvar = 0.f;
    #pragma unroll
    for (int i = 0; i < 3; i++) { float dd = v[i] - mean; lvar += dd * dd; }
    float var = block_sum256(lvar, sb) * (1.f / (float)DD0);
    float inv = rsqrtf(var + EPS);
    #pragma unroll
    for (int i = 0; i < 3; i++) {
        int d = tid + i * 256;
        xr[d] = (v[i] - mean) * inv * g[d] + bb[d];
    }
}

// ---------------- BN stats ----------------
__global__ void bn1stats_kernel(const float* __restrict__ y1, float* __restrict__ stats)
{
    int b = blockIdx.x, tid = threadIdx.x;
    if (tid < DDB) {
        float s = 0.f, q = 0.f;
        for (int n = 0; n < NN; n++) {
            float v = y1[((long long)b * NN + n) * DDB + tid];
            s += v; q += v * v;
        }
        atomicAdd(&stats[tid], s);
        atomicAdd(&stats[DDB + tid], q);
    }
}

__global__ void bn1apply_kernel(float* __restrict__ y1, const float* __restrict__ stats,
                                const float* __restrict__ g, const float* __restrict__ bb)
{
    long long i = (long long)blockIdx.x * 256 + threadIdx.x;
    if (i >= (long long)BB * NN * DDB) return;
    int e = (int)(i % DDB);
    const float cnt = (float)(BB * NN);
    float mu = stats[e] / cnt;
    float var = stats[DDB + e] / cnt - mu * mu;
    float v = (y1[i] - mu) * rsqrtf(var + EPS) * g[e] + bb[e];
    y1[i] = fmaxf(v, 0.f);
}

__global__ void bn2stats_kernel(const float* __restrict__ y2, float* __restrict__ stats)
{
    int b = blockIdx.x, tid = threadIdx.x;
    #pragma unroll
    for (int i = 0; i < 3; i++) {
        int d = tid + i * 256;
        float s = 0.f, q = 0.f;
        for (int n = 0; n < NN; n++) {
            float v = y2[((long long)b * NN + n) * DD0 + d];
            s += v; q += v * v;
        }
        atomicAdd(&stats[d], s);
        atomicAdd(&stats[DD0 + d], q);
    }
}

// ---------------- BN2 + LN(lnp) + gate -> out_tmp[b][n][d] ----------------
__global__ __launch_bounds__(256)
void final_kernel(const float* __restrict__ y2, const float* __restrict__ stats2,
                  const float* __restrict__ g2, const float* __restrict__ b2,
                  const float* __restrict__ lg, const float* __restrict__ lb,
                  const float* __restrict__ gate, float* __restrict__ out_tmp)
{
    int b = blockIdx.y, n = blockIdx.x, tid = threadIdx.x;
    __shared__ float sb[4];
    const float* yr = y2 + ((long long)b * NN + n) * DD0;
    const float cnt = (float)(BB * NN);
    float v[3];
    float lsum = 0.f;
    #pragma unroll
    for (int i = 0; i < 3; i++) {
        int d = tid + i * 256;
        float mu = stats2[d] / cnt;
        float var = stats2[DD0 + d] / cnt - mu * mu;
        v[i] = (yr[d] - mu) * rsqrtf(var + EPS) * g2[d] + b2[d];
        lsum += v[i];
    }
    float mean = block_sum256(lsum, sb) * (1.f / (float)DD0);
    float lvar = 0.f;
    #pragma unroll
    for (int i = 0; i < 3; i++) { float dd = v[i] - mean; lvar += dd * dd; }
    float var = block_sum256(lvar, sb) * (1.f / (float)DD0);
    float inv = rsqrtf(var + EPS);
    float gt = gate[0];
    float* orow = out_tmp + ((long long)b * NN + n) * DD0;
    #pragma unroll
    for (int i = 0; i < 3; i++) {
        int d = tid + i * 256;
        orow[d] = ((v[i] - mean) * inv * lg[d] + lb[d]) * gt;
    }
}

// ======================= launch =======================
extern "C" void kernel_launch(void* const* d_in, const int* in_sizes, int n_in,
                              void* d_out, int out_size, void* d_ws, size_t ws_size,
                              hipStream_t stream)
{
    const float* x       = (const float*)d_in[0];
    const float* vis     = (const float*)d_in[1];
    const float* conv_w  = (const float*)d_in[2];
    const float* conv_b  = (const float*)d_in[3];
    const float* fc_w    = (const float*)d_in[4];
    const float* fc_b    = (const float*)d_in[5];
    const float* a1_w    = (const float*)d_in[6];
    const float* a1_b    = (const float*)d_in[7];
    const float* v1_w    = (const float*)d_in[8];
    const float* v1_b    = (const float*)d_in[9];
    const float* btl_w   = (const float*)d_in[10];
    const float* btl_b   = (const float*)d_in[11];
    const float* v2_w    = (const float*)d_in[12];
    const float* v2_b    = (const float*)d_in[13];
    const float* a2_w    = (const float*)d_in[14];
    const float* a2_b    = (const float*)d_in[15];
    const float* vs_w    = (const float*)d_in[16];
    const float* vs_b    = (const float*)d_in[17];
    const float* vc_w    = (const float*)d_in[18];
    const float* vc_b    = (const float*)d_in[19];
    const float* my_tok  = (const float*)d_in[20];
    const float* gate_av = (const float*)d_in[21];
    const float* gate    = (const float*)d_in[22];
    const float* down_w  = (const float*)d_in[23];
    const float* up_w    = (const float*)d_in[24];
    const float* bn1_g   = (const float*)d_in[25];
    const float* bn1_b   = (const float*)d_in[26];
    const float* bn2_g   = (const float*)d_in[27];
    const float* bn2_b   = (const float*)d_in[28];
    const float* lnb_g   = (const float*)d_in[29];
    const float* lnb_b   = (const float*)d_in[30];
    const float* lnp_g   = (const float*)d_in[31];
    const float* lnp_b   = (const float*)d_in[32];

    float* ws = (float*)d_ws;
    unsigned short* vtc_bf = (unsigned short*)(ws + OFF_A);
    float* vq1     = ws + OFF_A;     // region A reuse (after fc consumed vtc_bf)
    float* cq      = ws + OFF_A;
    float* y2      = ws + OFF_A;
    float* vtf     = ws + OFF_B;
    float* out_tmp = ws + OFF_B;
    float* xT      = ws + OFF_XT;
    float* rep     = ws + OFF_REP;
    float* y1      = ws + OFF_Y1;
    unsigned short* wconv = (unsigned short*)(ws + OFF_WCONV);
    unsigned short* wfc   = (unsigned short*)(ws + OFF_WFC);
    unsigned short* wv1   = (unsigned short*)(ws + OFF_WV1);
    unsigned short* wv2   = (unsigned short*)(ws + OFF_WV2);
    float* audio   = ws + OFF_AUDIO;
    float* aq1b    = ws + OFF_AQ1;
    float* mvqb    = ws + OFF_MVQ;
    float* avqb    = ws + OFF_AVQ;
    float* chattb  = ws + OFF_CHATT;
    float* aq2b    = ws + OFF_AQ2;
    float* ssigb   = ws + OFF_SSIG;
    float* stats1  = ws + OFF_STATS;
    float* stats2  = ws + OFF_STATS + 2 * DDB;

    float* out   = (float*)d_out;
    float* spatt = out + (long long)BB * DD0 * NN;

    hipMemsetAsync(stats1, 0, (2 * DDB + 2 * DD0) * sizeof(float), stream);

    // 0. weight conversions (f32 -> bf16)
    cvt_f2bf<<<(DD0 * LIN / 4 + 255) / 256, 256, 0, stream>>>(fc_w, wfc, DD0 * LIN);
    cvt_f2bf<<<(DD0 * DD0 / 4 + 255) / 256, 256, 0, stream>>>(v1_w, wv1, DD0 * DD0);
    cvt_f2bf<<<(DM * DD0 / 4 + 255) / 256, 256, 0, stream>>>(v2_w, wv2, DM * DD0);
    cvt_f2bf_pad<<<(COUT * 200 + 255) / 256, 256, 0, stream>>>(conv_w, wconv, COUT, CIN, 200);

    // 1. x [B,768,196] -> xT [B,196,768]
    transpose_kernel<<<dim3(7, 24, BB), dim3(32, 8), 0, stream>>>(x, xT, DD0, NN);
    // 2. conv (MFMA): M=196(o), N'=98304(b,l), K=196; A=conv_w bf16 (lda 200), B=vis f32; -> vtc_bf
    gemm_mfma<1, true, false, false, 0><<<dim3(NCONV / 128, 2), 256, 0, stream>>>(
        wconv, 200, vis, CIN, conv_b, nullptr, vtc_bf, COUT, NCONV, CIN);
    // 3. fc (MFMA): M'=12544, N=768, K=1536; A=vtc_bf, B=wfc; -> vtf f32
    gemm_mfma<0, true, true, false, 0><<<dim3(DD0 / 128, MFLAT / 128), 256, 0, stream>>>(
        vtc_bf, LIN, wfc, LIN, fc_b, nullptr, vtf, MFLAT, DD0, LIN);
    // 4. audio
    audio_kernel<<<BB, 256, 0, stream>>>(vtf, audio);
    // 5. token<-vis attention -> rep
    att1_kernel<<<dim3(TT, BB), 256, 0, stream>>>(vtf, my_tok, rep);
    // 6. x<-token attention (in place on xT)
    att2_kernel<<<dim3(NN, BB), 256, 0, stream>>>(rep, gate_av, xT);
    // 7. aq1 = relu(audio@a1^T+b) fp32
    gemm_nt<1><<<dim3(12, 1, 1), 256, 0, stream>>>(
        audio, 0, DD0, a1_w, DD0, a1_b, aq1b, 0, DD0, BB, DD0, DD0);
    // 8. vq1 (MFMA): M'=12544, N=768, K=768, relu
    gemm_mfma<0, false, true, false, 1><<<dim3(DD0 / 128, MFLAT / 128), 256, 0, stream>>>(
        xT, DD0, wv1, DD0, v1_b, nullptr, vq1, MFLAT, DD0, DD0);
    // 9. mvq = aq1 * mean_n vq1
    mvq_kernel<<<BB, 256, 0, stream>>>(vq1, aq1b, mvqb);
    // 10. avq = relu(mvq@btl^T+b) fp32
    gemm_nt<1><<<dim3(6, 1, 1), 256, 0, stream>>>(
        mvqb, 0, DD0, btl_w, DD0, btl_b, avqb, 0, DM, BB, DM, DD0);
    // 11. ch_att = sigmoid(avq@vc^T+b) fp32
    gemm_nt<2><<<dim3(12, 1, 1), 256, 0, stream>>>(
        avqb, 0, DM, vc_w, DM, vc_b, chattb, 0, DD0, BB, DD0, DM);
    // 12. aq2 = relu(audio@a2^T+b) fp32
    gemm_nt<1><<<dim3(6, 1, 1), 256, 0, stream>>>(
        audio, 0, DD0, a2_w, DD0, a2_b, aq2b, 0, DM, BB, DM, DD0);
    // 13. c_q (MFMA): M'=12544, N=384, K=768, relu, k-scale=(ch_att+1) per row-batch
    gemm_mfma<0, false, true, true, 1><<<dim3(DM / 128, MFLAT / 128), 256, 0, stream>>>(
        xT, DD0, wv2, DD0, v2_b, chattb, cq, MFLAT, DM, DD0);
    // 14. s_tmp / s_sig / sp_att
    stmp_kernel<<<BB, 256, 0, stream>>>(cq, aq2b, vs_w, vs_b, ssigb, spatt);
    // 15. gating scale + ln_before (in place on xT)
    scale_ln_kernel<<<dim3(NN, BB), 256, 0, stream>>>(xT, chattb, ssigb, lnb_g, lnb_b);
    // 16. down: y1 = xT@down^T fp32 (precision-critical path)
    gemm_nt<0><<<dim3(2, 4, BB), 256, 0, stream>>>(
        xT, (long long)NN * DD0, DD0, down_w, DD0, nullptr,
        y1, (long long)NN * DDB, DDB, NN, DDB, DD0);
    // 17-18. BN1 stats + apply(relu)
    bn1stats_kernel<<<BB, 128, 0, stream>>>(y1, stats1);
    bn1apply_kernel<<<(BB * NN * DDB + 255) / 256, 256, 0, stream>>>(y1, stats1, bn1_g, bn1_b);
    // 19. up: y2 = z@up^T fp32
    gemm_nt<0><<<dim3(12, 4, BB), 256, 0, stream>>>(
        y1, (long long)NN * DDB, DDB, up_w, DDB, nullptr,
        y2, (long long)NN * DD0, DD0, NN, DD0, DDB);
    // 20. BN2 stats
    bn2stats_kernel<<<BB, 256, 0, stream>>>(y2, stats2);
    // 21. BN2 + LN(lnp) + gate -> out_tmp
    final_kernel<<<dim3(NN, BB), 256, 0, stream>>>(y2, stats2, bn2_g, bn2_b,
                                                   lnp_g, lnp_b, gate, out_tmp);
    // 22. out_tmp [B,196,768] -> out [B,768,196]
    transpose_kernel<<<dim3(24, 7, BB), dim3(32, 8), 0, stream>>>(out_tmp, out, NN, DD0);
}

// Round 4
// 1151.126 us; speedup vs baseline: 2.1839x; 1.3636x over previous
//
#include <hip/hip_runtime.h>
#include <math.h>

// ---- problem constants ----
#define BB 64
#define DD0 768
#define NN 196
#define LIN 1536
#define CIN 196
#define COUT 196
#define TT 32
#define DM 384
#define DDB 96
#define EPS 1e-5f
#define MFLAT (BB * NN)          // 12544, batch-flattened M for fc/vq1/cq
#define NCONV (BB * LIN)         // 98304, batch-flattened N for conv

// ---- workspace layout (float offsets) ----
#define OFF_A     0LL            // vtc_bf16 -> vq1 f32 -> cq f32 -> y2 f32
#define OFF_B     9633792LL      // vtf f32 -> out_tmp f32
#define OFF_XT    19267584LL     // xT f32
#define OFF_REP   28901376LL     // rep f32
#define OFF_Y1    30474240LL     // y1 f32
#define OFF_WCONV 31678464LL     // 196x200 ushort padded
#define OFF_WFC   31698064LL     // 768x1536 ushort
#define OFF_WV1   32287888LL     // 768x768  ushort
#define OFF_WV2   32582800LL     // 384x768  ushort
#define OFF_SM    32730256LL
#define OFF_AUDIO (OFF_SM)
#define OFF_AQ1   (OFF_SM+49152)
#define OFF_MVQ   (OFF_SM+98304)
#define OFF_AVQ   (OFF_SM+147456)
#define OFF_CHATT (OFF_SM+172032)
#define OFF_AQ2   (OFF_SM+221184)
#define OFF_SSIG  (OFF_SM+245760)
#define OFF_STATS (OFF_SM+258304)
#define OFF_PBUF  (OFF_SM+262144)  // att1 P: B*32*224 ushort = 229,376 f slots

typedef __attribute__((ext_vector_type(8))) short short8;
typedef __attribute__((ext_vector_type(4))) float f32x4;

__device__ __forceinline__ unsigned short f2bf(float f) {
    union { float f; unsigned u; } v; v.f = f;
    unsigned r = v.u + 0x7fffu + ((v.u >> 16) & 1u);
    return (unsigned short)(r >> 16);
}
__device__ __forceinline__ short8 cvt8(const float4 a, const float4 b) {
    short8 r;
    r[0] = (short)f2bf(a.x); r[1] = (short)f2bf(a.y); r[2] = (short)f2bf(a.z); r[3] = (short)f2bf(a.w);
    r[4] = (short)f2bf(b.x); r[5] = (short)f2bf(b.y); r[6] = (short)f2bf(b.z); r[7] = (short)f2bf(b.w);
    return r;
}
// LDS fragment read as 2x b64 (rows padded to 36 ushorts = 72B; 8B-aligned)
__device__ __forceinline__ short8 lds_frag(const unsigned short* p) {
    short4 lo = *(const short4*)p;
    short4 hi = *(const short4*)(p + 4);
    short8 r;
    r[0] = lo.x; r[1] = lo.y; r[2] = lo.z; r[3] = lo.w;
    r[4] = hi.x; r[5] = hi.y; r[6] = hi.z; r[7] = hi.w;
    return r;
}

// ---------------- reduction helpers ----------------
__device__ __forceinline__ float warp_sum(float v) {
    for (int o = 32; o; o >>= 1) v += __shfl_down(v, o, 64);
    return v;
}
__device__ __forceinline__ float wave_allsum(float v) {
    for (int o = 1; o < 64; o <<= 1) v += __shfl_xor(v, o, 64);
    return v;
}
__device__ __forceinline__ float wave_allmax(float v) {
    for (int o = 1; o < 64; o <<= 1) v = fmaxf(v, __shfl_xor(v, o, 64));
    return v;
}
__device__ __forceinline__ float warp_max(float v) {
    for (int o = 32; o; o >>= 1) v = fmaxf(v, __shfl_down(v, o, 64));
    return v;
}
__device__ __forceinline__ float block_sum256(float v, float* sb) {
    v = warp_sum(v);
    __syncthreads();
    if ((threadIdx.x & 63) == 0) sb[threadIdx.x >> 6] = v;
    __syncthreads();
    return sb[0] + sb[1] + sb[2] + sb[3];
}
__device__ __forceinline__ float block_max256(float v, float* sb) {
    v = warp_max(v);
    __syncthreads();
    if ((threadIdx.x & 63) == 0) sb[threadIdx.x >> 6] = v;
    __syncthreads();
    return fmaxf(fmaxf(sb[0], sb[1]), fmaxf(sb[2], sb[3]));
}

// ================= bf16 MFMA GEMM (unchanged from R3) =================
template<int MODE, bool ABF, bool BBF, bool KSC, int EPI>
__global__ __launch_bounds__(256)
void gemm_mfma(const void* __restrict__ Ap, int lda,
               const void* __restrict__ Bp, int ldb,
               const float* __restrict__ bias, const float* __restrict__ ksc,
               void* __restrict__ Cp, int M, int N, int K)
{
    __shared__ unsigned short Asm[128][72];
    __shared__ unsigned short Bsm[128][72];
    const int tid = threadIdx.x;
    const int m0 = blockIdx.y * 128, n0 = blockIdx.x * 128;
    const int w = tid >> 6, lane = tid & 63;
    const int wr = w >> 1, wc = w & 1;
    const int sr = tid >> 1, skh = (tid & 1) << 5;

    f32x4 acc[4][4];
    #pragma unroll
    for (int i = 0; i < 4; i++)
        #pragma unroll
        for (int j = 0; j < 4; j++) acc[i][j] = (f32x4){0.f, 0.f, 0.f, 0.f};

    const int nkt = (K + 63) >> 6;
    for (int kt = 0; kt < nkt; kt++) {
        const int k0 = kt << 6;
        {
            const int gm = m0 + sr;
            const bool rok = (MODE == 1) ? (gm < M) : true;
            unsigned short tmp[32];
            if (ABF) {
                const unsigned short* Arow = (const unsigned short*)Ap + (long long)gm * lda + k0 + skh;
                #pragma unroll
                for (int q = 0; q < 4; q++) {
                    uint4 u = make_uint4(0u, 0u, 0u, 0u);
                    if (rok && (k0 + skh + q * 8) < K) u = *(const uint4*)(Arow + q * 8);
                    *(uint4*)&tmp[q * 8] = u;
                }
            } else {
                const float* Arow = (const float*)Ap + (long long)gm * lda + k0 + skh;
                const float* kc = nullptr;
                if (KSC) kc = ksc + (gm / 196) * 768 + k0 + skh;
                #pragma unroll
                for (int q = 0; q < 8; q++) {
                    float4 v = make_float4(0.f, 0.f, 0.f, 0.f);
                    if (rok && (k0 + skh + q * 4) < K) v = *(const float4*)(Arow + q * 4);
                    if (KSC) {
                        v.x *= kc[q * 4 + 0] + 1.f; v.y *= kc[q * 4 + 1] + 1.f;
                        v.z *= kc[q * 4 + 2] + 1.f; v.w *= kc[q * 4 + 3] + 1.f;
                    }
                    tmp[q * 4 + 0] = f2bf(v.x); tmp[q * 4 + 1] = f2bf(v.y);
                    tmp[q * 4 + 2] = f2bf(v.z); tmp[q * 4 + 3] = f2bf(v.w);
                }
            }
            #pragma unroll
            for (int q = 0; q < 4; q++) *(uint4*)&Asm[sr][skh + q * 8] = *(const uint4*)&tmp[q * 8];
        }
        {
            const int gn = n0 + sr;
            unsigned short tmp[32];
            if (BBF) {
                const unsigned short* Brow = (const unsigned short*)Bp + (long long)gn * ldb + k0 + skh;
                #pragma unroll
                for (int q = 0; q < 4; q++) {
                    uint4 u = make_uint4(0u, 0u, 0u, 0u);
                    if ((k0 + skh + q * 8) < K) u = *(const uint4*)(Brow + q * 8);
                    *(uint4*)&tmp[q * 8] = u;
                }
            } else {
                const float* Brow = (const float*)Bp + (long long)gn * ldb + k0 + skh;
                #pragma unroll
                for (int q = 0; q < 8; q++) {
                    float4 v = make_float4(0.f, 0.f, 0.f, 0.f);
                    if ((k0 + skh + q * 4) < K) v = *(const float4*)(Brow + q * 4);
                    tmp[q * 4 + 0] = f2bf(v.x); tmp[q * 4 + 1] = f2bf(v.y);
                    tmp[q * 4 + 2] = f2bf(v.z); tmp[q * 4 + 3] = f2bf(v.w);
                }
            }
            #pragma unroll
            for (int q = 0; q < 4; q++) *(uint4*)&Bsm[sr][skh + q * 8] = *(const uint4*)&tmp[q * 8];
        }
        __syncthreads();
        #pragma unroll
        for (int kk = 0; kk < 2; kk++) {
            short8 af[4], bfr[4];
            const int koff = kk * 32 + (lane >> 4) * 8;
            #pragma unroll
            for (int i = 0; i < 4; i++)
                af[i] = *(const short8*)&Asm[wr * 64 + i * 16 + (lane & 15)][koff];
            #pragma unroll
            for (int j = 0; j < 4; j++)
                bfr[j] = *(const short8*)&Bsm[wc * 64 + j * 16 + (lane & 15)][koff];
            #pragma unroll
            for (int i = 0; i < 4; i++)
                #pragma unroll
                for (int j = 0; j < 4; j++)
                    acc[i][j] = __builtin_amdgcn_mfma_f32_16x16x32_bf16(af[i], bfr[j], acc[i][j], 0, 0, 0);
        }
        __syncthreads();
    }
    const int cmb = wr * 64 + ((lane >> 4) << 2);
    const int cnb = wc * 64 + (lane & 15);
    #pragma unroll
    for (int i = 0; i < 4; i++) {
        #pragma unroll
        for (int j = 0; j < 4; j++) {
            const int gn = n0 + cnb + j * 16;
            #pragma unroll
            for (int rr = 0; rr < 4; rr++) {
                const int gm = m0 + cmb + i * 16 + rr;
                float v = acc[i][j][rr];
                if (MODE == 0) {
                    v += bias[gn];
                    if (EPI == 1) v = fmaxf(v, 0.f);
                    ((float*)Cp)[(long long)gm * N + gn] = v;
                } else {
                    if (gm < M) {
                        v += bias[gm];
                        const int b = gn / LIN, l = gn - b * LIN;
                        ((unsigned short*)Cp)[((long long)b * COUT + gm) * LIN + l] = f2bf(v);
                    }
                }
            }
        }
    }
}

// ---------------- weight f32 -> bf16 converters ----------------
__global__ void cvt_f2bf(const float* __restrict__ in, unsigned short* __restrict__ out, int n)
{
    int i = (blockIdx.x * 256 + threadIdx.x) * 4;
    if (i + 4 <= n) {
        float4 v = *(const float4*)(in + i);
        ushort4 o; o.x = f2bf(v.x); o.y = f2bf(v.y); o.z = f2bf(v.z); o.w = f2bf(v.w);
        *(ushort4*)(out + i) = o;
    }
}
__global__ void cvt_f2bf_pad(const float* __restrict__ in, unsigned short* __restrict__ out,
                             int rows, int cols, int ldo)
{
    int i = blockIdx.x * 256 + threadIdx.x;
    if (i < rows * ldo) {
        int r = i / ldo, c = i - r * ldo;
        out[i] = (c < cols) ? f2bf(in[r * cols + c]) : (unsigned short)0;
    }
}

// ---------------- fp32 NT GEMM (small/precision-critical) ----------------
template<int EPI>
__global__ __launch_bounds__(256)
void gemm_nt(const float* __restrict__ A, long long sAb, int lda,
             const float* __restrict__ Bm, int ldb,
             const float* __restrict__ bias,
             float* __restrict__ C, long long sCb, int ldc,
             int M, int N, int K)
{
    A += (long long)blockIdx.z * sAb;
    C += (long long)blockIdx.z * sCb;
    const int m0 = blockIdx.y * 64, n0 = blockIdx.x * 64;
    __shared__ float As[16][68];
    __shared__ float Bs[16][68];
    const int tid = threadIdx.x;
    const int lr = tid >> 2, lk = (tid & 3) << 2;
    const int tm = (tid >> 4) << 2, tn = (tid & 15) << 2;
    float acc[4][4] = {};
    for (int k0 = 0; k0 < K; k0 += 16) {
        float4 av = make_float4(0.f, 0.f, 0.f, 0.f);
        {
            int m = m0 + lr;
            if (m < M && k0 + lk < K) av = *(const float4*)(A + (long long)m * lda + k0 + lk);
        }
        float4 bv = make_float4(0.f, 0.f, 0.f, 0.f);
        {
            int n = n0 + lr;
            if (n < N && k0 + lk < K) bv = *(const float4*)(Bm + (long long)n * ldb + k0 + lk);
        }
        As[lk + 0][lr] = av.x; As[lk + 1][lr] = av.y; As[lk + 2][lr] = av.z; As[lk + 3][lr] = av.w;
        Bs[lk + 0][lr] = bv.x; Bs[lk + 1][lr] = bv.y; Bs[lk + 2][lr] = bv.z; Bs[lk + 3][lr] = bv.w;
        __syncthreads();
        #pragma unroll
        for (int kk = 0; kk < 16; kk++) {
            float a0 = As[kk][tm + 0], a1 = As[kk][tm + 1], a2 = As[kk][tm + 2], a3 = As[kk][tm + 3];
            float b0 = Bs[kk][tn + 0], b1 = Bs[kk][tn + 1], b2 = Bs[kk][tn + 2], b3 = Bs[kk][tn + 3];
            acc[0][0] += a0 * b0; acc[0][1] += a0 * b1; acc[0][2] += a0 * b2; acc[0][3] += a0 * b3;
            acc[1][0] += a1 * b0; acc[1][1] += a1 * b1; acc[1][2] += a1 * b2; acc[1][3] += a1 * b3;
            acc[2][0] += a2 * b0; acc[2][1] += a2 * b1; acc[2][2] += a2 * b2; acc[2][3] += a2 * b3;
            acc[3][0] += a3 * b0; acc[3][1] += a3 * b1; acc[3][2] += a3 * b2; acc[3][3] += a3 * b3;
        }
        __syncthreads();
    }
    #pragma unroll
    for (int i = 0; i < 4; i++) {
        int m = m0 + tm + i; if (m >= M) continue;
        #pragma unroll
        for (int j = 0; j < 4; j++) {
            int n = n0 + tn + j; if (n >= N) continue;
            float v = acc[i][j];
            if (bias) v += bias[n];
            if (EPI == 1) v = fmaxf(v, 0.f);
            if (EPI == 2) v = 1.f / (1.f + expf(-v));
            C[(long long)m * ldc + n] = v;
        }
    }
}

// ---------------- transpose: in[b][D][N] -> out[b][N][D] ----------------
__global__ void transpose_kernel(const float* __restrict__ in, float* __restrict__ out,
                                 int D, int N)
{
    __shared__ float tile[32][33];
    int b = blockIdx.z;
    int d0 = blockIdx.y * 32, n0 = blockIdx.x * 32;
    int tx = threadIdx.x, ty = threadIdx.y;
    for (int i = 0; i < 32; i += 8) {
        int d = d0 + ty + i, n = n0 + tx;
        if (d < D && n < N) tile[ty + i][tx] = in[((long long)b * D + d) * N + n];
    }
    __syncthreads();
    for (int i = 0; i < 32; i += 8) {
        int n = n0 + ty + i, d = d0 + tx;
        if (n < N && d < D) out[((long long)b * N + n) * D + d] = tile[tx][ty + i];
    }
}

// ---------------- audio[b][d] = mean_m vtf[b][m][d]  (grid 3 x B) -------------
__global__ void audio_kernel(const float* __restrict__ vtf, float* __restrict__ audio)
{
    int b = blockIdx.y, d = blockIdx.x * 256 + threadIdx.x;
    float s = 0.f;
    for (int m = 0; m < COUT; m++) s += vtf[((long long)b * COUT + m) * DD0 + d];
    audio[b * DD0 + d] = s * (1.f / (float)COUT);
}

// ========== att1 scores: P[b][t][m] = softmax_m(mt[t]·vtf[b][m]) (bf16, K-pad 224) ====
__global__ __launch_bounds__(256)
void att1_scores(const float* __restrict__ vtf, const float* __restrict__ mt,
                 unsigned short* __restrict__ pbuf)
{
    __shared__ float sc[TT][208];
    const int b = blockIdx.x;
    const int tid = threadIdx.x, w = tid >> 6, lane = tid & 63;
    const int l15 = lane & 15, kg = (lane >> 4) << 3;
    const float* vb = vtf + (long long)b * COUT * DD0;

    f32x4 acc[4][2];
    #pragma unroll
    for (int q = 0; q < 4; q++) { acc[q][0] = (f32x4){0.f,0.f,0.f,0.f}; acc[q][1] = (f32x4){0.f,0.f,0.f,0.f}; }

    for (int kt = 0; kt < DD0; kt += 32) {
        const float* a0p = mt + (long long)l15 * DD0 + kt + kg;
        const float* a1p = a0p + 16 * DD0;
        short8 a0 = cvt8(*(const float4*)a0p, *(const float4*)(a0p + 4));
        short8 a1 = cvt8(*(const float4*)a1p, *(const float4*)(a1p + 4));
        #pragma unroll
        for (int q = 0; q < 4; q++) {
            const int mtile = w + q * 4;           // up to 15; >=13 is padding work
            const int gm = mtile * 16 + l15;
            short8 bf = {0,0,0,0,0,0,0,0};
            if (gm < COUT) {
                const float* bp = vb + (long long)gm * DD0 + kt + kg;
                bf = cvt8(*(const float4*)bp, *(const float4*)(bp + 4));
            }
            acc[q][0] = __builtin_amdgcn_mfma_f32_16x16x32_bf16(a0, bf, acc[q][0], 0, 0, 0);
            acc[q][1] = __builtin_amdgcn_mfma_f32_16x16x32_bf16(a1, bf, acc[q][1], 0, 0, 0);
        }
    }
    #pragma unroll
    for (int q = 0; q < 4; q++) {
        const int mtile = w + q * 4;
        if (mtile < 13) {
            #pragma unroll
            for (int j = 0; j < 2; j++)
                #pragma unroll
                for (int r = 0; r < 4; r++)
                    sc[j * 16 + ((lane >> 4) << 2) + r][mtile * 16 + l15] = acc[q][j][r];
        }
    }
    __syncthreads();
    // wave-parallel softmax over m (196), rows w*8..w*8+7
    for (int tr = 0; tr < 8; tr++) {
        const int t = w * 8 + tr;
        float v = -1e30f;
        for (int m = lane; m < COUT; m += 64) v = fmaxf(v, sc[t][m]);
        v = wave_allmax(v);
        float s = 0.f;
        for (int m = lane; m < COUT; m += 64) { float e = __expf(sc[t][m] - v); sc[t][m] = e; s += e; }
        s = wave_allsum(s);
        const float inv = 1.f / s;
        unsigned short* pr = pbuf + ((long long)b * TT + t) * 224;
        for (int m = lane; m < 224; m += 64) pr[m] = (m < COUT) ? f2bf(sc[t][m] * inv) : (unsigned short)0;
    }
}

// ========== att1 PV: rep[b][t][d] = mt[t][d] + sum_m P[t][m]·vtf[b][m][d] ==========
__global__ __launch_bounds__(256)
void att1_pv(const float* __restrict__ vtf, const unsigned short* __restrict__ pbuf,
             const float* __restrict__ mt, float* __restrict__ rep)
{
    __shared__ unsigned short vT[128][36];
    const int b = blockIdx.y, d0 = blockIdx.x * 128;
    const int tid = threadIdx.x, w = tid >> 6, lane = tid & 63;
    const int l15 = lane & 15, kg = (lane >> 4) << 3;
    const float* vb = vtf + (long long)b * COUT * DD0;

    f32x4 acc[2][2];
    acc[0][0] = (f32x4){0.f,0.f,0.f,0.f}; acc[0][1] = (f32x4){0.f,0.f,0.f,0.f};
    acc[1][0] = (f32x4){0.f,0.f,0.f,0.f}; acc[1][1] = (f32x4){0.f,0.f,0.f,0.f};

    for (int kc = 0; kc < 7; kc++) {
        for (int i = tid; i < 32 * 128; i += 256) {
            const int m = i >> 7, dd = i & 127;
            const int gm = kc * 32 + m;
            const float v = (gm < COUT) ? vb[(long long)gm * DD0 + d0 + dd] : 0.f;
            vT[dd][m] = f2bf(v);
        }
        const short8 p0 = *(const short8*)(pbuf + ((long long)b * TT + l15) * 224 + kc * 32 + kg);
        const short8 p1 = *(const short8*)(pbuf + ((long long)b * TT + 16 + l15) * 224 + kc * 32 + kg);
        __syncthreads();
        #pragma unroll
        for (int jl = 0; jl < 2; jl++) {
            const short8 bf = lds_frag(&vT[(w * 2 + jl) * 16 + l15][kg]);
            acc[0][jl] = __builtin_amdgcn_mfma_f32_16x16x32_bf16(p0, bf, acc[0][jl], 0, 0, 0);
            acc[1][jl] = __builtin_amdgcn_mfma_f32_16x16x32_bf16(p1, bf, acc[1][jl], 0, 0, 0);
        }
        __syncthreads();
    }
    #pragma unroll
    for (int j = 0; j < 2; j++) {
        #pragma unroll
        for (int jl = 0; jl < 2; jl++) {
            const int t = j * 16 + ((lane >> 4) << 2);
            const int gd = d0 + (w * 2 + jl) * 16 + l15;
            #pragma unroll
            for (int r = 0; r < 4; r++)
                rep[((long long)b * TT + t + r) * DD0 + gd] = mt[(long long)(t + r) * DD0 + gd] + acc[j][jl][r];
        }
    }
}

// ========== att2 fused: xT[n] += gate_av * softmax_t(xT[n]·rep[t]) @ rep ==========
__global__ __launch_bounds__(256)
void att2_mfma(const float* __restrict__ rep, const float* __restrict__ gav,
               float* __restrict__ xT)
{
    __shared__ unsigned short repT[DD0][36];
    __shared__ unsigned short Pl[64][36];
    const int b = blockIdx.y, m0 = blockIdx.x * 64;
    const int tid = threadIdx.x, w = tid >> 6, lane = tid & 63;
    const int l15 = lane & 15, kg = (lane >> 4) << 3;
    const float* repb = rep + (long long)b * TT * DD0;

    for (int i = tid; i < TT * DD0; i += 256) {
        const int t = i / DD0, d = i - t * DD0;
        repT[d][t] = f2bf(repb[i]);
    }
    __syncthreads();

    // scores: D[m][t], A = xT rows, B = rep rows (from global, L2-hot)
    f32x4 acc0 = (f32x4){0.f,0.f,0.f,0.f}, acc1 = (f32x4){0.f,0.f,0.f,0.f};
    const int arow = m0 + w * 16 + l15;
    const bool rok = arow < NN;
    const float* xrow = xT + ((long long)b * NN + arow) * DD0;
    for (int kt = 0; kt < DD0; kt += 32) {
        short8 af = {0,0,0,0,0,0,0,0};
        if (rok) af = cvt8(*(const float4*)(xrow + kt + kg), *(const float4*)(xrow + kt + kg + 4));
        const float* r0 = repb + (long long)l15 * DD0 + kt + kg;
        const float* r1 = r0 + 16 * DD0;
        const short8 b0 = cvt8(*(const float4*)r0, *(const float4*)(r0 + 4));
        const short8 b1 = cvt8(*(const float4*)r1, *(const float4*)(r1 + 4));
        acc0 = __builtin_amdgcn_mfma_f32_16x16x32_bf16(af, b0, acc0, 0, 0, 0);
        acc1 = __builtin_amdgcn_mfma_f32_16x16x32_bf16(af, b1, acc1, 0, 0, 0);
    }
    // row softmax over 32 t (16-lane col group reduce)
    #pragma unroll
    for (int r = 0; r < 4; r++) {
        float m = fmaxf(acc0[r], acc1[r]);
        m = fmaxf(m, __shfl_xor(m, 1, 64));
        m = fmaxf(m, __shfl_xor(m, 2, 64));
        m = fmaxf(m, __shfl_xor(m, 4, 64));
        m = fmaxf(m, __shfl_xor(m, 8, 64));
        const float e0 = __expf(acc0[r] - m), e1 = __expf(acc1[r] - m);
        float s = e0 + e1;
        s += __shfl_xor(s, 1, 64); s += __shfl_xor(s, 2, 64);
        s += __shfl_xor(s, 4, 64); s += __shfl_xor(s, 8, 64);
        const float inv = 1.f / s;
        const int prow = w * 16 + ((lane >> 4) << 2) + r;
        Pl[prow][l15] = f2bf(e0 * inv);
        Pl[prow][l15 + 16] = f2bf(e1 * inv);
    }
    __syncthreads();
    // PV: out[m][d] = sum_t P[m][t]·rep[t][d]; xT += ga*out
    const short8 pa = lds_frag(&Pl[w * 16 + l15][kg]);
    const float ga = gav[0];
    const int gmb = m0 + w * 16 + ((lane >> 4) << 2);
    for (int jd = 0; jd < 48; jd++) {
        const short8 bf = lds_frag(&repT[jd * 16 + l15][kg]);
        f32x4 av = (f32x4){0.f,0.f,0.f,0.f};
        av = __builtin_amdgcn_mfma_f32_16x16x32_bf16(pa, bf, av, 0, 0, 0);
        const int gd = jd * 16 + l15;
        #pragma unroll
        for (int r = 0; r < 4; r++) {
            if (gmb + r < NN) {
                const long long idx = ((long long)b * NN + gmb + r) * DD0 + gd;
                xT[idx] += ga * av[r];
            }
        }
    }
}

// ---------------- mvq[b][d] = aq1[b][d] * mean_n vq1[b][n][d]  (grid 3 x B) ----
__global__ void mvq_kernel(const float* __restrict__ vq1, const float* __restrict__ aq1,
                           float* __restrict__ mvq)
{
    int b = blockIdx.y, d = blockIdx.x * 256 + threadIdx.x;
    float s = 0.f;
    for (int n = 0; n < NN; n++) s += vq1[((long long)b * NN + n) * DD0 + d];
    mvq[b * DD0 + d] = aq1[b * DD0 + d] * s * (1.f / (float)NN);
}

// ---------------- s_tmp -> s_sig + sp_att ----------------
__global__ __launch_bounds__(256)
void stmp_kernel(const float* __restrict__ cq, const float* __restrict__ aq2,
                 const float* __restrict__ vsw, const float* __restrict__ vsb,
                 float* __restrict__ ssig, float* __restrict__ spatt)
{
    int b = blockIdx.x, tid = threadIdx.x;
    __shared__ float wv[DM];
    __shared__ float st[NN];
    __shared__ float sb[4];
    for (int i = tid; i < DM; i += 256) wv[i] = aq2[b * DM + i] * vsw[i];
    __syncthreads();
    float vb = vsb[0];
    for (int n = tid; n < NN; n += 256) {
        const float* cr = cq + ((long long)b * NN + n) * DM;
        float s = vb;
        for (int d = 0; d < DM; d++) s += cr[d] * wv[d];
        st[n] = tanhf(s);
        ssig[b * NN + n] = 1.f / (1.f + expf(-s));
    }
    __syncthreads();
    float lm = -1e30f;
    for (int n = tid; n < NN; n += 256) lm = fmaxf(lm, st[n]);
    float mx = block_max256(lm, sb);
    float ls = 0.f;
    for (int n = tid; n < NN; n += 256) { float e = expf(st[n] - mx); st[n] = e; ls += e; }
    float s = block_sum256(ls, sb);
    float inv = 1.f / s;
    for (int n = tid; n < NN; n += 256) spatt[b * NN + n] = st[n] * inv;
}

// ---------------- gating scale + LayerNorm (lnb) in place on xT ----------------
__global__ __launch_bounds__(256)
void scale_ln_kernel(float* __restrict__ xT, const float* __restrict__ chatt,
                     const float* __restrict__ ssig, const float* __restrict__ g,
                     const float* __restrict__ bb)
{
    int b = blockIdx.y, n = blockIdx.x, tid = threadIdx.x;
    __shared__ float sb[4];
    float* xr = xT + ((long long)b * NN + n) * DD0;
    float ss = ssig[b * NN + n];
    float v[3];
    float lsum = 0.f;
    #pragma unroll
    for (int i = 0; i < 3; i++) {
        int d = tid + i * 256;
        float sc = 0.3f * chatt[b * DD0 + d] + 0.05f * ss + 0.7f;
        v[i] = xr[d] * sc;
        lsum += v[i];
    }
    float mean = block_sum256(lsum, sb) * (1.f / (float)DD0);
    float lvar = 0.f;
    #pragma unroll
    for (int i = 0; i < 3; i++) { float dd = v[i] - mean; lvar += dd * dd; }
    float var = block_sum256(lvar, sb) * (1.f / (float)DD0);
    float inv = rsqrtf(var + EPS);
    #pragma unroll
    for (int i = 0; i < 3; i++) {
        int d = tid + i * 256;
        xr[d] = (v[i] - mean) * inv * g[d] + bb[d];
    }
}

// ---------------- BN stats ----------------
__global__ void bn1stats_kernel(const float* __restrict__ y1, float* __restrict__ stats)
{
    int b = blockIdx.x, tid = threadIdx.x;
    if (tid < DDB) {
        float s = 0.f, q = 0.f;
        for (int n = 0; n < NN; n++) {
            float v = y1[((long long)b * NN + n) * DDB + tid];
            s += v; q += v * v;
        }
        atomicAdd(&stats[tid], s);
        atomicAdd(&stats[DDB + tid], q);
    }
}

__global__ void bn1apply_kernel(float* __restrict__ y1, const float* __restrict__ stats,
                                const float* __restrict__ g, const float* __restrict__ bb)
{
    long long i = (long long)blockIdx.x * 256 + threadIdx.x;
    if (i >= (long long)BB * NN * DDB) return;
    int e = (int)(i % DDB);
    const float cnt = (float)(BB * NN);
    float mu = stats[e] / cnt;
    float var = stats[DDB + e] / cnt - mu * mu;
    float v = (y1[i] - mu) * rsqrtf(var + EPS) * g[e] + bb[e];
    y1[i] = fmaxf(v, 0.f);
}

__global__ void bn2stats_kernel(const float* __restrict__ y2, float* __restrict__ stats)
{
    int b = blockIdx.y, d = blockIdx.x * 256 + threadIdx.x;
    float s = 0.f, q = 0.f;
    for (int n = 0; n < NN; n++) {
        float v = y2[((long long)b * NN + n) * DD0 + d];
        s += v; q += v * v;
    }
    atomicAdd(&stats[d], s);
    atomicAdd(&stats[DD0 + d], q);
}

// ---------------- BN2 + LN(lnp) + gate -> out_tmp[b][n][d] ----------------
__global__ __launch_bounds__(256)
void final_kernel(const float* __restrict__ y2, const float* __restrict__ stats2,
                  const float* __restrict__ g2, const float* __restrict__ b2,
                  const float* __restrict__ lg, const float* __restrict__ lb,
                  const float* __restrict__ gate, float* __restrict__ out_tmp)
{
    int b = blockIdx.y, n = blockIdx.x, tid = threadIdx.x;
    __shared__ float sb[4];
    const float* yr = y2 + ((long long)b * NN + n) * DD0;
    const float cnt = (float)(BB * NN);
    float v[3];
    float lsum = 0.f;
    #pragma unroll
    for (int i = 0; i < 3; i++) {
        int d = tid + i * 256;
        float mu = stats2[d] / cnt;
        float var = stats2[DD0 + d] / cnt - mu * mu;
        v[i] = (yr[d] - mu) * rsqrtf(var + EPS) * g2[d] + b2[d];
        lsum += v[i];
    }
    float mean = block_sum256(lsum, sb) * (1.f / (float)DD0);
    float lvar = 0.f;
    #pragma unroll
    for (int i = 0; i < 3; i++) { float dd = v[i] - mean; lvar += dd * dd; }
    float var = block_sum256(lvar, sb) * (1.f / (float)DD0);
    float inv = rsqrtf(var + EPS);
    float gt = gate[0];
    float* orow = out_tmp + ((long long)b * NN + n) * DD0;
    #pragma unroll
    for (int i = 0; i < 3; i++) {
        int d = tid + i * 256;
        orow[d] = ((v[i] - mean) * inv * lg[d] + lb[d]) * gt;
    }
}

// ======================= launch =======================
extern "C" void kernel_launch(void* const* d_in, const int* in_sizes, int n_in,
                              void* d_out, int out_size, void* d_ws, size_t ws_size,
                              hipStream_t stream)
{
    const float* x       = (const float*)d_in[0];
    const float* vis     = (const float*)d_in[1];
    const float* conv_w  = (const float*)d_in[2];
    const float* conv_b  = (const float*)d_in[3];
    const float* fc_w    = (const float*)d_in[4];
    const float* fc_b    = (const float*)d_in[5];
    const float* a1_w    = (const float*)d_in[6];
    const float* a1_b    = (const float*)d_in[7];
    const float* v1_w    = (const float*)d_in[8];
    const float* v1_b    = (const float*)d_in[9];
    const float* btl_w   = (const float*)d_in[10];
    const float* btl_b   = (const float*)d_in[11];
    const float* v2_w    = (const float*)d_in[12];
    const float* v2_b    = (const float*)d_in[13];
    const float* a2_w    = (const float*)d_in[14];
    const float* a2_b    = (const float*)d_in[15];
    const float* vs_w    = (const float*)d_in[16];
    const float* vs_b    = (const float*)d_in[17];
    const float* vc_w    = (const float*)d_in[18];
    const float* vc_b    = (const float*)d_in[19];
    const float* my_tok  = (const float*)d_in[20];
    const float* gate_av = (const float*)d_in[21];
    const float* gate    = (const float*)d_in[22];
    const float* down_w  = (const float*)d_in[23];
    const float* up_w    = (const float*)d_in[24];
    const float* bn1_g   = (const float*)d_in[25];
    const float* bn1_b   = (const float*)d_in[26];
    const float* bn2_g   = (const float*)d_in[27];
    const float* bn2_b   = (const float*)d_in[28];
    const float* lnb_g   = (const float*)d_in[29];
    const float* lnb_b   = (const float*)d_in[30];
    const float* lnp_g   = (const float*)d_in[31];
    const float* lnp_b   = (const float*)d_in[32];

    float* ws = (float*)d_ws;
    unsigned short* vtc_bf = (unsigned short*)(ws + OFF_A);
    float* vq1     = ws + OFF_A;
    float* cq      = ws + OFF_A;
    float* y2      = ws + OFF_A;
    float* vtf     = ws + OFF_B;
    float* out_tmp = ws + OFF_B;
    float* xT      = ws + OFF_XT;
    float* rep     = ws + OFF_REP;
    float* y1      = ws + OFF_Y1;
    unsigned short* wconv = (unsigned short*)(ws + OFF_WCONV);
    unsigned short* wfc   = (unsigned short*)(ws + OFF_WFC);
    unsigned short* wv1   = (unsigned short*)(ws + OFF_WV1);
    unsigned short* wv2   = (unsigned short*)(ws + OFF_WV2);
    float* audio   = ws + OFF_AUDIO;
    float* aq1b    = ws + OFF_AQ1;
    float* mvqb    = ws + OFF_MVQ;
    float* avqb    = ws + OFF_AVQ;
    float* chattb  = ws + OFF_CHATT;
    float* aq2b    = ws + OFF_AQ2;
    float* ssigb   = ws + OFF_SSIG;
    float* stats1  = ws + OFF_STATS;
    float* stats2  = ws + OFF_STATS + 2 * DDB;
    unsigned short* pbuf = (unsigned short*)(ws + OFF_PBUF);

    float* out   = (float*)d_out;
    float* spatt = out + (long long)BB * DD0 * NN;

    hipMemsetAsync(stats1, 0, (2 * DDB + 2 * DD0) * sizeof(float), stream);

    // 0. weight conversions (f32 -> bf16)
    cvt_f2bf<<<(DD0 * LIN / 4 + 255) / 256, 256, 0, stream>>>(fc_w, wfc, DD0 * LIN);
    cvt_f2bf<<<(DD0 * DD0 / 4 + 255) / 256, 256, 0, stream>>>(v1_w, wv1, DD0 * DD0);
    cvt_f2bf<<<(DM * DD0 / 4 + 255) / 256, 256, 0, stream>>>(v2_w, wv2, DM * DD0);
    cvt_f2bf_pad<<<(COUT * 200 + 255) / 256, 256, 0, stream>>>(conv_w, wconv, COUT, CIN, 200);

    // 1. x -> xT
    transpose_kernel<<<dim3(7, 24, BB), dim3(32, 8), 0, stream>>>(x, xT, DD0, NN);
    // 2. conv (MFMA) -> vtc_bf
    gemm_mfma<1, true, false, false, 0><<<dim3(NCONV / 128, 2), 256, 0, stream>>>(
        wconv, 200, vis, CIN, conv_b, nullptr, vtc_bf, COUT, NCONV, CIN);
    // 3. fc (MFMA) -> vtf f32
    gemm_mfma<0, true, true, false, 0><<<dim3(DD0 / 128, MFLAT / 128), 256, 0, stream>>>(
        vtc_bf, LIN, wfc, LIN, fc_b, nullptr, vtf, MFLAT, DD0, LIN);
    // 4. audio
    audio_kernel<<<dim3(3, BB), 256, 0, stream>>>(vtf, audio);
    // 5. att1 (MFMA): scores+softmax -> pbuf; PV -> rep
    att1_scores<<<BB, 256, 0, stream>>>(vtf, my_tok, pbuf);
    att1_pv<<<dim3(6, BB), 256, 0, stream>>>(vtf, pbuf, my_tok, rep);
    // 6. att2 (MFMA, fused) in place on xT
    att2_mfma<<<dim3(4, BB), 256, 0, stream>>>(rep, gate_av, xT);
    // 7. aq1 = relu(audio@a1^T+b) fp32
    gemm_nt<1><<<dim3(12, 1, 1), 256, 0, stream>>>(
        audio, 0, DD0, a1_w, DD0, a1_b, aq1b, 0, DD0, BB, DD0, DD0);
    // 8. vq1 (MFMA) relu
    gemm_mfma<0, false, true, false, 1><<<dim3(DD0 / 128, MFLAT / 128), 256, 0, stream>>>(
        xT, DD0, wv1, DD0, v1_b, nullptr, vq1, MFLAT, DD0, DD0);
    // 9. mvq
    mvq_kernel<<<dim3(3, BB), 256, 0, stream>>>(vq1, aq1b, mvqb);
    // 10. avq fp32
    gemm_nt<1><<<dim3(6, 1, 1), 256, 0, stream>>>(
        mvqb, 0, DD0, btl_w, DD0, btl_b, avqb, 0, DM, BB, DM, DD0);
    // 11. ch_att fp32
    gemm_nt<2><<<dim3(12, 1, 1), 256, 0, stream>>>(
        avqb, 0, DM, vc_w, DM, vc_b, chattb, 0, DD0, BB, DD0, DM);
    // 12. aq2 fp32
    gemm_nt<1><<<dim3(6, 1, 1), 256, 0, stream>>>(
        audio, 0, DD0, a2_w, DD0, a2_b, aq2b, 0, DM, BB, DM, DD0);
    // 13. c_q (MFMA) relu, k-scale
    gemm_mfma<0, false, true, true, 1><<<dim3(DM / 128, MFLAT / 128), 256, 0, stream>>>(
        xT, DD0, wv2, DD0, v2_b, chattb, cq, MFLAT, DM, DD0);
    // 14. s_tmp / s_sig / sp_att
    stmp_kernel<<<BB, 256, 0, stream>>>(cq, aq2b, vs_w, vs_b, ssigb, spatt);
    // 15. scale + ln_before
    scale_ln_kernel<<<dim3(NN, BB), 256, 0, stream>>>(xT, chattb, ssigb, lnb_g, lnb_b);
    // 16. down fp32
    gemm_nt<0><<<dim3(2, 4, BB), 256, 0, stream>>>(
        xT, (long long)NN * DD0, DD0, down_w, DD0, nullptr,
        y1, (long long)NN * DDB, DDB, NN, DDB, DD0);
    // 17-18. BN1
    bn1stats_kernel<<<BB, 128, 0, stream>>>(y1, stats1);
    bn1apply_kernel<<<(BB * NN * DDB + 255) / 256, 256, 0, stream>>>(y1, stats1, bn1_g, bn1_b);
    // 19. up fp32
    gemm_nt<0><<<dim3(12, 4, BB), 256, 0, stream>>>(
        y1, (long long)NN * DDB, DDB, up_w, DDB, nullptr,
        y2, (long long)NN * DD0, DD0, NN, DD0, DDB);
    // 20. BN2 stats
    bn2stats_kernel<<<dim3(3, BB), 256, 0, stream>>>(y2, stats2);
    // 21. BN2 + LN + gate
    final_kernel<<<dim3(NN, BB), 256, 0, stream>>>(y2, stats2, bn2_g, bn2_b,
                                                   lnp_g, lnp_b, gate, out_tmp);
    // 22. out_tmp -> out
    transpose_kernel<<<dim3(24, 7, BB), dim3(32, 8), 0, stream>>>(out_tmp, out, NN, DD0);
}

// Round 6
// 982.749 us; speedup vs baseline: 2.5581x; 1.1713x over previous
//
#include <hip/hip_runtime.h>
#include <math.h>

// ---- problem constants ----
#define BB 64
#define DD0 768
#define NN 196
#define LIN 1536
#define CIN 196
#define COUT 196
#define TT 32
#define DM 384
#define DDB 96
#define EPS 1e-5f
#define MFLAT (BB * NN)          // 12544
#define NCONV (BB * LIN)         // 98304

// ---- workspace layout (float offsets) ----
#define OFF_A     0LL            // vtc_bf16 -> vq1 f32 -> cq f32 -> y2 f32
#define OFF_B     9633792LL      // vtf f32 -> out_tmp f32
#define OFF_XT    19267584LL     // xT f32
#define OFF_REP   28901376LL     // rep f32
#define OFF_Y1    30474240LL     // y1 f32
#define OFF_WCONV 31678464LL     // 196x200 ushort padded
#define OFF_WFC   31698064LL     // 768x1536 ushort
#define OFF_WV1   32287888LL     // 768x768  ushort
#define OFF_WV2   32582800LL     // 384x768  ushort
#define OFF_SM    32730256LL
#define OFF_AUDIO (OFF_SM)
#define OFF_AQ1   (OFF_SM+49152)
#define OFF_MVQ   (OFF_SM+98304)
#define OFF_AVQ   (OFF_SM+147456)
#define OFF_CHATT (OFF_SM+172032)
#define OFF_AQ2   (OFF_SM+221184)
#define OFF_SSIG  (OFF_SM+245760)
#define OFF_STATS (OFF_SM+258304)
#define OFF_PBUF  (OFF_SM+262144)   // att1 P: 64*32*224 ushort = 229376 f
#define OFF_WDOWN (OFF_SM+491520)   // 96x768 ushort = 36864 f
#define OFF_WUP   (OFF_SM+528384)   // 768x96 ushort = 36864 f

typedef __attribute__((ext_vector_type(8))) short short8;
typedef __attribute__((ext_vector_type(4))) float f32x4;

__device__ __forceinline__ unsigned short f2bf(float f) {
    union { float f; unsigned u; } v; v.f = f;
    unsigned r = v.u + 0x7fffu + ((v.u >> 16) & 1u);
    return (unsigned short)(r >> 16);
}
__device__ __forceinline__ short8 cvt8(const float4 a, const float4 b) {
    short8 r;
    r[0] = (short)f2bf(a.x); r[1] = (short)f2bf(a.y); r[2] = (short)f2bf(a.z); r[3] = (short)f2bf(a.w);
    r[4] = (short)f2bf(b.x); r[5] = (short)f2bf(b.y); r[6] = (short)f2bf(b.z); r[7] = (short)f2bf(b.w);
    return r;
}
__device__ __forceinline__ short8 lds_frag(const unsigned short* p) {
    short4 lo = *(const short4*)p;
    short4 hi = *(const short4*)(p + 4);
    short8 r;
    r[0] = lo.x; r[1] = lo.y; r[2] = lo.z; r[3] = lo.w;
    r[4] = hi.x; r[5] = hi.y; r[6] = hi.z; r[7] = hi.w;
    return r;
}

// ---------------- reduction helpers ----------------
__device__ __forceinline__ float warp_sum(float v) {
    for (int o = 32; o; o >>= 1) v += __shfl_down(v, o, 64);
    return v;
}
__device__ __forceinline__ float wave_allsum(float v) {
    for (int o = 1; o < 64; o <<= 1) v += __shfl_xor(v, o, 64);
    return v;
}
__device__ __forceinline__ float wave_allmax(float v) {
    for (int o = 1; o < 64; o <<= 1) v = fmaxf(v, __shfl_xor(v, o, 64));
    return v;
}
__device__ __forceinline__ float warp_max(float v) {
    for (int o = 32; o; o >>= 1) v = fmaxf(v, __shfl_down(v, o, 64));
    return v;
}
__device__ __forceinline__ float block_sum256(float v, float* sb) {
    v = warp_sum(v);
    __syncthreads();
    if ((threadIdx.x & 63) == 0) sb[threadIdx.x >> 6] = v;
    __syncthreads();
    return sb[0] + sb[1] + sb[2] + sb[3];
}
__device__ __forceinline__ float block_max256(float v, float* sb) {
    v = warp_max(v);
    __syncthreads();
    if ((threadIdx.x & 63) == 0) sb[threadIdx.x >> 6] = v;
    __syncthreads();
    return fmaxf(fmaxf(sb[0], sb[1]), fmaxf(sb[2], sb[3]));
}

// ================= bf16 MFMA GEMM, coalesced staging =================
// C[m][n] = epi(sum_k A[m][k]*B[n][k] + bias)
// Tile 128x128xBK64, 256 threads = 4 waves (2x2), 16x16x32 MFMA, fp32 accum.
// MODE 0: fp32 C [M][N] (ldc=N), bias on N (nullable). MODE 1: conv scatter, bf16 C, bias on M.
// ABF/BBF: operand is bf16 else fp32 (converted at stage).  KSC: A k-scale (ch_att+1).
// NG: guard N tail (B-stage + epilogue).  Ka: A load-guard K (conv pads to 200).
// Staging is lane-contiguous: bf16 row = q*32+(tid>>3), 16B at col (tid&7)*8  -> 8x128B/wave
//                             f32  row = q*16+(tid>>4), 16B at col (tid&15)*4 -> 4x256B/wave
template<int MODE, bool ABF, bool BBF, bool KSC, int EPI, bool NG>
__global__ __launch_bounds__(256)
void gemm_mfma(const void* __restrict__ Ap, int lda,
               const void* __restrict__ Bp, int ldb,
               const float* __restrict__ bias, const float* __restrict__ ksc,
               void* __restrict__ Cp, int M, int N, int K, int Ka)
{
    __shared__ unsigned short Asm[128][72];
    __shared__ unsigned short Bsm[128][72];
    const int tid = threadIdx.x;
    const int m0 = blockIdx.y * 128, n0 = blockIdx.x * 128;
    const int w = tid >> 6, lane = tid & 63;
    const int wr = w >> 1, wc = w & 1;

    f32x4 acc[4][4];
    #pragma unroll
    for (int i = 0; i < 4; i++)
        #pragma unroll
        for (int j = 0; j < 4; j++) acc[i][j] = (f32x4){0.f, 0.f, 0.f, 0.f};

    const int nkt = (K + 63) >> 6;
    for (int kt = 0; kt < nkt; kt++) {
        const int k0 = kt << 6;
        // ---- stage A ----
        if (ABF) {
            #pragma unroll
            for (int q = 0; q < 4; q++) {
                const int row = q * 32 + (tid >> 3);
                const int ce = (tid & 7) * 8;
                const int gm = m0 + row;
                const bool rok = (MODE == 1) ? (gm < M) : true;
                uint4 u = make_uint4(0u, 0u, 0u, 0u);
                if (rok && (k0 + ce) < Ka)
                    u = *(const uint4*)((const unsigned short*)Ap + (long long)gm * lda + k0 + ce);
                *(uint4*)&Asm[row][ce] = u;
            }
        } else {
            #pragma unroll
            for (int q = 0; q < 8; q++) {
                const int row = q * 16 + (tid >> 4);
                const int ce = (tid & 15) * 4;
                const int gm = m0 + row;
                const bool rok = (MODE == 1) ? (gm < M) : true;
                float4 v = make_float4(0.f, 0.f, 0.f, 0.f);
                const bool kok = (k0 + ce) < K;
                if (rok && kok)
                    v = *(const float4*)((const float*)Ap + (long long)gm * lda + k0 + ce);
                if (KSC && kok) {
                    const float* kc = ksc + (gm / 196) * 768 + k0 + ce;
                    v.x *= kc[0] + 1.f; v.y *= kc[1] + 1.f;
                    v.z *= kc[2] + 1.f; v.w *= kc[3] + 1.f;
                }
                ushort4 o; o.x = f2bf(v.x); o.y = f2bf(v.y); o.z = f2bf(v.z); o.w = f2bf(v.w);
                *(ushort4*)&Asm[row][ce] = o;
            }
        }
        // ---- stage B ----
        if (BBF) {
            #pragma unroll
            for (int q = 0; q < 4; q++) {
                const int row = q * 32 + (tid >> 3);
                const int ce = (tid & 7) * 8;
                const int gn = n0 + row;
                const bool nok = NG ? (gn < N) : true;
                uint4 u = make_uint4(0u, 0u, 0u, 0u);
                if (nok && (k0 + ce) < K)
                    u = *(const uint4*)((const unsigned short*)Bp + (long long)gn * ldb + k0 + ce);
                *(uint4*)&Bsm[row][ce] = u;
            }
        } else {
            #pragma unroll
            for (int q = 0; q < 8; q++) {
                const int row = q * 16 + (tid >> 4);
                const int ce = (tid & 15) * 4;
                const int gn = n0 + row;
                const bool nok = NG ? (gn < N) : true;
                float4 v = make_float4(0.f, 0.f, 0.f, 0.f);
                if (nok && (k0 + ce) < K)
                    v = *(const float4*)((const float*)Bp + (long long)gn * ldb + k0 + ce);
                ushort4 o; o.x = f2bf(v.x); o.y = f2bf(v.y); o.z = f2bf(v.z); o.w = f2bf(v.w);
                *(ushort4*)&Bsm[row][ce] = o;
            }
        }
        __syncthreads();
        // ---- MFMA ----
        #pragma unroll
        for (int kk = 0; kk < 2; kk++) {
            short8 af[4], bfr[4];
            const int koff = kk * 32 + (lane >> 4) * 8;
            #pragma unroll
            for (int i = 0; i < 4; i++)
                af[i] = *(const short8*)&Asm[wr * 64 + i * 16 + (lane & 15)][koff];
            #pragma unroll
            for (int j = 0; j < 4; j++)
                bfr[j] = *(const short8*)&Bsm[wc * 64 + j * 16 + (lane & 15)][koff];
            #pragma unroll
            for (int i = 0; i < 4; i++)
                #pragma unroll
                for (int j = 0; j < 4; j++)
                    acc[i][j] = __builtin_amdgcn_mfma_f32_16x16x32_bf16(af[i], bfr[j], acc[i][j], 0, 0, 0);
        }
        __syncthreads();
    }
    // ---- epilogue (C/D layout: col=lane&15, row=(lane>>4)*4+rr) ----
    const int cmb = wr * 64 + ((lane >> 4) << 2);
    const int cnb = wc * 64 + (lane & 15);
    #pragma unroll
    for (int i = 0; i < 4; i++) {
        #pragma unroll
        for (int j = 0; j < 4; j++) {
            const int gn = n0 + cnb + j * 16;
            if (NG && gn >= N) continue;
            #pragma unroll
            for (int rr = 0; rr < 4; rr++) {
                const int gm = m0 + cmb + i * 16 + rr;
                float v = acc[i][j][rr];
                if (MODE == 0) {
                    if (bias) v += bias[gn];
                    if (EPI == 1) v = fmaxf(v, 0.f);
                    ((float*)Cp)[(long long)gm * N + gn] = v;
                } else {
                    if (gm < M) {
                        v += bias[gm];
                        const int b = gn / LIN, l = gn - b * LIN;
                        ((unsigned short*)Cp)[((long long)b * COUT + gm) * LIN + l] = f2bf(v);
                    }
                }
            }
        }
    }
}

// ---------------- weight f32 -> bf16 converters ----------------
__global__ void cvt_f2bf(const float* __restrict__ in, unsigned short* __restrict__ out, int n)
{
    int i = (blockIdx.x * 256 + threadIdx.x) * 4;
    if (i + 4 <= n) {
        float4 v = *(const float4*)(in + i);
        ushort4 o; o.x = f2bf(v.x); o.y = f2bf(v.y); o.z = f2bf(v.z); o.w = f2bf(v.w);
        *(ushort4*)(out + i) = o;
    }
}
__global__ void cvt_f2bf_pad(const float* __restrict__ in, unsigned short* __restrict__ out,
                             int rows, int cols, int ldo)
{
    int i = blockIdx.x * 256 + threadIdx.x;
    if (i < rows * ldo) {
        int r = i / ldo, c = i - r * ldo;
        out[i] = (c < cols) ? f2bf(in[r * cols + c]) : (unsigned short)0;
    }
}

// ---------------- wave-per-output GEMV: C[m][n] = act(A[m]·B[n] + bias[n]) ------
template<int ACT>
__global__ __launch_bounds__(256)
void wave_gemv(const float* __restrict__ A, int lda,
               const float* __restrict__ B, int ldb,
               const float* __restrict__ bias,
               float* __restrict__ C, int N, int K)
{
    const int w = threadIdx.x >> 6, lane = threadIdx.x & 63;
    const long long o = (long long)blockIdx.x * 4 + w;
    const int m = (int)(o / N), n = (int)(o - (long long)m * N);
    const float* ar = A + (long long)m * lda;
    const float* br = B + (long long)n * ldb;
    float s = 0.f;
    for (int k = lane; k < K; k += 64) s += ar[k] * br[k];
    s = wave_allsum(s);
    if (lane == 0) {
        float v = s + bias[n];
        if (ACT == 1) v = fmaxf(v, 0.f);
        if (ACT == 2) v = 1.f / (1.f + expf(-v));
        C[o] = v;
    }
}

// ---------------- transpose: in[b][D][N] -> out[b][N][D] ----------------
__global__ void transpose_kernel(const float* __restrict__ in, float* __restrict__ out,
                                 int D, int N)
{
    __shared__ float tile[32][33];
    int b = blockIdx.z;
    int d0 = blockIdx.y * 32, n0 = blockIdx.x * 32;
    int tx = threadIdx.x, ty = threadIdx.y;
    for (int i = 0; i < 32; i += 8) {
        int d = d0 + ty + i, n = n0 + tx;
        if (d < D && n < N) tile[ty + i][tx] = in[((long long)b * D + d) * N + n];
    }
    __syncthreads();
    for (int i = 0; i < 32; i += 8) {
        int n = n0 + ty + i, d = d0 + tx;
        if (n < N && d < D) out[((long long)b * N + n) * D + d] = tile[tx][ty + i];
    }
}

// ---------------- audio[b][d] = mean_m vtf[b][m][d]  (grid 3 x B) -------------
__global__ void audio_kernel(const float* __restrict__ vtf, float* __restrict__ audio)
{
    int b = blockIdx.y, d = blockIdx.x * 256 + threadIdx.x;
    float s = 0.f;
    for (int m = 0; m < COUT; m++) s += vtf[((long long)b * COUT + m) * DD0 + d];
    audio[b * DD0 + d] = s * (1.f / (float)COUT);
}

// ========== att1 scores: P[b][t][m] = softmax_m(mt[t]·vtf[b][m]) ==========
__global__ __launch_bounds__(256)
void att1_scores(const float* __restrict__ vtf, const float* __restrict__ mt,
                 unsigned short* __restrict__ pbuf)
{
    __shared__ float sc[TT][208];
    const int b = blockIdx.x;
    const int tid = threadIdx.x, w = tid >> 6, lane = tid & 63;
    const int l15 = lane & 15, kg = (lane >> 4) << 3;
    const float* vb = vtf + (long long)b * COUT * DD0;

    f32x4 acc[4][2];
    #pragma unroll
    for (int q = 0; q < 4; q++) { acc[q][0] = (f32x4){0.f,0.f,0.f,0.f}; acc[q][1] = (f32x4){0.f,0.f,0.f,0.f}; }

    for (int kt = 0; kt < DD0; kt += 32) {
        const float* a0p = mt + (long long)l15 * DD0 + kt + kg;
        const float* a1p = a0p + 16 * DD0;
        short8 a0 = cvt8(*(const float4*)a0p, *(const float4*)(a0p + 4));
        short8 a1 = cvt8(*(const float4*)a1p, *(const float4*)(a1p + 4));
        #pragma unroll
        for (int q = 0; q < 4; q++) {
            const int mtile = w + q * 4;
            const int gm = mtile * 16 + l15;
            short8 bf = {0,0,0,0,0,0,0,0};
            if (gm < COUT) {
                const float* bp = vb + (long long)gm * DD0 + kt + kg;
                bf = cvt8(*(const float4*)bp, *(const float4*)(bp + 4));
            }
            acc[q][0] = __builtin_amdgcn_mfma_f32_16x16x32_bf16(a0, bf, acc[q][0], 0, 0, 0);
            acc[q][1] = __builtin_amdgcn_mfma_f32_16x16x32_bf16(a1, bf, acc[q][1], 0, 0, 0);
        }
    }
    #pragma unroll
    for (int q = 0; q < 4; q++) {
        const int mtile = w + q * 4;
        if (mtile < 13) {
            #pragma unroll
            for (int j = 0; j < 2; j++)
                #pragma unroll
                for (int r = 0; r < 4; r++)
                    sc[j * 16 + ((lane >> 4) << 2) + r][mtile * 16 + l15] = acc[q][j][r];
        }
    }
    __syncthreads();
    for (int tr = 0; tr < 8; tr++) {
        const int t = w * 8 + tr;
        float v = -1e30f;
        for (int m = lane; m < COUT; m += 64) v = fmaxf(v, sc[t][m]);
        v = wave_allmax(v);
        float s = 0.f;
        for (int m = lane; m < COUT; m += 64) { float e = __expf(sc[t][m] - v); sc[t][m] = e; s += e; }
        s = wave_allsum(s);
        const float inv = 1.f / s;
        unsigned short* pr = pbuf + ((long long)b * TT + t) * 224;
        for (int m = lane; m < 224; m += 64) pr[m] = (m < COUT) ? f2bf(sc[t][m] * inv) : (unsigned short)0;
    }
}

// ========== att1 PV: rep[b][t][d] = mt[t][d] + sum_m P[t][m]·vtf[b][m][d] ======
__global__ __launch_bounds__(256)
void att1_pv(const float* __restrict__ vtf, const unsigned short* __restrict__ pbuf,
             const float* __restrict__ mt, float* __restrict__ rep)
{
    __shared__ unsigned short vT[128][36];
    const int b = blockIdx.y, d0 = blockIdx.x * 128;
    const int tid = threadIdx.x, w = tid >> 6, lane = tid & 63;
    const int l15 = lane & 15, kg = (lane >> 4) << 3;
    const float* vb = vtf + (long long)b * COUT * DD0;

    f32x4 acc[2][2];
    acc[0][0] = (f32x4){0.f,0.f,0.f,0.f}; acc[0][1] = (f32x4){0.f,0.f,0.f,0.f};
    acc[1][0] = (f32x4){0.f,0.f,0.f,0.f}; acc[1][1] = (f32x4){0.f,0.f,0.f,0.f};

    for (int kc = 0; kc < 7; kc++) {
        for (int i = tid; i < 32 * 128; i += 256) {
            const int m = i >> 7, dd = i & 127;
            const int gm = kc * 32 + m;
            const float v = (gm < COUT) ? vb[(long long)gm * DD0 + d0 + dd] : 0.f;
            vT[dd][m] = f2bf(v);
        }
        const short8 p0 = *(const short8*)(pbuf + ((long long)b * TT + l15) * 224 + kc * 32 + kg);
        const short8 p1 = *(const short8*)(pbuf + ((long long)b * TT + 16 + l15) * 224 + kc * 32 + kg);
        __syncthreads();
        #pragma unroll
        for (int jl = 0; jl < 2; jl++) {
            const short8 bf = lds_frag(&vT[(w * 2 + jl) * 16 + l15][kg]);
            acc[0][jl] = __builtin_amdgcn_mfma_f32_16x16x32_bf16(p0, bf, acc[0][jl], 0, 0, 0);
            acc[1][jl] = __builtin_amdgcn_mfma_f32_16x16x32_bf16(p1, bf, acc[1][jl], 0, 0, 0);
        }
        __syncthreads();
    }
    #pragma unroll
    for (int j = 0; j < 2; j++) {
        #pragma unroll
        for (int jl = 0; jl < 2; jl++) {
            const int t = j * 16 + ((lane >> 4) << 2);
            const int gd = d0 + (w * 2 + jl) * 16 + l15;
            #pragma unroll
            for (int r = 0; r < 4; r++)
                rep[((long long)b * TT + t + r) * DD0 + gd] = mt[(long long)(t + r) * DD0 + gd] + acc[j][jl][r];
        }
    }
}

// ========== att2 fused: xT[n] += gate_av * softmax_t(xT[n]·rep[t]) @ rep ======
__global__ __launch_bounds__(256)
void att2_mfma(const float* __restrict__ rep, const float* __restrict__ gav,
               float* __restrict__ xT)
{
    __shared__ unsigned short repT[DD0][36];
    __shared__ unsigned short Pl[64][36];
    const int b = blockIdx.y, m0 = blockIdx.x * 64;
    const int tid = threadIdx.x, w = tid >> 6, lane = tid & 63;
    const int l15 = lane & 15, kg = (lane >> 4) << 3;
    const float* repb = rep + (long long)b * TT * DD0;

    for (int i = tid; i < TT * DD0; i += 256) {
        const int t = i / DD0, d = i - t * DD0;
        repT[d][t] = f2bf(repb[i]);
    }
    __syncthreads();

    f32x4 acc0 = (f32x4){0.f,0.f,0.f,0.f}, acc1 = (f32x4){0.f,0.f,0.f,0.f};
    const int arow = m0 + w * 16 + l15;
    const bool rok = arow < NN;
    const float* xrow = xT + ((long long)b * NN + arow) * DD0;
    for (int kt = 0; kt < DD0; kt += 32) {
        short8 af = {0,0,0,0,0,0,0,0};
        if (rok) af = cvt8(*(const float4*)(xrow + kt + kg), *(const float4*)(xrow + kt + kg + 4));
        const float* r0 = repb + (long long)l15 * DD0 + kt + kg;
        const float* r1 = r0 + 16 * DD0;
        const short8 b0 = cvt8(*(const float4*)r0, *(const float4*)(r0 + 4));
        const short8 b1 = cvt8(*(const float4*)r1, *(const float4*)(r1 + 4));
        acc0 = __builtin_amdgcn_mfma_f32_16x16x32_bf16(af, b0, acc0, 0, 0, 0);
        acc1 = __builtin_amdgcn_mfma_f32_16x16x32_bf16(af, b1, acc1, 0, 0, 0);
    }
    #pragma unroll
    for (int r = 0; r < 4; r++) {
        float m = fmaxf(acc0[r], acc1[r]);
        m = fmaxf(m, __shfl_xor(m, 1, 64));
        m = fmaxf(m, __shfl_xor(m, 2, 64));
        m = fmaxf(m, __shfl_xor(m, 4, 64));
        m = fmaxf(m, __shfl_xor(m, 8, 64));
        const float e0 = __expf(acc0[r] - m), e1 = __expf(acc1[r] - m);
        float s = e0 + e1;
        s += __shfl_xor(s, 1, 64); s += __shfl_xor(s, 2, 64);
        s += __shfl_xor(s, 4, 64); s += __shfl_xor(s, 8, 64);
        const float inv = 1.f / s;
        const int prow = w * 16 + ((lane >> 4) << 2) + r;
        Pl[prow][l15] = f2bf(e0 * inv);
        Pl[prow][l15 + 16] = f2bf(e1 * inv);
    }
    __syncthreads();
    const short8 pa = lds_frag(&Pl[w * 16 + l15][kg]);
    const float ga = gav[0];
    const int gmb = m0 + w * 16 + ((lane >> 4) << 2);
    for (int jd = 0; jd < 48; jd++) {
        const short8 bf = lds_frag(&repT[jd * 16 + l15][kg]);
        f32x4 av = (f32x4){0.f,0.f,0.f,0.f};
        av = __builtin_amdgcn_mfma_f32_16x16x32_bf16(pa, bf, av, 0, 0, 0);
        const int gd = jd * 16 + l15;
        #pragma unroll
        for (int r = 0; r < 4; r++) {
            if (gmb + r < NN) {
                const long long idx = ((long long)b * NN + gmb + r) * DD0 + gd;
                xT[idx] += ga * av[r];
            }
        }
    }
}

// ---------------- mvq[b][d] = aq1[b][d] * mean_n vq1[b][n][d]  (grid 3 x B) ----
__global__ void mvq_kernel(const float* __restrict__ vq1, const float* __restrict__ aq1,
                           float* __restrict__ mvq)
{
    int b = blockIdx.y, d = blockIdx.x * 256 + threadIdx.x;
    float s = 0.f;
    for (int n = 0; n < NN; n++) s += vq1[((long long)b * NN + n) * DD0 + d];
    mvq[b * DD0 + d] = aq1[b * DD0 + d] * s * (1.f / (float)NN);
}

// ---------------- s_tmp -> s_sig + sp_att (wave-per-row dot) ----------------
__global__ __launch_bounds__(256)
void stmp_kernel(const float* __restrict__ cq, const float* __restrict__ aq2,
                 const float* __restrict__ vsw, const float* __restrict__ vsb,
                 float* __restrict__ ssig, float* __restrict__ spatt)
{
    int b = blockIdx.x, tid = threadIdx.x, w = tid >> 6, lane = tid & 63;
    __shared__ float wv[DM];
    __shared__ float st[NN];
    __shared__ float sb[4];
    for (int i = tid; i < DM; i += 256) wv[i] = aq2[b * DM + i] * vsw[i];
    __syncthreads();
    float vb = vsb[0];
    for (int n = w; n < NN; n += 4) {
        const float* cr = cq + ((long long)b * NN + n) * DM;
        float s = 0.f;
        for (int d = lane; d < DM; d += 64) s += cr[d] * wv[d];
        s = wave_allsum(s);
        if (lane == 0) {
            float sv = s + vb;
            st[n] = tanhf(sv);
            ssig[b * NN + n] = 1.f / (1.f + expf(-sv));
        }
    }
    __syncthreads();
    float lm = -1e30f;
    for (int n = tid; n < NN; n += 256) lm = fmaxf(lm, st[n]);
    float mx = block_max256(lm, sb);
    float ls = 0.f;
    for (int n = tid; n < NN; n += 256) { float e = expf(st[n] - mx); st[n] = e; ls += e; }
    float s = block_sum256(ls, sb);
    float inv = 1.f / s;
    for (int n = tid; n < NN; n += 256) spatt[b * NN + n] = st[n] * inv;
}

// ---------------- gating scale + LayerNorm (lnb) in place on xT ----------------
__global__ __launch_bounds__(256)
void scale_ln_kernel(float* __restrict__ xT, const float* __restrict__ chatt,
                     const float* __restrict__ ssig, const float* __restrict__ g,
                     const float* __restrict__ bb)
{
    int b = blockIdx.y, n = blockIdx.x, tid = threadIdx.x;
    __shared__ float sb[4];
    float* xr = xT + ((long long)b * NN + n) * DD0;
    float ss = ssig[b * NN + n];
    float v[3];
    float lsum = 0.f;
    #pragma unroll
    for (int i = 0; i < 3; i++) {
        int d = tid + i * 256;
        float sc = 0.3f * chatt[b * DD0 + d] + 0.05f * ss + 0.7f;
        v[i] = xr[d] * sc;
        lsum += v[i];
    }
    float mean = block_sum256(lsum, sb) * (1.f / (float)DD0);
    float lvar = 0.f;
    #pragma unroll
    for (int i = 0; i < 3; i++) { float dd = v[i] - mean; lvar += dd * dd; }
    float var = block_sum256(lvar, sb) * (1.f / (float)DD0);
    float inv = rsqrtf(var + EPS);
    #pragma unroll
    for (int i = 0; i < 3; i++) {
        int d = tid + i * 256;
        xr[d] = (v[i] - mean) * inv * g[d] + bb[d];
    }
}

// ---------------- BN stats ----------------
__global__ void bn1stats_kernel(const float* __restrict__ y1, float* __restrict__ stats)
{
    int b = blockIdx.x, tid = threadIdx.x;
    if (tid < DDB) {
        float s = 0.f, q = 0.f;
        for (int n = 0; n < NN; n++) {
            float v = y1[((long long)b * NN + n) * DDB + tid];
            s += v; q += v * v;
        }
        atomicAdd(&stats[tid], s);
        atomicAdd(&stats[DDB + tid], q);
    }
}

__global__ void bn1apply_kernel(float* __restrict__ y1, const float* __restrict__ stats,
                                const float* __restrict__ g, const float* __restrict__ bb)
{
    long long i = (long long)blockIdx.x * 256 + threadIdx.x;
    if (i >= (long long)BB * NN * DDB) return;
    int e = (int)(i % DDB);
    const float cnt = (float)(BB * NN);
    float mu = stats[e] / cnt;
    float var = stats[DDB + e] / cnt - mu * mu;
    float v = (y1[i] - mu) * rsqrtf(var + EPS) * g[e] + bb[e];
    y1[i] = fmaxf(v, 0.f);
}

__global__ void bn2stats_kernel(const float* __restrict__ y2, float* __restrict__ stats)
{
    int b = blockIdx.y, d = blockIdx.x * 256 + threadIdx.x;
    float s = 0.f, q = 0.f;
    for (int n = 0; n < NN; n++) {
        float v = y2[((long long)b * NN + n) * DD0 + d];
        s += v; q += v * v;
    }
    atomicAdd(&stats[d], s);
    atomicAdd(&stats[DD0 + d], q);
}

// ---------------- BN2 + LN(lnp) + gate -> out_tmp[b][n][d] ----------------
__global__ __launch_bounds__(256)
void final_kernel(const float* __restrict__ y2, const float* __restrict__ stats2,
                  const float* __restrict__ g2, const float* __restrict__ b2,
                  const float* __restrict__ lg, const float* __restrict__ lb,
                  const float* __restrict__ gate, float* __restrict__ out_tmp)
{
    int b = blockIdx.y, n = blockIdx.x, tid = threadIdx.x;
    __shared__ float sb[4];
    const float* yr = y2 + ((long long)b * NN + n) * DD0;
    const float cnt = (float)(BB * NN);
    float v[3];
    float lsum = 0.f;
    #pragma unroll
    for (int i = 0; i < 3; i++) {
        int d = tid + i * 256;
        float mu = stats2[d] / cnt;
        float var = stats2[DD0 + d] / cnt - mu * mu;
        v[i] = (yr[d] - mu) * rsqrtf(var + EPS) * g2[d] + b2[d];
        lsum += v[i];
    }
    float mean = block_sum256(lsum, sb) * (1.f / (float)DD0);
    float lvar = 0.f;
    #pragma unroll
    for (int i = 0; i < 3; i++) { float dd = v[i] - mean; lvar += dd * dd; }
    float var = block_sum256(lvar, sb) * (1.f / (float)DD0);
    float inv = rsqrtf(var + EPS);
    float gt = gate[0];
    float* orow = out_tmp + ((long long)b * NN + n) * DD0;
    #pragma unroll
    for (int i = 0; i < 3; i++) {
        int d = tid + i * 256;
        orow[d] = ((v[i] - mean) * inv * lg[d] + lb[d]) * gt;
    }
}

// ======================= launch =======================
extern "C" void kernel_launch(void* const* d_in, const int* in_sizes, int n_in,
                              void* d_out, int out_size, void* d_ws, size_t ws_size,
                              hipStream_t stream)
{
    const float* x       = (const float*)d_in[0];
    const float* vis     = (const float*)d_in[1];
    const float* conv_w  = (const float*)d_in[2];
    const float* conv_b  = (const float*)d_in[3];
    const float* fc_w    = (const float*)d_in[4];
    const float* fc_b    = (const float*)d_in[5];
    const float* a1_w    = (const float*)d_in[6];
    const float* a1_b    = (const float*)d_in[7];
    const float* v1_w    = (const float*)d_in[8];
    const float* v1_b    = (const float*)d_in[9];
    const float* btl_w   = (const float*)d_in[10];
    const float* btl_b   = (const float*)d_in[11];
    const float* v2_w    = (const float*)d_in[12];
    const float* v2_b    = (const float*)d_in[13];
    const float* a2_w    = (const float*)d_in[14];
    const float* a2_b    = (const float*)d_in[15];
    const float* vs_w    = (const float*)d_in[16];
    const float* vs_b    = (const float*)d_in[17];
    const float* vc_w    = (const float*)d_in[18];
    const float* vc_b    = (const float*)d_in[19];
    const float* my_tok  = (const float*)d_in[20];
    const float* gate_av = (const float*)d_in[21];
    const float* gate    = (const float*)d_in[22];
    const float* down_w  = (const float*)d_in[23];
    const float* up_w    = (const float*)d_in[24];
    const float* bn1_g   = (const float*)d_in[25];
    const float* bn1_b   = (const float*)d_in[26];
    const float* bn2_g   = (const float*)d_in[27];
    const float* bn2_b   = (const float*)d_in[28];
    const float* lnb_g   = (const float*)d_in[29];
    const float* lnb_b   = (const float*)d_in[30];
    const float* lnp_g   = (const float*)d_in[31];
    const float* lnp_b   = (const float*)d_in[32];

    float* ws = (float*)d_ws;
    unsigned short* vtc_bf = (unsigned short*)(ws + OFF_A);
    float* vq1     = ws + OFF_A;
    float* cq      = ws + OFF_A;
    float* y2      = ws + OFF_A;
    float* vtf     = ws + OFF_B;
    float* out_tmp = ws + OFF_B;
    float* xT      = ws + OFF_XT;
    float* rep     = ws + OFF_REP;
    float* y1      = ws + OFF_Y1;
    unsigned short* wconv = (unsigned short*)(ws + OFF_WCONV);
    unsigned short* wfc   = (unsigned short*)(ws + OFF_WFC);
    unsigned short* wv1   = (unsigned short*)(ws + OFF_WV1);
    unsigned short* wv2   = (unsigned short*)(ws + OFF_WV2);
    unsigned short* wdown = (unsigned short*)(ws + OFF_WDOWN);
    unsigned short* wup   = (unsigned short*)(ws + OFF_WUP);
    float* audio   = ws + OFF_AUDIO;
    float* aq1b    = ws + OFF_AQ1;
    float* mvqb    = ws + OFF_MVQ;
    float* avqb    = ws + OFF_AVQ;
    float* chattb  = ws + OFF_CHATT;
    float* aq2b    = ws + OFF_AQ2;
    float* ssigb   = ws + OFF_SSIG;
    float* stats1  = ws + OFF_STATS;
    float* stats2  = ws + OFF_STATS + 2 * DDB;
    unsigned short* pbuf = (unsigned short*)(ws + OFF_PBUF);

    float* out   = (float*)d_out;
    float* spatt = out + (long long)BB * DD0 * NN;

    hipMemsetAsync(stats1, 0, (2 * DDB + 2 * DD0) * sizeof(float), stream);

    // 0. weight conversions (f32 -> bf16)
    cvt_f2bf<<<(DD0 * LIN / 4 + 255) / 256, 256, 0, stream>>>(fc_w, wfc, DD0 * LIN);
    cvt_f2bf<<<(DD0 * DD0 / 4 + 255) / 256, 256, 0, stream>>>(v1_w, wv1, DD0 * DD0);
    cvt_f2bf<<<(DM * DD0 / 4 + 255) / 256, 256, 0, stream>>>(v2_w, wv2, DM * DD0);
    cvt_f2bf<<<(DDB * DD0 / 4 + 255) / 256, 256, 0, stream>>>(down_w, wdown, DDB * DD0);
    cvt_f2bf<<<(DD0 * DDB / 4 + 255) / 256, 256, 0, stream>>>(up_w, wup, DD0 * DDB);
    cvt_f2bf_pad<<<(COUT * 200 + 255) / 256, 256, 0, stream>>>(conv_w, wconv, COUT, CIN, 200);

    // 1. x -> xT
    transpose_kernel<<<dim3(7, 24, BB), dim3(32, 8), 0, stream>>>(x, xT, DD0, NN);
    // 2. conv (MFMA) -> vtc_bf   (Ka=200: wconv zero-padded)
    gemm_mfma<1, true, false, false, 0, false><<<dim3(NCONV / 128, 2), 256, 0, stream>>>(
        wconv, 200, vis, CIN, conv_b, nullptr, vtc_bf, COUT, NCONV, CIN, 200);
    // 3. fc (MFMA) -> vtf f32
    gemm_mfma<0, true, true, false, 0, false><<<dim3(DD0 / 128, MFLAT / 128), 256, 0, stream>>>(
        vtc_bf, LIN, wfc, LIN, fc_b, nullptr, vtf, MFLAT, DD0, LIN, LIN);
    // 4. audio
    audio_kernel<<<dim3(3, BB), 256, 0, stream>>>(vtf, audio);
    // 5. att1 (MFMA)
    att1_scores<<<BB, 256, 0, stream>>>(vtf, my_tok, pbuf);
    att1_pv<<<dim3(6, BB), 256, 0, stream>>>(vtf, pbuf, my_tok, rep);
    // 6. att2 (MFMA, fused)
    att2_mfma<<<dim3(4, BB), 256, 0, stream>>>(rep, gate_av, xT);
    // 7. aq1 = relu(audio@a1^T+b)
    wave_gemv<1><<<BB * DD0 / 4, 256, 0, stream>>>(audio, DD0, a1_w, DD0, a1_b, aq1b, DD0, DD0);
    // 8. vq1 (MFMA) relu
    gemm_mfma<0, false, true, false, 1, false><<<dim3(DD0 / 128, MFLAT / 128), 256, 0, stream>>>(
        xT, DD0, wv1, DD0, v1_b, nullptr, vq1, MFLAT, DD0, DD0, DD0);
    // 9. mvq
    mvq_kernel<<<dim3(3, BB), 256, 0, stream>>>(vq1, aq1b, mvqb);
    // 10. avq = relu(mvq@btl^T+b)
    wave_gemv<1><<<BB * DM / 4, 256, 0, stream>>>(mvqb, DD0, btl_w, DD0, btl_b, avqb, DM, DD0);
    // 11. ch_att = sigmoid(avq@vc^T+b)
    wave_gemv<2><<<BB * DD0 / 4, 256, 0, stream>>>(avqb, DM, vc_w, DM, vc_b, chattb, DD0, DM);
    // 12. aq2 = relu(audio@a2^T+b)
    wave_gemv<1><<<BB * DM / 4, 256, 0, stream>>>(audio, DD0, a2_w, DD0, a2_b, aq2b, DM, DD0);
    // 13. c_q (MFMA) relu, k-scale
    gemm_mfma<0, false, true, true, 1, false><<<dim3(DM / 128, MFLAT / 128), 256, 0, stream>>>(
        xT, DD0, wv2, DD0, v2_b, chattb, cq, MFLAT, DM, DD0, DD0);
    // 14. s_tmp / s_sig / sp_att
    stmp_kernel<<<BB, 256, 0, stream>>>(cq, aq2b, vs_w, vs_b, ssigb, spatt);
    // 15. scale + ln_before
    scale_ln_kernel<<<dim3(NN, BB), 256, 0, stream>>>(xT, chattb, ssigb, lnb_g, lnb_b);
    // 16. down (MFMA, N=96 guarded): y1 = xT@down^T
    gemm_mfma<0, false, true, false, 0, true><<<dim3(1, MFLAT / 128), 256, 0, stream>>>(
        xT, DD0, wdown, DD0, nullptr, nullptr, y1, MFLAT, DDB, DD0, DD0);
    // 17-18. BN1
    bn1stats_kernel<<<BB, 128, 0, stream>>>(y1, stats1);
    bn1apply_kernel<<<(BB * NN * DDB + 255) / 256, 256, 0, stream>>>(y1, stats1, bn1_g, bn1_b);
    // 19. up (MFMA): y2 = z@up^T
    gemm_mfma<0, false, true, false, 0, false><<<dim3(DD0 / 128, MFLAT / 128), 256, 0, stream>>>(
        y1, DDB, wup, DDB, nullptr, nullptr, y2, MFLAT, DD0, DDB, DDB);
    // 20. BN2 stats
    bn2stats_kernel<<<dim3(3, BB), 256, 0, stream>>>(y2, stats2);
    // 21. BN2 + LN + gate
    final_kernel<<<dim3(NN, BB), 256, 0, stream>>>(y2, stats2, bn2_g, bn2_b,
                                                   lnp_g, lnp_b, gate, out_tmp);
    // 22. out_tmp -> out
    transpose_kernel<<<dim3(24, 7, BB), dim3(32, 8), 0, stream>>>(out_tmp, out, NN, DD0);
}

// Round 7
// 930.508 us; speedup vs baseline: 2.7017x; 1.0561x over previous
//
#include <hip/hip_runtime.h>
#include <math.h>

// ---- problem constants ----
#define BB 64
#define DD0 768
#define NN 196
#define LIN 1536
#define CIN 196
#define COUT 196
#define TT 32
#define DM 384
#define DDB 96
#define EPS 1e-5f
#define MFLAT (BB * NN)          // 12544
#define NCONV (BB * LIN)         // 98304

// ---- workspace layout (float offsets) ----
#define OFF_A     0LL            // vtc_bf16 -> vq1 f32 -> cq f32 -> y2 f32
#define OFF_B     9633792LL      // vtf f32 -> out_tmp f32
#define OFF_XT    19267584LL     // xT f32
#define OFF_REP   28901376LL     // rep f32
#define OFF_Y1    30474240LL     // y1 f32
#define OFF_WCONV 31678464LL     // 196x200 ushort padded
#define OFF_WFC   31698064LL     // 768x1536 ushort
#define OFF_WV1   32287888LL     // 768x768  ushort
#define OFF_WV2   32582800LL     // 384x768  ushort
#define OFF_SM    32730256LL
#define OFF_AUDIO (OFF_SM)
#define OFF_AQ1   (OFF_SM+49152)
#define OFF_MVQ   (OFF_SM+98304)
#define OFF_AVQ   (OFF_SM+147456)
#define OFF_CHATT (OFF_SM+172032)
#define OFF_AQ2   (OFF_SM+221184)
#define OFF_SSIG  (OFF_SM+245760)
#define OFF_STATS (OFF_SM+258304)
#define OFF_PBUF  (OFF_SM+262144)   // att1 P: 64*32*224 ushort = 229376 f
#define OFF_WDOWN (OFF_SM+491520)   // 96x768 ushort = 36864 f
#define OFF_WUP   (OFF_SM+528384)   // 768x96 ushort = 36864 f
#define OFF_STMP  (OFF_SM+565248)   // st_buf: 64*196 f = 12544 f

typedef __attribute__((ext_vector_type(8))) short short8;
typedef __attribute__((ext_vector_type(4))) float f32x4;

__device__ __forceinline__ unsigned short f2bf(float f) {
    union { float f; unsigned u; } v; v.f = f;
    unsigned r = v.u + 0x7fffu + ((v.u >> 16) & 1u);
    return (unsigned short)(r >> 16);
}
__device__ __forceinline__ short8 cvt8(const float4 a, const float4 b) {
    short8 r;
    r[0] = (short)f2bf(a.x); r[1] = (short)f2bf(a.y); r[2] = (short)f2bf(a.z); r[3] = (short)f2bf(a.w);
    r[4] = (short)f2bf(b.x); r[5] = (short)f2bf(b.y); r[6] = (short)f2bf(b.z); r[7] = (short)f2bf(b.w);
    return r;
}
__device__ __forceinline__ short8 lds_frag(const unsigned short* p) {
    short4 lo = *(const short4*)p;
    short4 hi = *(const short4*)(p + 4);
    short8 r;
    r[0] = lo.x; r[1] = lo.y; r[2] = lo.z; r[3] = lo.w;
    r[4] = hi.x; r[5] = hi.y; r[6] = hi.z; r[7] = hi.w;
    return r;
}

// ---------------- reduction helpers ----------------
__device__ __forceinline__ float warp_sum(float v) {
    for (int o = 32; o; o >>= 1) v += __shfl_down(v, o, 64);
    return v;
}
__device__ __forceinline__ float wave_allsum(float v) {
    for (int o = 1; o < 64; o <<= 1) v += __shfl_xor(v, o, 64);
    return v;
}
__device__ __forceinline__ float wave_allmax(float v) {
    for (int o = 1; o < 64; o <<= 1) v = fmaxf(v, __shfl_xor(v, o, 64));
    return v;
}
__device__ __forceinline__ float warp_max(float v) {
    for (int o = 32; o; o >>= 1) v = fmaxf(v, __shfl_down(v, o, 64));
    return v;
}
__device__ __forceinline__ float block_sum256(float v, float* sb) {
    v = warp_sum(v);
    __syncthreads();
    if ((threadIdx.x & 63) == 0) sb[threadIdx.x >> 6] = v;
    __syncthreads();
    return sb[0] + sb[1] + sb[2] + sb[3];
}
__device__ __forceinline__ float block_max256(float v, float* sb) {
    v = warp_max(v);
    __syncthreads();
    if ((threadIdx.x & 63) == 0) sb[threadIdx.x >> 6] = v;
    __syncthreads();
    return fmaxf(fmaxf(sb[0], sb[1]), fmaxf(sb[2], sb[3]));
}

// ================= bf16 MFMA GEMM, coalesced staging =================
template<int MODE, bool ABF, bool BBF, bool KSC, int EPI, bool NG>
__global__ __launch_bounds__(256)
void gemm_mfma(const void* __restrict__ Ap, int lda,
               const void* __restrict__ Bp, int ldb,
               const float* __restrict__ bias, const float* __restrict__ ksc,
               void* __restrict__ Cp, int M, int N, int K, int Ka)
{
    __shared__ unsigned short Asm[128][72];
    __shared__ unsigned short Bsm[128][72];
    const int tid = threadIdx.x;
    const int m0 = blockIdx.y * 128, n0 = blockIdx.x * 128;
    const int w = tid >> 6, lane = tid & 63;
    const int wr = w >> 1, wc = w & 1;

    f32x4 acc[4][4];
    #pragma unroll
    for (int i = 0; i < 4; i++)
        #pragma unroll
        for (int j = 0; j < 4; j++) acc[i][j] = (f32x4){0.f, 0.f, 0.f, 0.f};

    const int nkt = (K + 63) >> 6;
    for (int kt = 0; kt < nkt; kt++) {
        const int k0 = kt << 6;
        // ---- stage A ----
        if (ABF) {
            #pragma unroll
            for (int q = 0; q < 4; q++) {
                const int row = q * 32 + (tid >> 3);
                const int ce = (tid & 7) * 8;
                const int gm = m0 + row;
                const bool rok = (MODE == 1) ? (gm < M) : true;
                uint4 u = make_uint4(0u, 0u, 0u, 0u);
                if (rok && (k0 + ce) < Ka)
                    u = *(const uint4*)((const unsigned short*)Ap + (long long)gm * lda + k0 + ce);
                *(uint4*)&Asm[row][ce] = u;
            }
        } else {
            #pragma unroll
            for (int q = 0; q < 8; q++) {
                const int row = q * 16 + (tid >> 4);
                const int ce = (tid & 15) * 4;
                const int gm = m0 + row;
                const bool rok = (MODE == 1) ? (gm < M) : true;
                float4 v = make_float4(0.f, 0.f, 0.f, 0.f);
                const bool kok = (k0 + ce) < K;
                if (rok && kok)
                    v = *(const float4*)((const float*)Ap + (long long)gm * lda + k0 + ce);
                if (KSC && kok) {
                    const float* kc = ksc + (gm / 196) * 768 + k0 + ce;
                    v.x *= kc[0] + 1.f; v.y *= kc[1] + 1.f;
                    v.z *= kc[2] + 1.f; v.w *= kc[3] + 1.f;
                }
                ushort4 o; o.x = f2bf(v.x); o.y = f2bf(v.y); o.z = f2bf(v.z); o.w = f2bf(v.w);
                *(ushort4*)&Asm[row][ce] = o;
            }
        }
        // ---- stage B ----
        if (BBF) {
            #pragma unroll
            for (int q = 0; q < 4; q++) {
                const int row = q * 32 + (tid >> 3);
                const int ce = (tid & 7) * 8;
                const int gn = n0 + row;
                const bool nok = NG ? (gn < N) : true;
                uint4 u = make_uint4(0u, 0u, 0u, 0u);
                if (nok && (k0 + ce) < K)
                    u = *(const uint4*)((const unsigned short*)Bp + (long long)gn * ldb + k0 + ce);
                *(uint4*)&Bsm[row][ce] = u;
            }
        } else {
            #pragma unroll
            for (int q = 0; q < 8; q++) {
                const int row = q * 16 + (tid >> 4);
                const int ce = (tid & 15) * 4;
                const int gn = n0 + row;
                const bool nok = NG ? (gn < N) : true;
                float4 v = make_float4(0.f, 0.f, 0.f, 0.f);
                if (nok && (k0 + ce) < K)
                    v = *(const float4*)((const float*)Bp + (long long)gn * ldb + k0 + ce);
                ushort4 o; o.x = f2bf(v.x); o.y = f2bf(v.y); o.z = f2bf(v.z); o.w = f2bf(v.w);
                *(ushort4*)&Bsm[row][ce] = o;
            }
        }
        __syncthreads();
        // ---- MFMA ----
        #pragma unroll
        for (int kk = 0; kk < 2; kk++) {
            short8 af[4], bfr[4];
            const int koff = kk * 32 + (lane >> 4) * 8;
            #pragma unroll
            for (int i = 0; i < 4; i++)
                af[i] = *(const short8*)&Asm[wr * 64 + i * 16 + (lane & 15)][koff];
            #pragma unroll
            for (int j = 0; j < 4; j++)
                bfr[j] = *(const short8*)&Bsm[wc * 64 + j * 16 + (lane & 15)][koff];
            #pragma unroll
            for (int i = 0; i < 4; i++)
                #pragma unroll
                for (int j = 0; j < 4; j++)
                    acc[i][j] = __builtin_amdgcn_mfma_f32_16x16x32_bf16(af[i], bfr[j], acc[i][j], 0, 0, 0);
        }
        __syncthreads();
    }
    // ---- epilogue (C/D layout: col=lane&15, row=(lane>>4)*4+rr) ----
    const int cmb = wr * 64 + ((lane >> 4) << 2);
    const int cnb = wc * 64 + (lane & 15);
    #pragma unroll
    for (int i = 0; i < 4; i++) {
        #pragma unroll
        for (int j = 0; j < 4; j++) {
            const int gn = n0 + cnb + j * 16;
            if (NG && gn >= N) continue;
            #pragma unroll
            for (int rr = 0; rr < 4; rr++) {
                const int gm = m0 + cmb + i * 16 + rr;
                float v = acc[i][j][rr];
                if (MODE == 0) {
                    if (bias) v += bias[gn];
                    if (EPI == 1) v = fmaxf(v, 0.f);
                    ((float*)Cp)[(long long)gm * N + gn] = v;
                } else {
                    if (gm < M) {
                        v += bias[gm];
                        const int b = gn / LIN, l = gn - b * LIN;
                        ((unsigned short*)Cp)[((long long)b * COUT + gm) * LIN + l] = f2bf(v);
                    }
                }
            }
        }
    }
}

// ---------------- weight f32 -> bf16 converters ----------------
__global__ void cvt_f2bf(const float* __restrict__ in, unsigned short* __restrict__ out, int n)
{
    int i = (blockIdx.x * 256 + threadIdx.x) * 4;
    if (i + 4 <= n) {
        float4 v = *(const float4*)(in + i);
        ushort4 o; o.x = f2bf(v.x); o.y = f2bf(v.y); o.z = f2bf(v.z); o.w = f2bf(v.w);
        *(ushort4*)(out + i) = o;
    }
}
__global__ void cvt_f2bf_pad(const float* __restrict__ in, unsigned short* __restrict__ out,
                             int rows, int cols, int ldo)
{
    int i = blockIdx.x * 256 + threadIdx.x;
    if (i < rows * ldo) {
        int r = i / ldo, c = i - r * ldo;
        out[i] = (c < cols) ? f2bf(in[r * cols + c]) : (unsigned short)0;
    }
}

// ---------------- wave-per-output GEMV: C[m][n] = act(A[m]·B[n] + bias[n]) ------
template<int ACT>
__global__ __launch_bounds__(256)
void wave_gemv(const float* __restrict__ A, int lda,
               const float* __restrict__ B, int ldb,
               const float* __restrict__ bias,
               float* __restrict__ C, int N, int K)
{
    const int w = threadIdx.x >> 6, lane = threadIdx.x & 63;
    const long long o = (long long)blockIdx.x * 4 + w;
    const int m = (int)(o / N), n = (int)(o - (long long)m * N);
    const float* ar = A + (long long)m * lda;
    const float* br = B + (long long)n * ldb;
    float s = 0.f;
    for (int k = lane; k < K; k += 64) s += ar[k] * br[k];
    s = wave_allsum(s);
    if (lane == 0) {
        float v = s + bias[n];
        if (ACT == 1) v = fmaxf(v, 0.f);
        if (ACT == 2) v = 1.f / (1.f + expf(-v));
        C[o] = v;
    }
}

// ---------------- transpose: in[b][D][N] -> out[b][N][D] ----------------
__global__ void transpose_kernel(const float* __restrict__ in, float* __restrict__ out,
                                 int D, int N)
{
    __shared__ float tile[32][33];
    int b = blockIdx.z;
    int d0 = blockIdx.y * 32, n0 = blockIdx.x * 32;
    int tx = threadIdx.x, ty = threadIdx.y;
    for (int i = 0; i < 32; i += 8) {
        int d = d0 + ty + i, n = n0 + tx;
        if (d < D && n < N) tile[ty + i][tx] = in[((long long)b * D + d) * N + n];
    }
    __syncthreads();
    for (int i = 0; i < 32; i += 8) {
        int n = n0 + ty + i, d = d0 + tx;
        if (n < N && d < D) out[((long long)b * N + n) * D + d] = tile[tx][ty + i];
    }
}

// ---------------- audio[b][d] = mean_m vtf[b][m][d]  (grid 3 x B) -------------
__global__ void audio_kernel(const float* __restrict__ vtf, float* __restrict__ audio)
{
    int b = blockIdx.y, d = blockIdx.x * 256 + threadIdx.x;
    float s = 0.f;
    for (int m = 0; m < COUT; m++) s += vtf[((long long)b * COUT + m) * DD0 + d];
    audio[b * DD0 + d] = s * (1.f / (float)COUT);
}

// ========== att1 scores: P[b][t][m] = softmax_m(mt[t]·vtf[b][m]) ==========
__global__ __launch_bounds__(256)
void att1_scores(const float* __restrict__ vtf, const float* __restrict__ mt,
                 unsigned short* __restrict__ pbuf)
{
    __shared__ float sc[TT][208];
    const int b = blockIdx.x;
    const int tid = threadIdx.x, w = tid >> 6, lane = tid & 63;
    const int l15 = lane & 15, kg = (lane >> 4) << 3;
    const float* vb = vtf + (long long)b * COUT * DD0;

    f32x4 acc[4][2];
    #pragma unroll
    for (int q = 0; q < 4; q++) { acc[q][0] = (f32x4){0.f,0.f,0.f,0.f}; acc[q][1] = (f32x4){0.f,0.f,0.f,0.f}; }

    for (int kt = 0; kt < DD0; kt += 32) {
        const float* a0p = mt + (long long)l15 * DD0 + kt + kg;
        const float* a1p = a0p + 16 * DD0;
        short8 a0 = cvt8(*(const float4*)a0p, *(const float4*)(a0p + 4));
        short8 a1 = cvt8(*(const float4*)a1p, *(const float4*)(a1p + 4));
        #pragma unroll
        for (int q = 0; q < 4; q++) {
            const int mtile = w + q * 4;
            const int gm = mtile * 16 + l15;
            short8 bf = {0,0,0,0,0,0,0,0};
            if (gm < COUT) {
                const float* bp = vb + (long long)gm * DD0 + kt + kg;
                bf = cvt8(*(const float4*)bp, *(const float4*)(bp + 4));
            }
            acc[q][0] = __builtin_amdgcn_mfma_f32_16x16x32_bf16(a0, bf, acc[q][0], 0, 0, 0);
            acc[q][1] = __builtin_amdgcn_mfma_f32_16x16x32_bf16(a1, bf, acc[q][1], 0, 0, 0);
        }
    }
    #pragma unroll
    for (int q = 0; q < 4; q++) {
        const int mtile = w + q * 4;
        if (mtile < 13) {
            #pragma unroll
            for (int j = 0; j < 2; j++)
                #pragma unroll
                for (int r = 0; r < 4; r++)
                    sc[j * 16 + ((lane >> 4) << 2) + r][mtile * 16 + l15] = acc[q][j][r];
        }
    }
    __syncthreads();
    for (int tr = 0; tr < 8; tr++) {
        const int t = w * 8 + tr;
        float v = -1e30f;
        for (int m = lane; m < COUT; m += 64) v = fmaxf(v, sc[t][m]);
        v = wave_allmax(v);
        float s = 0.f;
        for (int m = lane; m < COUT; m += 64) { float e = __expf(sc[t][m] - v); sc[t][m] = e; s += e; }
        s = wave_allsum(s);
        const float inv = 1.f / s;
        unsigned short* pr = pbuf + ((long long)b * TT + t) * 224;
        for (int m = lane; m < 224; m += 64) pr[m] = (m < COUT) ? f2bf(sc[t][m] * inv) : (unsigned short)0;
    }
}

// ========== att1 PV: rep[b][t][d] = mt[t][d] + sum_m P[t][m]·vtf[b][m][d] ======
__global__ __launch_bounds__(256)
void att1_pv(const float* __restrict__ vtf, const unsigned short* __restrict__ pbuf,
             const float* __restrict__ mt, float* __restrict__ rep)
{
    __shared__ unsigned short vT[128][36];
    const int b = blockIdx.y, d0 = blockIdx.x * 128;
    const int tid = threadIdx.x, w = tid >> 6, lane = tid & 63;
    const int l15 = lane & 15, kg = (lane >> 4) << 3;
    const float* vb = vtf + (long long)b * COUT * DD0;

    f32x4 acc[2][2];
    acc[0][0] = (f32x4){0.f,0.f,0.f,0.f}; acc[0][1] = (f32x4){0.f,0.f,0.f,0.f};
    acc[1][0] = (f32x4){0.f,0.f,0.f,0.f}; acc[1][1] = (f32x4){0.f,0.f,0.f,0.f};

    for (int kc = 0; kc < 7; kc++) {
        for (int i = tid; i < 32 * 128; i += 256) {
            const int m = i >> 7, dd = i & 127;
            const int gm = kc * 32 + m;
            const float v = (gm < COUT) ? vb[(long long)gm * DD0 + d0 + dd] : 0.f;
            vT[dd][m] = f2bf(v);
        }
        const short8 p0 = *(const short8*)(pbuf + ((long long)b * TT + l15) * 224 + kc * 32 + kg);
        const short8 p1 = *(const short8*)(pbuf + ((long long)b * TT + 16 + l15) * 224 + kc * 32 + kg);
        __syncthreads();
        #pragma unroll
        for (int jl = 0; jl < 2; jl++) {
            const short8 bf = lds_frag(&vT[(w * 2 + jl) * 16 + l15][kg]);
            acc[0][jl] = __builtin_amdgcn_mfma_f32_16x16x32_bf16(p0, bf, acc[0][jl], 0, 0, 0);
            acc[1][jl] = __builtin_amdgcn_mfma_f32_16x16x32_bf16(p1, bf, acc[1][jl], 0, 0, 0);
        }
        __syncthreads();
    }
    #pragma unroll
    for (int j = 0; j < 2; j++) {
        #pragma unroll
        for (int jl = 0; jl < 2; jl++) {
            const int t = j * 16 + ((lane >> 4) << 2);
            const int gd = d0 + (w * 2 + jl) * 16 + l15;
            #pragma unroll
            for (int r = 0; r < 4; r++)
                rep[((long long)b * TT + t + r) * DD0 + gd] = mt[(long long)(t + r) * DD0 + gd] + acc[j][jl][r];
        }
    }
}

// ========== att2 fused: xT[n] += gate_av * softmax_t(xT[n]·rep[t]) @ rep ======
__global__ __launch_bounds__(256)
void att2_mfma(const float* __restrict__ rep, const float* __restrict__ gav,
               float* __restrict__ xT)
{
    __shared__ unsigned short repT[DD0][36];
    __shared__ unsigned short Pl[64][36];
    const int b = blockIdx.y, m0 = blockIdx.x * 64;
    const int tid = threadIdx.x, w = tid >> 6, lane = tid & 63;
    const int l15 = lane & 15, kg = (lane >> 4) << 3;
    const float* repb = rep + (long long)b * TT * DD0;

    for (int i = tid; i < TT * DD0; i += 256) {
        const int t = i / DD0, d = i - t * DD0;
        repT[d][t] = f2bf(repb[i]);
    }
    __syncthreads();

    f32x4 acc0 = (f32x4){0.f,0.f,0.f,0.f}, acc1 = (f32x4){0.f,0.f,0.f,0.f};
    const int arow = m0 + w * 16 + l15;
    const bool rok = arow < NN;
    const float* xrow = xT + ((long long)b * NN + arow) * DD0;
    for (int kt = 0; kt < DD0; kt += 32) {
        short8 af = {0,0,0,0,0,0,0,0};
        if (rok) af = cvt8(*(const float4*)(xrow + kt + kg), *(const float4*)(xrow + kt + kg + 4));
        const float* r0 = repb + (long long)l15 * DD0 + kt + kg;
        const float* r1 = r0 + 16 * DD0;
        const short8 b0 = cvt8(*(const float4*)r0, *(const float4*)(r0 + 4));
        const short8 b1 = cvt8(*(const float4*)r1, *(const float4*)(r1 + 4));
        acc0 = __builtin_amdgcn_mfma_f32_16x16x32_bf16(af, b0, acc0, 0, 0, 0);
        acc1 = __builtin_amdgcn_mfma_f32_16x16x32_bf16(af, b1, acc1, 0, 0, 0);
    }
    #pragma unroll
    for (int r = 0; r < 4; r++) {
        float m = fmaxf(acc0[r], acc1[r]);
        m = fmaxf(m, __shfl_xor(m, 1, 64));
        m = fmaxf(m, __shfl_xor(m, 2, 64));
        m = fmaxf(m, __shfl_xor(m, 4, 64));
        m = fmaxf(m, __shfl_xor(m, 8, 64));
        const float e0 = __expf(acc0[r] - m), e1 = __expf(acc1[r] - m);
        float s = e0 + e1;
        s += __shfl_xor(s, 1, 64); s += __shfl_xor(s, 2, 64);
        s += __shfl_xor(s, 4, 64); s += __shfl_xor(s, 8, 64);
        const float inv = 1.f / s;
        const int prow = w * 16 + ((lane >> 4) << 2) + r;
        Pl[prow][l15] = f2bf(e0 * inv);
        Pl[prow][l15 + 16] = f2bf(e1 * inv);
    }
    __syncthreads();
    const short8 pa = lds_frag(&Pl[w * 16 + l15][kg]);
    const float ga = gav[0];
    const int gmb = m0 + w * 16 + ((lane >> 4) << 2);
    for (int jd = 0; jd < 48; jd++) {
        const short8 bf = lds_frag(&repT[jd * 16 + l15][kg]);
        f32x4 av = (f32x4){0.f,0.f,0.f,0.f};
        av = __builtin_amdgcn_mfma_f32_16x16x32_bf16(pa, bf, av, 0, 0, 0);
        const int gd = jd * 16 + l15;
        #pragma unroll
        for (int r = 0; r < 4; r++) {
            if (gmb + r < NN) {
                const long long idx = ((long long)b * NN + gmb + r) * DD0 + gd;
                xT[idx] += ga * av[r];
            }
        }
    }
}

// ---------------- mvq[b][d] = aq1[b][d] * mean_n vq1[b][n][d]  (grid 3 x B) ----
__global__ void mvq_kernel(const float* __restrict__ vq1, const float* __restrict__ aq1,
                           float* __restrict__ mvq)
{
    int b = blockIdx.y, d = blockIdx.x * 256 + threadIdx.x;
    float s = 0.f;
    for (int n = 0; n < NN; n++) s += vq1[((long long)b * NN + n) * DD0 + d];
    mvq[b * DD0 + d] = aq1[b * DD0 + d] * s * (1.f / (float)NN);
}

// ---------------- stmp_dot: st[b][n]=tanh(s), ssig[b][n]=sigmoid(s) ----------
// s = cq[b][n]·(aq2[b]*vs_w) + vs_b.  grid (49, B), 4 waves = 4 rows/block.
__global__ __launch_bounds__(256)
void stmp_dot(const float* __restrict__ cq, const float* __restrict__ aq2,
              const float* __restrict__ vsw, const float* __restrict__ vsb,
              float* __restrict__ stb, float* __restrict__ ssig)
{
    const int b = blockIdx.y, tid = threadIdx.x, w = tid >> 6, lane = tid & 63;
    __shared__ float wv[DM];
    for (int i = tid; i < DM; i += 256) wv[i] = aq2[b * DM + i] * vsw[i];
    __syncthreads();
    const int n = blockIdx.x * 4 + w;   // 49*4 = 196 exactly
    const float* cr = cq + ((long long)b * NN + n) * DM;
    float s = 0.f;
    for (int d = lane; d < DM; d += 64) s += cr[d] * wv[d];
    s = wave_allsum(s);
    if (lane == 0) {
        const float sv = s + vsb[0];
        stb[b * NN + n] = tanhf(sv);
        ssig[b * NN + n] = 1.f / (1.f + expf(-sv));
    }
}

// ---------------- stmp_soft: spatt[b] = softmax_n(st[b]) ----------------
__global__ __launch_bounds__(256)
void stmp_soft(const float* __restrict__ stb, float* __restrict__ spatt)
{
    const int b = blockIdx.x, tid = threadIdx.x;
    __shared__ float sb[4];
    float v = (tid < NN) ? stb[b * NN + tid] : -1e30f;
    float mx = block_max256(v, sb);
    __syncthreads();
    float e = (tid < NN) ? __expf(v - mx) : 0.f;
    float s = block_sum256(e, sb);
    if (tid < NN) spatt[b * NN + tid] = e / s;
}

// ---------------- gating scale + LayerNorm (lnb) in place on xT ----------------
__global__ __launch_bounds__(256)
void scale_ln_kernel(float* __restrict__ xT, const float* __restrict__ chatt,
                     const float* __restrict__ ssig, const float* __restrict__ g,
                     const float* __restrict__ bb)
{
    int b = blockIdx.y, n = blockIdx.x, tid = threadIdx.x;
    __shared__ float sb[4];
    float* xr = xT + ((long long)b * NN + n) * DD0;
    float ss = ssig[b * NN + n];
    float v[3];
    float lsum = 0.f;
    #pragma unroll
    for (int i = 0; i < 3; i++) {
        int d = tid + i * 256;
        float sc = 0.3f * chatt[b * DD0 + d] + 0.05f * ss + 0.7f;
        v[i] = xr[d] * sc;
        lsum += v[i];
    }
    float mean = block_sum256(lsum, sb) * (1.f / (float)DD0);
    float lvar = 0.f;
    #pragma unroll
    for (int i = 0; i < 3; i++) { float dd = v[i] - mean; lvar += dd * dd; }
    float var = block_sum256(lvar, sb) * (1.f / (float)DD0);
    float inv = rsqrtf(var + EPS);
    #pragma unroll
    for (int i = 0; i < 3; i++) {
        int d = tid + i * 256;
        xr[d] = (v[i] - mean) * inv * g[d] + bb[d];
    }
}

// ---------------- BN stats ----------------
// grid (4, B): each block covers 49 n-rows of batch b
__global__ void bn1stats_kernel(const float* __restrict__ y1, float* __restrict__ stats)
{
    int b = blockIdx.y, n0 = blockIdx.x * 49, tid = threadIdx.x;
    if (tid < DDB) {
        float s = 0.f, q = 0.f;
        for (int n = n0; n < n0 + 49; n++) {
            float v = y1[((long long)b * NN + n) * DDB + tid];
            s += v; q += v * v;
        }
        atomicAdd(&stats[tid], s);
        atomicAdd(&stats[DDB + tid], q);
    }
}

__global__ void bn1apply_kernel(float* __restrict__ y1, const float* __restrict__ stats,
                                const float* __restrict__ g, const float* __restrict__ bb)
{
    long long i = (long long)blockIdx.x * 256 + threadIdx.x;
    if (i >= (long long)BB * NN * DDB) return;
    int e = (int)(i % DDB);
    const float cnt = (float)(BB * NN);
    float mu = stats[e] / cnt;
    float var = stats[DDB + e] / cnt - mu * mu;
    float v = (y1[i] - mu) * rsqrtf(var + EPS) * g[e] + bb[e];
    y1[i] = fmaxf(v, 0.f);
}

__global__ void bn2stats_kernel(const float* __restrict__ y2, float* __restrict__ stats)
{
    int b = blockIdx.y, d = blockIdx.x * 256 + threadIdx.x;
    float s = 0.f, q = 0.f;
    for (int n = 0; n < NN; n++) {
        float v = y2[((long long)b * NN + n) * DD0 + d];
        s += v; q += v * v;
    }
    atomicAdd(&stats[d], s);
    atomicAdd(&stats[DD0 + d], q);
}

// ---------------- BN2 + LN(lnp) + gate -> out_tmp[b][n][d] ----------------
__global__ __launch_bounds__(256)
void final_kernel(const float* __restrict__ y2, const float* __restrict__ stats2,
                  const float* __restrict__ g2, const float* __restrict__ b2,
                  const float* __restrict__ lg, const float* __restrict__ lb,
                  const float* __restrict__ gate, float* __restrict__ out_tmp)
{
    int b = blockIdx.y, n = blockIdx.x, tid = threadIdx.x;
    __shared__ float sb[4];
    const float* yr = y2 + ((long long)b * NN + n) * DD0;
    const float cnt = (float)(BB * NN);
    float v[3];
    float lsum = 0.f;
    #pragma unroll
    for (int i = 0; i < 3; i++) {
        int d = tid + i * 256;
        float mu = stats2[d] / cnt;
        float var = stats2[DD0 + d] / cnt - mu * mu;
        v[i] = (yr[d] - mu) * rsqrtf(var + EPS) * g2[d] + b2[d];
        lsum += v[i];
    }
    float mean = block_sum256(lsum, sb) * (1.f / (float)DD0);
    float lvar = 0.f;
    #pragma unroll
    for (int i = 0; i < 3; i++) { float dd = v[i] - mean; lvar += dd * dd; }
    float var = block_sum256(lvar, sb) * (1.f / (float)DD0);
    float inv = rsqrtf(var + EPS);
    float gt = gate[0];
    float* orow = out_tmp + ((long long)b * NN + n) * DD0;
    #pragma unroll
    for (int i = 0; i < 3; i++) {
        int d = tid + i * 256;
        orow[d] = ((v[i] - mean) * inv * lg[d] + lb[d]) * gt;
    }
}

// ======================= launch =======================
extern "C" void kernel_launch(void* const* d_in, const int* in_sizes, int n_in,
                              void* d_out, int out_size, void* d_ws, size_t ws_size,
                              hipStream_t stream)
{
    const float* x       = (const float*)d_in[0];
    const float* vis     = (const float*)d_in[1];
    const float* conv_w  = (const float*)d_in[2];
    const float* conv_b  = (const float*)d_in[3];
    const float* fc_w    = (const float*)d_in[4];
    const float* fc_b    = (const float*)d_in[5];
    const float* a1_w    = (const float*)d_in[6];
    const float* a1_b    = (const float*)d_in[7];
    const float* v1_w    = (const float*)d_in[8];
    const float* v1_b    = (const float*)d_in[9];
    const float* btl_w   = (const float*)d_in[10];
    const float* btl_b   = (const float*)d_in[11];
    const float* v2_w    = (const float*)d_in[12];
    const float* v2_b    = (const float*)d_in[13];
    const float* a2_w    = (const float*)d_in[14];
    const float* a2_b    = (const float*)d_in[15];
    const float* vs_w    = (const float*)d_in[16];
    const float* vs_b    = (const float*)d_in[17];
    const float* vc_w    = (const float*)d_in[18];
    const float* vc_b    = (const float*)d_in[19];
    const float* my_tok  = (const float*)d_in[20];
    const float* gate_av = (const float*)d_in[21];
    const float* gate    = (const float*)d_in[22];
    const float* down_w  = (const float*)d_in[23];
    const float* up_w    = (const float*)d_in[24];
    const float* bn1_g   = (const float*)d_in[25];
    const float* bn1_b   = (const float*)d_in[26];
    const float* bn2_g   = (const float*)d_in[27];
    const float* bn2_b   = (const float*)d_in[28];
    const float* lnb_g   = (const float*)d_in[29];
    const float* lnb_b   = (const float*)d_in[30];
    const float* lnp_g   = (const float*)d_in[31];
    const float* lnp_b   = (const float*)d_in[32];

    float* ws = (float*)d_ws;
    unsigned short* vtc_bf = (unsigned short*)(ws + OFF_A);
    float* vq1     = ws + OFF_A;
    float* cq      = ws + OFF_A;
    float* y2      = ws + OFF_A;
    float* vtf     = ws + OFF_B;
    float* out_tmp = ws + OFF_B;
    float* xT      = ws + OFF_XT;
    float* rep     = ws + OFF_REP;
    float* y1      = ws + OFF_Y1;
    unsigned short* wconv = (unsigned short*)(ws + OFF_WCONV);
    unsigned short* wfc   = (unsigned short*)(ws + OFF_WFC);
    unsigned short* wv1   = (unsigned short*)(ws + OFF_WV1);
    unsigned short* wv2   = (unsigned short*)(ws + OFF_WV2);
    unsigned short* wdown = (unsigned short*)(ws + OFF_WDOWN);
    unsigned short* wup   = (unsigned short*)(ws + OFF_WUP);
    float* audio   = ws + OFF_AUDIO;
    float* aq1b    = ws + OFF_AQ1;
    float* mvqb    = ws + OFF_MVQ;
    float* avqb    = ws + OFF_AVQ;
    float* chattb  = ws + OFF_CHATT;
    float* aq2b    = ws + OFF_AQ2;
    float* ssigb   = ws + OFF_SSIG;
    float* stats1  = ws + OFF_STATS;
    float* stats2  = ws + OFF_STATS + 2 * DDB;
    unsigned short* pbuf = (unsigned short*)(ws + OFF_PBUF);
    float* stbuf   = ws + OFF_STMP;

    float* out   = (float*)d_out;
    float* spatt = out + (long long)BB * DD0 * NN;

    hipMemsetAsync(stats1, 0, (2 * DDB + 2 * DD0) * sizeof(float), stream);

    // 0. weight conversions (f32 -> bf16)
    cvt_f2bf<<<(DD0 * LIN / 4 + 255) / 256, 256, 0, stream>>>(fc_w, wfc, DD0 * LIN);
    cvt_f2bf<<<(DD0 * DD0 / 4 + 255) / 256, 256, 0, stream>>>(v1_w, wv1, DD0 * DD0);
    cvt_f2bf<<<(DM * DD0 / 4 + 255) / 256, 256, 0, stream>>>(v2_w, wv2, DM * DD0);
    cvt_f2bf<<<(DDB * DD0 / 4 + 255) / 256, 256, 0, stream>>>(down_w, wdown, DDB * DD0);
    cvt_f2bf<<<(DD0 * DDB / 4 + 255) / 256, 256, 0, stream>>>(up_w, wup, DD0 * DDB);
    cvt_f2bf_pad<<<(COUT * 200 + 255) / 256, 256, 0, stream>>>(conv_w, wconv, COUT, CIN, 200);

    // 1. x -> xT
    transpose_kernel<<<dim3(7, 24, BB), dim3(32, 8), 0, stream>>>(x, xT, DD0, NN);
    // 2. conv (MFMA) -> vtc_bf   (Ka=200: wconv zero-padded)
    gemm_mfma<1, true, false, false, 0, false><<<dim3(NCONV / 128, 2), 256, 0, stream>>>(
        wconv, 200, vis, CIN, conv_b, nullptr, vtc_bf, COUT, NCONV, CIN, 200);
    // 3. fc (MFMA) -> vtf f32
    gemm_mfma<0, true, true, false, 0, false><<<dim3(DD0 / 128, MFLAT / 128), 256, 0, stream>>>(
        vtc_bf, LIN, wfc, LIN, fc_b, nullptr, vtf, MFLAT, DD0, LIN, LIN);
    // 4. audio
    audio_kernel<<<dim3(3, BB), 256, 0, stream>>>(vtf, audio);
    // 5. att1 (MFMA)
    att1_scores<<<BB, 256, 0, stream>>>(vtf, my_tok, pbuf);
    att1_pv<<<dim3(6, BB), 256, 0, stream>>>(vtf, pbuf, my_tok, rep);
    // 6. att2 (MFMA, fused)
    att2_mfma<<<dim3(4, BB), 256, 0, stream>>>(rep, gate_av, xT);
    // 7. aq1 = relu(audio@a1^T+b)
    wave_gemv<1><<<BB * DD0 / 4, 256, 0, stream>>>(audio, DD0, a1_w, DD0, a1_b, aq1b, DD0, DD0);
    // 8. vq1 (MFMA) relu
    gemm_mfma<0, false, true, false, 1, false><<<dim3(DD0 / 128, MFLAT / 128), 256, 0, stream>>>(
        xT, DD0, wv1, DD0, v1_b, nullptr, vq1, MFLAT, DD0, DD0, DD0);
    // 9. mvq
    mvq_kernel<<<dim3(3, BB), 256, 0, stream>>>(vq1, aq1b, mvqb);
    // 10. avq = relu(mvq@btl^T+b)
    wave_gemv<1><<<BB * DM / 4, 256, 0, stream>>>(mvqb, DD0, btl_w, DD0, btl_b, avqb, DM, DD0);
    // 11. ch_att = sigmoid(avq@vc^T+b)
    wave_gemv<2><<<BB * DD0 / 4, 256, 0, stream>>>(avqb, DM, vc_w, DM, vc_b, chattb, DD0, DM);
    // 12. aq2 = relu(audio@a2^T+b)
    wave_gemv<1><<<BB * DM / 4, 256, 0, stream>>>(audio, DD0, a2_w, DD0, a2_b, aq2b, DM, DD0);
    // 13. c_q (MFMA) relu, k-scale
    gemm_mfma<0, false, true, true, 1, false><<<dim3(DM / 128, MFLAT / 128), 256, 0, stream>>>(
        xT, DD0, wv2, DD0, v2_b, chattb, cq, MFLAT, DM, DD0, DD0);
    // 14. s_tmp: dot (grid 49xB) + softmax (grid B)
    stmp_dot<<<dim3(49, BB), 256, 0, stream>>>(cq, aq2b, vs_w, vs_b, stbuf, ssigb);
    stmp_soft<<<BB, 256, 0, stream>>>(stbuf, spatt);
    // 15. scale + ln_before
    scale_ln_kernel<<<dim3(NN, BB), 256, 0, stream>>>(xT, chattb, ssigb, lnb_g, lnb_b);
    // 16. down (MFMA, N=96 guarded): y1 = xT@down^T
    gemm_mfma<0, false, true, false, 0, true><<<dim3(1, MFLAT / 128), 256, 0, stream>>>(
        xT, DD0, wdown, DD0, nullptr, nullptr, y1, MFLAT, DDB, DD0, DD0);
    // 17-18. BN1 (stats grid 4xB)
    bn1stats_kernel<<<dim3(4, BB), 128, 0, stream>>>(y1, stats1);
    bn1apply_kernel<<<(BB * NN * DDB + 255) / 256, 256, 0, stream>>>(y1, stats1, bn1_g, bn1_b);
    // 19. up (MFMA): y2 = z@up^T
    gemm_mfma<0, false, true, false, 0, false><<<dim3(DD0 / 128, MFLAT / 128), 256, 0, stream>>>(
        y1, DDB, wup, DDB, nullptr, nullptr, y2, MFLAT, DD0, DDB, DDB);
    // 20. BN2 stats
    bn2stats_kernel<<<dim3(3, BB), 256, 0, stream>>>(y2, stats2);
    // 21. BN2 + LN + gate
    final_kernel<<<dim3(NN, BB), 256, 0, stream>>>(y2, stats2, bn2_g, bn2_b,
                                                   lnp_g, lnp_b, gate, out_tmp);
    // 22. out_tmp -> out
    transpose_kernel<<<dim3(24, 7, BB), dim3(32, 8), 0, stream>>>(out_tmp, out, NN, DD0);
}

// Round 8
// 860.304 us; speedup vs baseline: 2.9222x; 1.0816x over previous
//
#include <hip/hip_runtime.h>
#include <math.h>

// ---- problem constants ----
#define BB 64
#define DD0 768
#define NN 196
#define LIN 1536
#define CIN 196
#define COUT 196
#define TT 32
#define DM 384
#define DDB 96
#define EPS 1e-5f
#define MFLAT (BB * NN)          // 12544
#define NCONV (BB * LIN)         // 98304

// ---- workspace layout (float offsets) ----
#define OFF_A     0LL            // vtc_bf16 -> vq1 f32 -> cq f32 -> y2 f32
#define OFF_B     9633792LL      // vtf f32 -> out_tmp f32
#define OFF_XT    19267584LL     // xT f32
#define OFF_REP   28901376LL     // rep f32
#define OFF_Y1    30474240LL     // y1 f32
#define OFF_WCONV 31678464LL     // 196x200 ushort padded
#define OFF_WFC   31698064LL     // 768x1536 ushort
#define OFF_WV1   32287888LL     // 768x768  ushort
#define OFF_WV2   32582800LL     // 384x768  ushort
#define OFF_SM    32730256LL
#define OFF_AUDIO (OFF_SM)
#define OFF_AQ1   (OFF_SM+49152)
#define OFF_MVQ   (OFF_SM+98304)
#define OFF_AVQ   (OFF_SM+147456)
#define OFF_CHATT (OFF_SM+172032)
#define OFF_AQ2   (OFF_SM+221184)
#define OFF_SSIG  (OFF_SM+245760)
#define OFF_STATS (OFF_SM+258304)
#define OFF_PBUF  (OFF_SM+262144)   // att1 P: 64*32*224 ushort = 229376 f
#define OFF_WDOWN (OFF_SM+491520)   // 96x768 ushort = 36864 f
#define OFF_WUP   (OFF_SM+528384)   // 768x96 ushort = 36864 f
#define OFF_STMP  (OFF_SM+565248)   // st_buf: 64*196 f = 12544 f
#define OFF_XTBF  (OFF_SM+577792)   // xT bf16: 12544*768 ushort = 4,816,896 f

typedef __attribute__((ext_vector_type(8))) short short8;
typedef __attribute__((ext_vector_type(4))) float f32x4;

__device__ __forceinline__ unsigned short f2bf(float f) {
    union { float f; unsigned u; } v; v.f = f;
    unsigned r = v.u + 0x7fffu + ((v.u >> 16) & 1u);
    return (unsigned short)(r >> 16);
}
__device__ __forceinline__ short8 cvt8(const float4 a, const float4 b) {
    short8 r;
    r[0] = (short)f2bf(a.x); r[1] = (short)f2bf(a.y); r[2] = (short)f2bf(a.z); r[3] = (short)f2bf(a.w);
    r[4] = (short)f2bf(b.x); r[5] = (short)f2bf(b.y); r[6] = (short)f2bf(b.z); r[7] = (short)f2bf(b.w);
    return r;
}
__device__ __forceinline__ short8 lds_frag(const unsigned short* p) {
    short4 lo = *(const short4*)p;
    short4 hi = *(const short4*)(p + 4);
    short8 r;
    r[0] = lo.x; r[1] = lo.y; r[2] = lo.z; r[3] = lo.w;
    r[4] = hi.x; r[5] = hi.y; r[6] = hi.z; r[7] = hi.w;
    return r;
}
// async global->LDS, 16B per lane; LDS dest = wave-uniform base + lane*16
__device__ __forceinline__ void gload16(const void* g, void* l) {
    __builtin_amdgcn_global_load_lds(
        (const __attribute__((address_space(1))) unsigned int*)g,
        (__attribute__((address_space(3))) unsigned int*)l, 16, 0, 0);
}
// bijective XCD-chunk swizzle (m204): consecutive new-ids land on one XCD
__device__ __forceinline__ int xcd_swizzle(int orig, int nwg) {
    const int q = nwg >> 3, r = nwg & 7;
    const int x = orig & 7, lo = orig >> 3;
    return (x < r ? x * (q + 1) : r * (q + 1) + (x - r) * q) + lo;
}

// ---------------- reduction helpers ----------------
__device__ __forceinline__ float warp_sum(float v) {
    for (int o = 32; o; o >>= 1) v += __shfl_down(v, o, 64);
    return v;
}
__device__ __forceinline__ float wave_allsum(float v) {
    for (int o = 1; o < 64; o <<= 1) v += __shfl_xor(v, o, 64);
    return v;
}
__device__ __forceinline__ float wave_allmax(float v) {
    for (int o = 1; o < 64; o <<= 1) v = fmaxf(v, __shfl_xor(v, o, 64));
    return v;
}
__device__ __forceinline__ float warp_max(float v) {
    for (int o = 32; o; o >>= 1) v = fmaxf(v, __shfl_down(v, o, 64));
    return v;
}
__device__ __forceinline__ float block_sum256(float v, float* sb) {
    v = warp_sum(v);
    __syncthreads();
    if ((threadIdx.x & 63) == 0) sb[threadIdx.x >> 6] = v;
    __syncthreads();
    return sb[0] + sb[1] + sb[2] + sb[3];
}
__device__ __forceinline__ float block_max256(float v, float* sb) {
    v = warp_max(v);
    __syncthreads();
    if ((threadIdx.x & 63) == 0) sb[threadIdx.x >> 6] = v;
    __syncthreads();
    return fmaxf(fmaxf(sb[0], sb[1]), fmaxf(sb[2], sb[3]));
}

// ============== bf16 GEMM via global_load_lds (fc, vq1) ==============
// All dims exact: M%128==0 (grid-y), N%128==0, K%64==0. A,B bf16 row-major NT.
// LDS linear [128][64] bf16; XOR involution swz(row,byte)=byte^((row&7)<<4)
// applied on SOURCE address (stage) and on READ address -> bank-spread, rule #21.
template<int EPI>
__global__ __launch_bounds__(256)
void gemm_gll(const unsigned short* __restrict__ Ap, int lda,
              const unsigned short* __restrict__ Bp, int ldb,
              const float* __restrict__ bias,
              float* __restrict__ Cp, int N, int K)
{
    __shared__ unsigned short Asm[128 * 64];
    __shared__ unsigned short Bsm[128 * 64];
    const int nwg = gridDim.x * gridDim.y;
    const int wg = xcd_swizzle(blockIdx.y * gridDim.x + blockIdx.x, nwg);
    const int m0 = (wg / gridDim.x) * 128, n0 = (wg % gridDim.x) * 128;

    const int tid = threadIdx.x, w = tid >> 6, lane = tid & 63;
    const int wr = w >> 1, wc = w & 1;
    // staging: chunk c covers rows [c*8, c*8+8); lane l -> row c*8+(l>>3),
    // LDS byte-in-row (l&7)*16; source byte-in-row pre-swizzled:
    const int soff = ((lane & 7) << 4) ^ ((lane >> 3) << 4);
    const int arow = (lane >> 3);

    f32x4 acc[4][4];
    #pragma unroll
    for (int i = 0; i < 4; i++)
        #pragma unroll
        for (int j = 0; j < 4; j++) acc[i][j] = (f32x4){0.f, 0.f, 0.f, 0.f};

    for (int k0 = 0; k0 < K; k0 += 64) {
        #pragma unroll
        for (int q = 0; q < 4; q++) {
            const int c = w * 4 + q;
            const int row = c * 8 + arow;
            const char* g = (const char*)Ap + (((long long)(m0 + row) * lda + k0) << 1) + soff;
            gload16(g, (char*)Asm + c * 1024);
        }
        #pragma unroll
        for (int q = 0; q < 4; q++) {
            const int c = w * 4 + q;
            const int row = c * 8 + arow;
            const char* g = (const char*)Bp + (((long long)(n0 + row) * ldb + k0) << 1) + soff;
            gload16(g, (char*)Bsm + c * 1024);
        }
        __syncthreads();   // drains vmcnt (gload_lds) before ds_read
        #pragma unroll
        for (int kk = 0; kk < 2; kk++) {
            const int kb = kk * 64 + ((lane >> 4) << 4);
            const int swz = (lane & 7) << 4;   // row&7 == lane&7 for all fragments
            short8 af[4], bfr[4];
            #pragma unroll
            for (int i = 0; i < 4; i++) {
                const int ra = wr * 64 + i * 16 + (lane & 15);
                af[i] = *(const short8*)((const char*)Asm + ra * 128 + (kb ^ swz));
            }
            #pragma unroll
            for (int j = 0; j < 4; j++) {
                const int rb = wc * 64 + j * 16 + (lane & 15);
                bfr[j] = *(const short8*)((const char*)Bsm + rb * 128 + (kb ^ swz));
            }
            #pragma unroll
            for (int i = 0; i < 4; i++)
                #pragma unroll
                for (int j = 0; j < 4; j++)
                    acc[i][j] = __builtin_amdgcn_mfma_f32_16x16x32_bf16(af[i], bfr[j], acc[i][j], 0, 0, 0);
        }
        __syncthreads();
    }
    const int cmb = wr * 64 + ((lane >> 4) << 2);
    const int cnb = wc * 64 + (lane & 15);
    #pragma unroll
    for (int i = 0; i < 4; i++) {
        #pragma unroll
        for (int j = 0; j < 4; j++) {
            const int gn = n0 + cnb + j * 16;
            #pragma unroll
            for (int rr = 0; rr < 4; rr++) {
                const int gm = m0 + cmb + i * 16 + rr;
                float v = acc[i][j][rr] + bias[gn];
                if (EPI == 1) v = fmaxf(v, 0.f);
                Cp[(long long)gm * N + gn] = v;
            }
        }
    }
}

// ================= bf16 MFMA GEMM, reg-staging (conv/cq/down/up) =================
template<int MODE, bool ABF, bool BBF, bool KSC, int EPI, bool NG>
__global__ __launch_bounds__(256)
void gemm_mfma(const void* __restrict__ Ap, int lda,
               const void* __restrict__ Bp, int ldb,
               const float* __restrict__ bias, const float* __restrict__ ksc,
               void* __restrict__ Cp, int M, int N, int K, int Ka)
{
    __shared__ unsigned short Asm[128][72];
    __shared__ unsigned short Bsm[128][72];
    const int tid = threadIdx.x;
    const int nwg = gridDim.x * gridDim.y;
    const int wg = xcd_swizzle(blockIdx.y * gridDim.x + blockIdx.x, nwg);
    const int m0 = (wg / gridDim.x) * 128, n0 = (wg % gridDim.x) * 128;
    const int w = tid >> 6, lane = tid & 63;
    const int wr = w >> 1, wc = w & 1;

    f32x4 acc[4][4];
    #pragma unroll
    for (int i = 0; i < 4; i++)
        #pragma unroll
        for (int j = 0; j < 4; j++) acc[i][j] = (f32x4){0.f, 0.f, 0.f, 0.f};

    const int nkt = (K + 63) >> 6;
    for (int kt = 0; kt < nkt; kt++) {
        const int k0 = kt << 6;
        // ---- stage A ----
        if (ABF) {
            #pragma unroll
            for (int q = 0; q < 4; q++) {
                const int row = q * 32 + (tid >> 3);
                const int ce = (tid & 7) * 8;
                const int gm = m0 + row;
                const bool rok = (MODE == 1) ? (gm < M) : true;
                uint4 u = make_uint4(0u, 0u, 0u, 0u);
                if (rok && (k0 + ce) < Ka)
                    u = *(const uint4*)((const unsigned short*)Ap + (long long)gm * lda + k0 + ce);
                *(uint4*)&Asm[row][ce] = u;
            }
        } else {
            #pragma unroll
            for (int q = 0; q < 8; q++) {
                const int row = q * 16 + (tid >> 4);
                const int ce = (tid & 15) * 4;
                const int gm = m0 + row;
                const bool rok = (MODE == 1) ? (gm < M) : true;
                float4 v = make_float4(0.f, 0.f, 0.f, 0.f);
                const bool kok = (k0 + ce) < K;
                if (rok && kok)
                    v = *(const float4*)((const float*)Ap + (long long)gm * lda + k0 + ce);
                if (KSC && kok) {
                    const float* kc = ksc + (gm / 196) * 768 + k0 + ce;
                    v.x *= kc[0] + 1.f; v.y *= kc[1] + 1.f;
                    v.z *= kc[2] + 1.f; v.w *= kc[3] + 1.f;
                }
                ushort4 o; o.x = f2bf(v.x); o.y = f2bf(v.y); o.z = f2bf(v.z); o.w = f2bf(v.w);
                *(ushort4*)&Asm[row][ce] = o;
            }
        }
        // ---- stage B ----
        if (BBF) {
            #pragma unroll
            for (int q = 0; q < 4; q++) {
                const int row = q * 32 + (tid >> 3);
                const int ce = (tid & 7) * 8;
                const int gn = n0 + row;
                const bool nok = NG ? (gn < N) : true;
                uint4 u = make_uint4(0u, 0u, 0u, 0u);
                if (nok && (k0 + ce) < K)
                    u = *(const uint4*)((const unsigned short*)Bp + (long long)gn * ldb + k0 + ce);
                *(uint4*)&Bsm[row][ce] = u;
            }
        } else {
            #pragma unroll
            for (int q = 0; q < 8; q++) {
                const int row = q * 16 + (tid >> 4);
                const int ce = (tid & 15) * 4;
                const int gn = n0 + row;
                const bool nok = NG ? (gn < N) : true;
                float4 v = make_float4(0.f, 0.f, 0.f, 0.f);
                if (nok && (k0 + ce) < K)
                    v = *(const float4*)((const float*)Bp + (long long)gn * ldb + k0 + ce);
                ushort4 o; o.x = f2bf(v.x); o.y = f2bf(v.y); o.z = f2bf(v.z); o.w = f2bf(v.w);
                *(ushort4*)&Bsm[row][ce] = o;
            }
        }
        __syncthreads();
        // ---- MFMA ----
        #pragma unroll
        for (int kk = 0; kk < 2; kk++) {
            short8 af[4], bfr[4];
            const int koff = kk * 32 + (lane >> 4) * 8;
            #pragma unroll
            for (int i = 0; i < 4; i++)
                af[i] = *(const short8*)&Asm[wr * 64 + i * 16 + (lane & 15)][koff];
            #pragma unroll
            for (int j = 0; j < 4; j++)
                bfr[j] = *(const short8*)&Bsm[wc * 64 + j * 16 + (lane & 15)][koff];
            #pragma unroll
            for (int i = 0; i < 4; i++)
                #pragma unroll
                for (int j = 0; j < 4; j++)
                    acc[i][j] = __builtin_amdgcn_mfma_f32_16x16x32_bf16(af[i], bfr[j], acc[i][j], 0, 0, 0);
        }
        __syncthreads();
    }
    // ---- epilogue (C/D layout: col=lane&15, row=(lane>>4)*4+rr) ----
    const int cmb = wr * 64 + ((lane >> 4) << 2);
    const int cnb = wc * 64 + (lane & 15);
    #pragma unroll
    for (int i = 0; i < 4; i++) {
        #pragma unroll
        for (int j = 0; j < 4; j++) {
            const int gn = n0 + cnb + j * 16;
            if (NG && gn >= N) continue;
            #pragma unroll
            for (int rr = 0; rr < 4; rr++) {
                const int gm = m0 + cmb + i * 16 + rr;
                float v = acc[i][j][rr];
                if (MODE == 0) {
                    if (bias) v += bias[gn];
                    if (EPI == 1) v = fmaxf(v, 0.f);
                    ((float*)Cp)[(long long)gm * N + gn] = v;
                } else {
                    if (gm < M) {
                        v += bias[gm];
                        const int b = gn / LIN, l = gn - b * LIN;
                        ((unsigned short*)Cp)[((long long)b * COUT + gm) * LIN + l] = f2bf(v);
                    }
                }
            }
        }
    }
}

// ---------------- weight f32 -> bf16 converters ----------------
__global__ void cvt_f2bf(const float* __restrict__ in, unsigned short* __restrict__ out, int n)
{
    int i = (blockIdx.x * 256 + threadIdx.x) * 4;
    if (i + 4 <= n) {
        float4 v = *(const float4*)(in + i);
        ushort4 o; o.x = f2bf(v.x); o.y = f2bf(v.y); o.z = f2bf(v.z); o.w = f2bf(v.w);
        *(ushort4*)(out + i) = o;
    }
}
__global__ void cvt_f2bf_pad(const float* __restrict__ in, unsigned short* __restrict__ out,
                             int rows, int cols, int ldo)
{
    int i = blockIdx.x * 256 + threadIdx.x;
    if (i < rows * ldo) {
        int r = i / ldo, c = i - r * ldo;
        out[i] = (c < cols) ? f2bf(in[r * cols + c]) : (unsigned short)0;
    }
}

// ---------------- wave-per-output GEMV: C[m][n] = act(A[m]·B[n] + bias[n]) ------
template<int ACT>
__global__ __launch_bounds__(256)
void wave_gemv(const float* __restrict__ A, int lda,
               const float* __restrict__ B, int ldb,
               const float* __restrict__ bias,
               float* __restrict__ C, int N, int K)
{
    const int w = threadIdx.x >> 6, lane = threadIdx.x & 63;
    const long long o = (long long)blockIdx.x * 4 + w;
    const int m = (int)(o / N), n = (int)(o - (long long)m * N);
    const float* ar = A + (long long)m * lda;
    const float* br = B + (long long)n * ldb;
    float s = 0.f;
    for (int k = lane; k < K; k += 64) s += ar[k] * br[k];
    s = wave_allsum(s);
    if (lane == 0) {
        float v = s + bias[n];
        if (ACT == 1) v = fmaxf(v, 0.f);
        if (ACT == 2) v = 1.f / (1.f + expf(-v));
        C[o] = v;
    }
}

// ---------------- transpose: in[b][D][N] -> out[b][N][D] ----------------
__global__ void transpose_kernel(const float* __restrict__ in, float* __restrict__ out,
                                 int D, int N)
{
    __shared__ float tile[32][33];
    int b = blockIdx.z;
    int d0 = blockIdx.y * 32, n0 = blockIdx.x * 32;
    int tx = threadIdx.x, ty = threadIdx.y;
    for (int i = 0; i < 32; i += 8) {
        int d = d0 + ty + i, n = n0 + tx;
        if (d < D && n < N) tile[ty + i][tx] = in[((long long)b * D + d) * N + n];
    }
    __syncthreads();
    for (int i = 0; i < 32; i += 8) {
        int n = n0 + ty + i, d = d0 + tx;
        if (n < N && d < D) out[((long long)b * N + n) * D + d] = tile[tx][ty + i];
    }
}

// ---------------- audio[b][d] = mean_m vtf[b][m][d]  (grid 3 x B) -------------
__global__ void audio_kernel(const float* __restrict__ vtf, float* __restrict__ audio)
{
    int b = blockIdx.y, d = blockIdx.x * 256 + threadIdx.x;
    float s = 0.f;
    for (int m = 0; m < COUT; m++) s += vtf[((long long)b * COUT + m) * DD0 + d];
    audio[b * DD0 + d] = s * (1.f / (float)COUT);
}

// ========== att1 scores: P[b][t][m] = softmax_m(mt[t]·vtf[b][m]) ==========
__global__ __launch_bounds__(256)
void att1_scores(const float* __restrict__ vtf, const float* __restrict__ mt,
                 unsigned short* __restrict__ pbuf)
{
    __shared__ float sc[TT][208];
    const int b = blockIdx.x;
    const int tid = threadIdx.x, w = tid >> 6, lane = tid & 63;
    const int l15 = lane & 15, kg = (lane >> 4) << 3;
    const float* vb = vtf + (long long)b * COUT * DD0;

    f32x4 acc[4][2];
    #pragma unroll
    for (int q = 0; q < 4; q++) { acc[q][0] = (f32x4){0.f,0.f,0.f,0.f}; acc[q][1] = (f32x4){0.f,0.f,0.f,0.f}; }

    for (int kt = 0; kt < DD0; kt += 32) {
        const float* a0p = mt + (long long)l15 * DD0 + kt + kg;
        const float* a1p = a0p + 16 * DD0;
        short8 a0 = cvt8(*(const float4*)a0p, *(const float4*)(a0p + 4));
        short8 a1 = cvt8(*(const float4*)a1p, *(const float4*)(a1p + 4));
        #pragma unroll
        for (int q = 0; q < 4; q++) {
            const int mtile = w + q * 4;
            const int gm = mtile * 16 + l15;
            short8 bf = {0,0,0,0,0,0,0,0};
            if (gm < COUT) {
                const float* bp = vb + (long long)gm * DD0 + kt + kg;
                bf = cvt8(*(const float4*)bp, *(const float4*)(bp + 4));
            }
            acc[q][0] = __builtin_amdgcn_mfma_f32_16x16x32_bf16(a0, bf, acc[q][0], 0, 0, 0);
            acc[q][1] = __builtin_amdgcn_mfma_f32_16x16x32_bf16(a1, bf, acc[q][1], 0, 0, 0);
        }
    }
    #pragma unroll
    for (int q = 0; q < 4; q++) {
        const int mtile = w + q * 4;
        if (mtile < 13) {
            #pragma unroll
            for (int j = 0; j < 2; j++)
                #pragma unroll
                for (int r = 0; r < 4; r++)
                    sc[j * 16 + ((lane >> 4) << 2) + r][mtile * 16 + l15] = acc[q][j][r];
        }
    }
    __syncthreads();
    for (int tr = 0; tr < 8; tr++) {
        const int t = w * 8 + tr;
        float v = -1e30f;
        for (int m = lane; m < COUT; m += 64) v = fmaxf(v, sc[t][m]);
        v = wave_allmax(v);
        float s = 0.f;
        for (int m = lane; m < COUT; m += 64) { float e = __expf(sc[t][m] - v); sc[t][m] = e; s += e; }
        s = wave_allsum(s);
        const float inv = 1.f / s;
        unsigned short* pr = pbuf + ((long long)b * TT + t) * 224;
        for (int m = lane; m < 224; m += 64) pr[m] = (m < COUT) ? f2bf(sc[t][m] * inv) : (unsigned short)0;
    }
}

// ========== att1 PV: rep[b][t][d] = mt[t][d] + sum_m P[t][m]·vtf[b][m][d] ======
__global__ __launch_bounds__(256)
void att1_pv(const float* __restrict__ vtf, const unsigned short* __restrict__ pbuf,
             const float* __restrict__ mt, float* __restrict__ rep)
{
    __shared__ unsigned short vT[128][36];
    const int b = blockIdx.y, d0 = blockIdx.x * 128;
    const int tid = threadIdx.x, w = tid >> 6, lane = tid & 63;
    const int l15 = lane & 15, kg = (lane >> 4) << 3;
    const float* vb = vtf + (long long)b * COUT * DD0;

    f32x4 acc[2][2];
    acc[0][0] = (f32x4){0.f,0.f,0.f,0.f}; acc[0][1] = (f32x4){0.f,0.f,0.f,0.f};
    acc[1][0] = (f32x4){0.f,0.f,0.f,0.f}; acc[1][1] = (f32x4){0.f,0.f,0.f,0.f};

    for (int kc = 0; kc < 7; kc++) {
        for (int i = tid; i < 32 * 128; i += 256) {
            const int m = i >> 7, dd = i & 127;
            const int gm = kc * 32 + m;
            const float v = (gm < COUT) ? vb[(long long)gm * DD0 + d0 + dd] : 0.f;
            vT[dd][m] = f2bf(v);
        }
        const short8 p0 = *(const short8*)(pbuf + ((long long)b * TT + l15) * 224 + kc * 32 + kg);
        const short8 p1 = *(const short8*)(pbuf + ((long long)b * TT + 16 + l15) * 224 + kc * 32 + kg);
        __syncthreads();
        #pragma unroll
        for (int jl = 0; jl < 2; jl++) {
            const short8 bf = lds_frag(&vT[(w * 2 + jl) * 16 + l15][kg]);
            acc[0][jl] = __builtin_amdgcn_mfma_f32_16x16x32_bf16(p0, bf, acc[0][jl], 0, 0, 0);
            acc[1][jl] = __builtin_amdgcn_mfma_f32_16x16x32_bf16(p1, bf, acc[1][jl], 0, 0, 0);
        }
        __syncthreads();
    }
    #pragma unroll
    for (int j = 0; j < 2; j++) {
        #pragma unroll
        for (int jl = 0; jl < 2; jl++) {
            const int t = j * 16 + ((lane >> 4) << 2);
            const int gd = d0 + (w * 2 + jl) * 16 + l15;
            #pragma unroll
            for (int r = 0; r < 4; r++)
                rep[((long long)b * TT + t + r) * DD0 + gd] = mt[(long long)(t + r) * DD0 + gd] + acc[j][jl][r];
        }
    }
}

// ========== att2 fused: xT[n] += gate_av * softmax_t(xT[n]·rep[t]) @ rep ======
__global__ __launch_bounds__(256)
void att2_mfma(const float* __restrict__ rep, const float* __restrict__ gav,
               float* __restrict__ xT)
{
    __shared__ unsigned short repT[DD0][36];
    __shared__ unsigned short Pl[64][36];
    const int b = blockIdx.y, m0 = blockIdx.x * 64;
    const int tid = threadIdx.x, w = tid >> 6, lane = tid & 63;
    const int l15 = lane & 15, kg = (lane >> 4) << 3;
    const float* repb = rep + (long long)b * TT * DD0;

    for (int i = tid; i < TT * DD0; i += 256) {
        const int t = i / DD0, d = i - t * DD0;
        repT[d][t] = f2bf(repb[i]);
    }
    __syncthreads();

    f32x4 acc0 = (f32x4){0.f,0.f,0.f,0.f}, acc1 = (f32x4){0.f,0.f,0.f,0.f};
    const int arow = m0 + w * 16 + l15;
    const bool rok = arow < NN;
    const float* xrow = xT + ((long long)b * NN + arow) * DD0;
    for (int kt = 0; kt < DD0; kt += 32) {
        short8 af = {0,0,0,0,0,0,0,0};
        if (rok) af = cvt8(*(const float4*)(xrow + kt + kg), *(const float4*)(xrow + kt + kg + 4));
        const float* r0 = repb + (long long)l15 * DD0 + kt + kg;
        const float* r1 = r0 + 16 * DD0;
        const short8 b0 = cvt8(*(const float4*)r0, *(const float4*)(r0 + 4));
        const short8 b1 = cvt8(*(const float4*)r1, *(const float4*)(r1 + 4));
        acc0 = __builtin_amdgcn_mfma_f32_16x16x32_bf16(af, b0, acc0, 0, 0, 0);
        acc1 = __builtin_amdgcn_mfma_f32_16x16x32_bf16(af, b1, acc1, 0, 0, 0);
    }
    #pragma unroll
    for (int r = 0; r < 4; r++) {
        float m = fmaxf(acc0[r], acc1[r]);
        m = fmaxf(m, __shfl_xor(m, 1, 64));
        m = fmaxf(m, __shfl_xor(m, 2, 64));
        m = fmaxf(m, __shfl_xor(m, 4, 64));
        m = fmaxf(m, __shfl_xor(m, 8, 64));
        const float e0 = __expf(acc0[r] - m), e1 = __expf(acc1[r] - m);
        float s = e0 + e1;
        s += __shfl_xor(s, 1, 64); s += __shfl_xor(s, 2, 64);
        s += __shfl_xor(s, 4, 64); s += __shfl_xor(s, 8, 64);
        const float inv = 1.f / s;
        const int prow = w * 16 + ((lane >> 4) << 2) + r;
        Pl[prow][l15] = f2bf(e0 * inv);
        Pl[prow][l15 + 16] = f2bf(e1 * inv);
    }
    __syncthreads();
    const short8 pa = lds_frag(&Pl[w * 16 + l15][kg]);
    const float ga = gav[0];
    const int gmb = m0 + w * 16 + ((lane >> 4) << 2);
    for (int jd = 0; jd < 48; jd++) {
        const short8 bf = lds_frag(&repT[jd * 16 + l15][kg]);
        f32x4 av = (f32x4){0.f,0.f,0.f,0.f};
        av = __builtin_amdgcn_mfma_f32_16x16x32_bf16(pa, bf, av, 0, 0, 0);
        const int gd = jd * 16 + l15;
        #pragma unroll
        for (int r = 0; r < 4; r++) {
            if (gmb + r < NN) {
                const long long idx = ((long long)b * NN + gmb + r) * DD0 + gd;
                xT[idx] += ga * av[r];
            }
        }
    }
}

// ---------------- mvq[b][d] = aq1[b][d] * mean_n vq1[b][n][d]  (grid 3 x B) ----
__global__ void mvq_kernel(const float* __restrict__ vq1, const float* __restrict__ aq1,
                           float* __restrict__ mvq)
{
    int b = blockIdx.y, d = blockIdx.x * 256 + threadIdx.x;
    float s = 0.f;
    for (int n = 0; n < NN; n++) s += vq1[((long long)b * NN + n) * DD0 + d];
    mvq[b * DD0 + d] = aq1[b * DD0 + d] * s * (1.f / (float)NN);
}

// ---------------- stmp_dot: st[b][n]=tanh(s), ssig[b][n]=sigmoid(s) ----------
__global__ __launch_bounds__(256)
void stmp_dot(const float* __restrict__ cq, const float* __restrict__ aq2,
              const float* __restrict__ vsw, const float* __restrict__ vsb,
              float* __restrict__ stb, float* __restrict__ ssig)
{
    const int b = blockIdx.y, tid = threadIdx.x, w = tid >> 6, lane = tid & 63;
    __shared__ float wv[DM];
    for (int i = tid; i < DM; i += 256) wv[i] = aq2[b * DM + i] * vsw[i];
    __syncthreads();
    const int n = blockIdx.x * 4 + w;   // 49*4 = 196 exactly
    const float* cr = cq + ((long long)b * NN + n) * DM;
    float s = 0.f;
    for (int d = lane; d < DM; d += 64) s += cr[d] * wv[d];
    s = wave_allsum(s);
    if (lane == 0) {
        const float sv = s + vsb[0];
        stb[b * NN + n] = tanhf(sv);
        ssig[b * NN + n] = 1.f / (1.f + expf(-sv));
    }
}

// ---------------- stmp_soft: spatt[b] = softmax_n(st[b]) ----------------
__global__ __launch_bounds__(256)
void stmp_soft(const float* __restrict__ stb, float* __restrict__ spatt)
{
    const int b = blockIdx.x, tid = threadIdx.x;
    __shared__ float sb[4];
    float v = (tid < NN) ? stb[b * NN + tid] : -1e30f;
    float mx = block_max256(v, sb);
    __syncthreads();
    float e = (tid < NN) ? __expf(v - mx) : 0.f;
    float s = block_sum256(e, sb);
    if (tid < NN) spatt[b * NN + tid] = e / s;
}

// ---------------- gating scale + LayerNorm (lnb) in place on xT ----------------
__global__ __launch_bounds__(256)
void scale_ln_kernel(float* __restrict__ xT, const float* __restrict__ chatt,
                     const float* __restrict__ ssig, const float* __restrict__ g,
                     const float* __restrict__ bb)
{
    int b = blockIdx.y, n = blockIdx.x, tid = threadIdx.x;
    __shared__ float sb[4];
    float* xr = xT + ((long long)b * NN + n) * DD0;
    float ss = ssig[b * NN + n];
    float v[3];
    float lsum = 0.f;
    #pragma unroll
    for (int i = 0; i < 3; i++) {
        int d = tid + i * 256;
        float sc = 0.3f * chatt[b * DD0 + d] + 0.05f * ss + 0.7f;
        v[i] = xr[d] * sc;
        lsum += v[i];
    }
    float mean = block_sum256(lsum, sb) * (1.f / (float)DD0);
    float lvar = 0.f;
    #pragma unroll
    for (int i = 0; i < 3; i++) { float dd = v[i] - mean; lvar += dd * dd; }
    float var = block_sum256(lvar, sb) * (1.f / (float)DD0);
    float inv = rsqrtf(var + EPS);
    #pragma unroll
    for (int i = 0; i < 3; i++) {
        int d = tid + i * 256;
        xr[d] = (v[i] - mean) * inv * g[d] + bb[d];
    }
}

// ---------------- BN stats ----------------
__global__ void bn1stats_kernel(const float* __restrict__ y1, float* __restrict__ stats)
{
    int b = blockIdx.y, n0 = blockIdx.x * 49, tid = threadIdx.x;
    if (tid < DDB) {
        float s = 0.f, q = 0.f;
        for (int n = n0; n < n0 + 49; n++) {
            float v = y1[((long long)b * NN + n) * DDB + tid];
            s += v; q += v * v;
        }
        atomicAdd(&stats[tid], s);
        atomicAdd(&stats[DDB + tid], q);
    }
}

__global__ void bn1apply_kernel(float* __restrict__ y1, const float* __restrict__ stats,
                                const float* __restrict__ g, const float* __restrict__ bb)
{
    long long i = (long long)blockIdx.x * 256 + threadIdx.x;
    if (i >= (long long)BB * NN * DDB) return;
    int e = (int)(i % DDB);
    const float cnt = (float)(BB * NN);
    float mu = stats[e] / cnt;
    float var = stats[DDB + e] / cnt - mu * mu;
    float v = (y1[i] - mu) * rsqrtf(var + EPS) * g[e] + bb[e];
    y1[i] = fmaxf(v, 0.f);
}

__global__ void bn2stats_kernel(const float* __restrict__ y2, float* __restrict__ stats)
{
    int b = blockIdx.y, d = blockIdx.x * 256 + threadIdx.x;
    float s = 0.f, q = 0.f;
    for (int n = 0; n < NN; n++) {
        float v = y2[((long long)b * NN + n) * DD0 + d];
        s += v; q += v * v;
    }
    atomicAdd(&stats[d], s);
    atomicAdd(&stats[DD0 + d], q);
}

// ---------------- BN2 + LN(lnp) + gate -> out_tmp[b][n][d] ----------------
__global__ __launch_bounds__(256)
void final_kernel(const float* __restrict__ y2, const float* __restrict__ stats2,
                  const float* __restrict__ g2, const float* __restrict__ b2,
                  const float* __restrict__ lg, const float* __restrict__ lb,
                  const float* __restrict__ gate, float* __restrict__ out_tmp)
{
    int b = blockIdx.y, n = blockIdx.x, tid = threadIdx.x;
    __shared__ float sb[4];
    const float* yr = y2 + ((long long)b * NN + n) * DD0;
    const float cnt = (float)(BB * NN);
    float v[3];
    float lsum = 0.f;
    #pragma unroll
    for (int i = 0; i < 3; i++) {
        int d = tid + i * 256;
        float mu = stats2[d] / cnt;
        float var = stats2[DD0 + d] / cnt - mu * mu;
        v[i] = (yr[d] - mu) * rsqrtf(var + EPS) * g2[d] + b2[d];
        lsum += v[i];
    }
    float mean = block_sum256(lsum, sb) * (1.f / (float)DD0);
    float lvar = 0.f;
    #pragma unroll
    for (int i = 0; i < 3; i++) { float dd = v[i] - mean; lvar += dd * dd; }
    float var = block_sum256(lvar, sb) * (1.f / (float)DD0);
    float inv = rsqrtf(var + EPS);
    float gt = gate[0];
    float* orow = out_tmp + ((long long)b * NN + n) * DD0;
    #pragma unroll
    for (int i = 0; i < 3; i++) {
        int d = tid + i * 256;
        orow[d] = ((v[i] - mean) * inv * lg[d] + lb[d]) * gt;
    }
}

// ======================= launch =======================
extern "C" void kernel_launch(void* const* d_in, const int* in_sizes, int n_in,
                              void* d_out, int out_size, void* d_ws, size_t ws_size,
                              hipStream_t stream)
{
    const float* x       = (const float*)d_in[0];
    const float* vis     = (const float*)d_in[1];
    const float* conv_w  = (const float*)d_in[2];
    const float* conv_b  = (const float*)d_in[3];
    const float* fc_w    = (const float*)d_in[4];
    const float* fc_b    = (const float*)d_in[5];
    const float* a1_w    = (const float*)d_in[6];
    const float* a1_b    = (const float*)d_in[7];
    const float* v1_w    = (const float*)d_in[8];
    const float* v1_b    = (const float*)d_in[9];
    const float* btl_w   = (const float*)d_in[10];
    const float* btl_b   = (const float*)d_in[11];
    const float* v2_w    = (const float*)d_in[12];
    const float* v2_b    = (const float*)d_in[13];
    const float* a2_w    = (const float*)d_in[14];
    const float* a2_b    = (const float*)d_in[15];
    const float* vs_w    = (const float*)d_in[16];
    const float* vs_b    = (const float*)d_in[17];
    const float* vc_w    = (const float*)d_in[18];
    const float* vc_b    = (const float*)d_in[19];
    const float* my_tok  = (const float*)d_in[20];
    const float* gate_av = (const float*)d_in[21];
    const float* gate    = (const float*)d_in[22];
    const float* down_w  = (const float*)d_in[23];
    const float* up_w    = (const float*)d_in[24];
    const float* bn1_g   = (const float*)d_in[25];
    const float* bn1_b   = (const float*)d_in[26];
    const float* bn2_g   = (const float*)d_in[27];
    const float* bn2_b   = (const float*)d_in[28];
    const float* lnb_g   = (const float*)d_in[29];
    const float* lnb_b   = (const float*)d_in[30];
    const float* lnp_g   = (const float*)d_in[31];
    const float* lnp_b   = (const float*)d_in[32];

    float* ws = (float*)d_ws;
    unsigned short* vtc_bf = (unsigned short*)(ws + OFF_A);
    float* vq1     = ws + OFF_A;
    float* cq      = ws + OFF_A;
    float* y2      = ws + OFF_A;
    float* vtf     = ws + OFF_B;
    float* out_tmp = ws + OFF_B;
    float* xT      = ws + OFF_XT;
    float* rep     = ws + OFF_REP;
    float* y1      = ws + OFF_Y1;
    unsigned short* wconv = (unsigned short*)(ws + OFF_WCONV);
    unsigned short* wfc   = (unsigned short*)(ws + OFF_WFC);
    unsigned short* wv1   = (unsigned short*)(ws + OFF_WV1);
    unsigned short* wv2   = (unsigned short*)(ws + OFF_WV2);
    unsigned short* wdown = (unsigned short*)(ws + OFF_WDOWN);
    unsigned short* wup   = (unsigned short*)(ws + OFF_WUP);
    float* audio   = ws + OFF_AUDIO;
    float* aq1b    = ws + OFF_AQ1;
    float* mvqb    = ws + OFF_MVQ;
    float* avqb    = ws + OFF_AVQ;
    float* chattb  = ws + OFF_CHATT;
    float* aq2b    = ws + OFF_AQ2;
    float* ssigb   = ws + OFF_SSIG;
    float* stats1  = ws + OFF_STATS;
    float* stats2  = ws + OFF_STATS + 2 * DDB;
    unsigned short* pbuf = (unsigned short*)(ws + OFF_PBUF);
    float* stbuf   = ws + OFF_STMP;
    unsigned short* xt_bf = (unsigned short*)(ws + OFF_XTBF);

    float* out   = (float*)d_out;
    float* spatt = out + (long long)BB * DD0 * NN;

    hipMemsetAsync(stats1, 0, (2 * DDB + 2 * DD0) * sizeof(float), stream);

    // 0. weight conversions (f32 -> bf16)
    cvt_f2bf<<<(DD0 * LIN / 4 + 255) / 256, 256, 0, stream>>>(fc_w, wfc, DD0 * LIN);
    cvt_f2bf<<<(DD0 * DD0 / 4 + 255) / 256, 256, 0, stream>>>(v1_w, wv1, DD0 * DD0);
    cvt_f2bf<<<(DM * DD0 / 4 + 255) / 256, 256, 0, stream>>>(v2_w, wv2, DM * DD0);
    cvt_f2bf<<<(DDB * DD0 / 4 + 255) / 256, 256, 0, stream>>>(down_w, wdown, DDB * DD0);
    cvt_f2bf<<<(DD0 * DDB / 4 + 255) / 256, 256, 0, stream>>>(up_w, wup, DD0 * DDB);
    cvt_f2bf_pad<<<(COUT * 200 + 255) / 256, 256, 0, stream>>>(conv_w, wconv, COUT, CIN, 200);

    // 1. x -> xT
    transpose_kernel<<<dim3(7, 24, BB), dim3(32, 8), 0, stream>>>(x, xT, DD0, NN);
    // 2. conv (MFMA reg-staged) -> vtc_bf
    gemm_mfma<1, true, false, false, 0, false><<<dim3(NCONV / 128, 2), 256, 0, stream>>>(
        wconv, 200, vis, CIN, conv_b, nullptr, vtc_bf, COUT, NCONV, CIN, 200);
    // 3. fc (global_load_lds GEMM) -> vtf f32
    gemm_gll<0><<<dim3(DD0 / 128, MFLAT / 128), 256, 0, stream>>>(
        vtc_bf, LIN, wfc, LIN, fc_b, vtf, DD0, LIN);
    // 4. audio
    audio_kernel<<<dim3(3, BB), 256, 0, stream>>>(vtf, audio);
    // 5. att1 (MFMA)
    att1_scores<<<BB, 256, 0, stream>>>(vtf, my_tok, pbuf);
    att1_pv<<<dim3(6, BB), 256, 0, stream>>>(vtf, pbuf, my_tok, rep);
    // 6. att2 (MFMA, fused)
    att2_mfma<<<dim3(4, BB), 256, 0, stream>>>(rep, gate_av, xT);
    // 6b. xT -> bf16 snapshot (pre-LN) for vq1's gload_lds path
    cvt_f2bf<<<(MFLAT * DD0 / 4 + 255) / 256, 256, 0, stream>>>(xT, xt_bf, MFLAT * DD0);
    // 7. aq1 = relu(audio@a1^T+b)
    wave_gemv<1><<<BB * DD0 / 4, 256, 0, stream>>>(audio, DD0, a1_w, DD0, a1_b, aq1b, DD0, DD0);
    // 8. vq1 (global_load_lds GEMM) relu
    gemm_gll<1><<<dim3(DD0 / 128, MFLAT / 128), 256, 0, stream>>>(
        xt_bf, DD0, wv1, DD0, v1_b, vq1, DD0, DD0);
    // 9. mvq
    mvq_kernel<<<dim3(3, BB), 256, 0, stream>>>(vq1, aq1b, mvqb);
    // 10. avq = relu(mvq@btl^T+b)
    wave_gemv<1><<<BB * DM / 4, 256, 0, stream>>>(mvqb, DD0, btl_w, DD0, btl_b, avqb, DM, DD0);
    // 11. ch_att = sigmoid(avq@vc^T+b)
    wave_gemv<2><<<BB * DD0 / 4, 256, 0, stream>>>(avqb, DM, vc_w, DM, vc_b, chattb, DD0, DM);
    // 12. aq2 = relu(audio@a2^T+b)
    wave_gemv<1><<<BB * DM / 4, 256, 0, stream>>>(audio, DD0, a2_w, DD0, a2_b, aq2b, DM, DD0);
    // 13. c_q (MFMA reg-staged) relu, k-scale
    gemm_mfma<0, false, true, true, 1, false><<<dim3(DM / 128, MFLAT / 128), 256, 0, stream>>>(
        xT, DD0, wv2, DD0, v2_b, chattb, cq, MFLAT, DM, DD0, DD0);
    // 14. s_tmp: dot (grid 49xB) + softmax (grid B)
    stmp_dot<<<dim3(49, BB), 256, 0, stream>>>(cq, aq2b, vs_w, vs_b, stbuf, ssigb);
    stmp_soft<<<BB, 256, 0, stream>>>(stbuf, spatt);
    // 15. scale + ln_before
    scale_ln_kernel<<<dim3(NN, BB), 256, 0, stream>>>(xT, chattb, ssigb, lnb_g, lnb_b);
    // 16. down (MFMA, N=96 guarded): y1 = xT@down^T
    gemm_mfma<0, false, true, false, 0, true><<<dim3(1, MFLAT / 128), 256, 0, stream>>>(
        xT, DD0, wdown, DD0, nullptr, nullptr, y1, MFLAT, DDB, DD0, DD0);
    // 17-18. BN1 (stats grid 4xB)
    bn1stats_kernel<<<dim3(4, BB), 128, 0, stream>>>(y1, stats1);
    bn1apply_kernel<<<(BB * NN * DDB + 255) / 256, 256, 0, stream>>>(y1, stats1, bn1_g, bn1_b);
    // 19. up (MFMA): y2 = z@up^T
    gemm_mfma<0, false, true, false, 0, false><<<dim3(DD0 / 128, MFLAT / 128), 256, 0, stream>>>(
        y1, DDB, wup, DDB, nullptr, nullptr, y2, MFLAT, DD0, DDB, DDB);
    // 20. BN2 stats
    bn2stats_kernel<<<dim3(3, BB), 256, 0, stream>>>(y2, stats2);
    // 21. BN2 + LN + gate
    final_kernel<<<dim3(NN, BB), 256, 0, stream>>>(y2, stats2, bn2_g, bn2_b,
                                                   lnp_g, lnp_b, gate, out_tmp);
    // 22. out_tmp -> out
    transpose_kernel<<<dim3(24, 7, BB), dim3(32, 8), 0, stream>>>(out_tmp, out, NN, DD0);
}

// Round 9
// 805.016 us; speedup vs baseline: 3.1229x; 1.0687x over previous
//
#include <hip/hip_runtime.h>
#include <math.h>

// ---- problem constants ----
#define BB 64
#define DD0 768
#define NN 196
#define LIN 1536
#define CIN 196
#define COUT 196
#define TT 32
#define DM 384
#define DDB 96
#define EPS 1e-5f
#define MFLAT (BB * NN)          // 12544
#define NCONV (BB * LIN)         // 98304

// ---- workspace layout (float offsets) ----
#define OFF_A     0LL            // vtc_bf16 -> vq1 f32 -> cq f32 -> y2 f32
#define OFF_B     9633792LL      // vtf f32 -> out_tmp f32
#define OFF_XT    19267584LL     // xT f32
#define OFF_REP   28901376LL     // rep f32
#define OFF_Y1    30474240LL     // y1 f32
#define OFF_WCONV 31678464LL     // 196x200 ushort padded
#define OFF_WFC   31698064LL     // 768x1536 ushort
#define OFF_WV1   32287888LL     // 768x768  ushort
#define OFF_WV2   32582800LL     // 384x768  ushort
#define OFF_SM    32730256LL
#define OFF_AUDIO (OFF_SM)
#define OFF_AQ1   (OFF_SM+49152)
#define OFF_MVQ   (OFF_SM+98304)
#define OFF_AVQ   (OFF_SM+147456)
#define OFF_CHATT (OFF_SM+172032)
#define OFF_AQ2   (OFF_SM+221184)
#define OFF_SSIG  (OFF_SM+245760)
#define OFF_STATS (OFF_SM+258304)
#define OFF_PBUF  (OFF_SM+262144)   // att1 P: 64*32*224 ushort = 229376 f
#define OFF_WDOWN (OFF_SM+491520)   // 96x768 ushort
#define OFF_WUP   (OFF_SM+528384)   // 768x96 ushort
#define OFF_STMP  (OFF_SM+565248)   // st_buf: 64*196 f
#define OFF_XTBF  (OFF_SM+577792)   // xT bf16: 12544*768 ushort = 4,816,896 f
#define OFF_REPBF (OFF_XTBF+4816896)  // rep bf16: 64*32*768 ushort = 786,432 f
#define OFF_P2    (OFF_REPBF+786432)  // att2 P: 64*196*32 ushort = 200,704 f
#define OFF_MTBF  (OFF_P2+200704)     // my_tokens bf16: 32*768 ushort = 12,288 f
#define OFF_SBUF  (OFF_MTBF+12288)    // att1 raw scores: 64*32*208 f = 425,984 f

typedef __attribute__((ext_vector_type(8))) short short8;
typedef __attribute__((ext_vector_type(4))) float f32x4;

__device__ __forceinline__ unsigned short f2bf(float f) {
    union { float f; unsigned u; } v; v.f = f;
    unsigned r = v.u + 0x7fffu + ((v.u >> 16) & 1u);
    return (unsigned short)(r >> 16);
}
__device__ __forceinline__ float bf2f(unsigned short u) {
    union { unsigned u; float f; } v; v.u = ((unsigned)u) << 16;
    return v.f;
}
__device__ __forceinline__ short8 cvt8(const float4 a, const float4 b) {
    short8 r;
    r[0] = (short)f2bf(a.x); r[1] = (short)f2bf(a.y); r[2] = (short)f2bf(a.z); r[3] = (short)f2bf(a.w);
    r[4] = (short)f2bf(b.x); r[5] = (short)f2bf(b.y); r[6] = (short)f2bf(b.z); r[7] = (short)f2bf(b.w);
    return r;
}
__device__ __forceinline__ short8 lds_frag(const unsigned short* p) {
    short4 lo = *(const short4*)p;
    short4 hi = *(const short4*)(p + 4);
    short8 r;
    r[0] = lo.x; r[1] = lo.y; r[2] = lo.z; r[3] = lo.w;
    r[4] = hi.x; r[5] = hi.y; r[6] = hi.z; r[7] = hi.w;
    return r;
}
// async global->LDS, 16B per lane
__device__ __forceinline__ void gload16(const void* g, void* l) {
    __builtin_amdgcn_global_load_lds(
        (const __attribute__((address_space(1))) unsigned int*)g,
        (__attribute__((address_space(3))) unsigned int*)l, 16, 0, 0);
}
// bijective XCD-chunk swizzle (m204)
__device__ __forceinline__ int xcd_swizzle(int orig, int nwg) {
    const int q = nwg >> 3, r = nwg & 7;
    const int x = orig & 7, lo = orig >> 3;
    return (x < r ? x * (q + 1) : r * (q + 1) + (x - r) * q) + lo;
}

// ---------------- reduction helpers ----------------
__device__ __forceinline__ float warp_sum(float v) {
    for (int o = 32; o; o >>= 1) v += __shfl_down(v, o, 64);
    return v;
}
__device__ __forceinline__ float wave_allsum(float v) {
    for (int o = 1; o < 64; o <<= 1) v += __shfl_xor(v, o, 64);
    return v;
}
__device__ __forceinline__ float wave_allmax(float v) {
    for (int o = 1; o < 64; o <<= 1) v = fmaxf(v, __shfl_xor(v, o, 64));
    return v;
}
__device__ __forceinline__ float warp_max(float v) {
    for (int o = 32; o; o >>= 1) v = fmaxf(v, __shfl_down(v, o, 64));
    return v;
}
__device__ __forceinline__ float block_sum256(float v, float* sb) {
    v = warp_sum(v);
    __syncthreads();
    if ((threadIdx.x & 63) == 0) sb[threadIdx.x >> 6] = v;
    __syncthreads();
    return sb[0] + sb[1] + sb[2] + sb[3];
}
__device__ __forceinline__ float block_max256(float v, float* sb) {
    v = warp_max(v);
    __syncthreads();
    if ((threadIdx.x & 63) == 0) sb[threadIdx.x >> 6] = v;
    __syncthreads();
    return fmaxf(fmaxf(sb[0], sb[1]), fmaxf(sb[2], sb[3]));
}

// ============== bf16 GEMM via global_load_lds (fc, vq1) ==============
template<int EPI>
__global__ __launch_bounds__(256)
void gemm_gll(const unsigned short* __restrict__ Ap, int lda,
              const unsigned short* __restrict__ Bp, int ldb,
              const float* __restrict__ bias,
              float* __restrict__ Cp, int N, int K)
{
    __shared__ unsigned short Asm[128 * 64];
    __shared__ unsigned short Bsm[128 * 64];
    const int nwg = gridDim.x * gridDim.y;
    const int wg = xcd_swizzle(blockIdx.y * gridDim.x + blockIdx.x, nwg);
    const int m0 = (wg / gridDim.x) * 128, n0 = (wg % gridDim.x) * 128;

    const int tid = threadIdx.x, w = tid >> 6, lane = tid & 63;
    const int wr = w >> 1, wc = w & 1;
    const int soff = ((lane & 7) << 4) ^ ((lane >> 3) << 4);
    const int arow = (lane >> 3);

    f32x4 acc[4][4];
    #pragma unroll
    for (int i = 0; i < 4; i++)
        #pragma unroll
        for (int j = 0; j < 4; j++) acc[i][j] = (f32x4){0.f, 0.f, 0.f, 0.f};

    for (int k0 = 0; k0 < K; k0 += 64) {
        #pragma unroll
        for (int q = 0; q < 4; q++) {
            const int c = w * 4 + q;
            const int row = c * 8 + arow;
            const char* g = (const char*)Ap + (((long long)(m0 + row) * lda + k0) << 1) + soff;
            gload16(g, (char*)Asm + c * 1024);
        }
        #pragma unroll
        for (int q = 0; q < 4; q++) {
            const int c = w * 4 + q;
            const int row = c * 8 + arow;
            const char* g = (const char*)Bp + (((long long)(n0 + row) * ldb + k0) << 1) + soff;
            gload16(g, (char*)Bsm + c * 1024);
        }
        __syncthreads();
        #pragma unroll
        for (int kk = 0; kk < 2; kk++) {
            const int kb = kk * 64 + ((lane >> 4) << 4);
            const int swz = (lane & 7) << 4;
            short8 af[4], bfr[4];
            #pragma unroll
            for (int i = 0; i < 4; i++) {
                const int ra = wr * 64 + i * 16 + (lane & 15);
                af[i] = *(const short8*)((const char*)Asm + ra * 128 + (kb ^ swz));
            }
            #pragma unroll
            for (int j = 0; j < 4; j++) {
                const int rb = wc * 64 + j * 16 + (lane & 15);
                bfr[j] = *(const short8*)((const char*)Bsm + rb * 128 + (kb ^ swz));
            }
            #pragma unroll
            for (int i = 0; i < 4; i++)
                #pragma unroll
                for (int j = 0; j < 4; j++)
                    acc[i][j] = __builtin_amdgcn_mfma_f32_16x16x32_bf16(af[i], bfr[j], acc[i][j], 0, 0, 0);
        }
        __syncthreads();
    }
    const int cmb = wr * 64 + ((lane >> 4) << 2);
    const int cnb = wc * 64 + (lane & 15);
    #pragma unroll
    for (int i = 0; i < 4; i++) {
        #pragma unroll
        for (int j = 0; j < 4; j++) {
            const int gn = n0 + cnb + j * 16;
            #pragma unroll
            for (int rr = 0; rr < 4; rr++) {
                const int gm = m0 + cmb + i * 16 + rr;
                float v = acc[i][j][rr] + bias[gn];
                if (EPI == 1) v = fmaxf(v, 0.f);
                Cp[(long long)gm * N + gn] = v;
            }
        }
    }
}

// ================= bf16 MFMA GEMM, reg-staging (conv/cq/down/up) =================
template<int MODE, bool ABF, bool BBF, bool KSC, int EPI, bool NG>
__global__ __launch_bounds__(256)
void gemm_mfma(const void* __restrict__ Ap, int lda,
               const void* __restrict__ Bp, int ldb,
               const float* __restrict__ bias, const float* __restrict__ ksc,
               void* __restrict__ Cp, int M, int N, int K, int Ka)
{
    __shared__ unsigned short Asm[128][72];
    __shared__ unsigned short Bsm[128][72];
    const int tid = threadIdx.x;
    const int nwg = gridDim.x * gridDim.y;
    const int wg = xcd_swizzle(blockIdx.y * gridDim.x + blockIdx.x, nwg);
    const int m0 = (wg / gridDim.x) * 128, n0 = (wg % gridDim.x) * 128;
    const int w = tid >> 6, lane = tid & 63;
    const int wr = w >> 1, wc = w & 1;

    f32x4 acc[4][4];
    #pragma unroll
    for (int i = 0; i < 4; i++)
        #pragma unroll
        for (int j = 0; j < 4; j++) acc[i][j] = (f32x4){0.f, 0.f, 0.f, 0.f};

    const int nkt = (K + 63) >> 6;
    for (int kt = 0; kt < nkt; kt++) {
        const int k0 = kt << 6;
        if (ABF) {
            #pragma unroll
            for (int q = 0; q < 4; q++) {
                const int row = q * 32 + (tid >> 3);
                const int ce = (tid & 7) * 8;
                const int gm = m0 + row;
                const bool rok = (MODE == 1) ? (gm < M) : true;
                uint4 u = make_uint4(0u, 0u, 0u, 0u);
                if (rok && (k0 + ce) < Ka)
                    u = *(const uint4*)((const unsigned short*)Ap + (long long)gm * lda + k0 + ce);
                *(uint4*)&Asm[row][ce] = u;
            }
        } else {
            #pragma unroll
            for (int q = 0; q < 8; q++) {
                const int row = q * 16 + (tid >> 4);
                const int ce = (tid & 15) * 4;
                const int gm = m0 + row;
                const bool rok = (MODE == 1) ? (gm < M) : true;
                float4 v = make_float4(0.f, 0.f, 0.f, 0.f);
                const bool kok = (k0 + ce) < K;
                if (rok && kok)
                    v = *(const float4*)((const float*)Ap + (long long)gm * lda + k0 + ce);
                if (KSC && kok) {
                    const float* kc = ksc + (gm / 196) * 768 + k0 + ce;
                    v.x *= kc[0] + 1.f; v.y *= kc[1] + 1.f;
                    v.z *= kc[2] + 1.f; v.w *= kc[3] + 1.f;
                }
                ushort4 o; o.x = f2bf(v.x); o.y = f2bf(v.y); o.z = f2bf(v.z); o.w = f2bf(v.w);
                *(ushort4*)&Asm[row][ce] = o;
            }
        }
        if (BBF) {
            #pragma unroll
            for (int q = 0; q < 4; q++) {
                const int row = q * 32 + (tid >> 3);
                const int ce = (tid & 7) * 8;
                const int gn = n0 + row;
                const bool nok = NG ? (gn < N) : true;
                uint4 u = make_uint4(0u, 0u, 0u, 0u);
                if (nok && (k0 + ce) < K)
                    u = *(const uint4*)((const unsigned short*)Bp + (long long)gn * ldb + k0 + ce);
                *(uint4*)&Bsm[row][ce] = u;
            }
        } else {
            #pragma unroll
            for (int q = 0; q < 8; q++) {
                const int row = q * 16 + (tid >> 4);
                const int ce = (tid & 15) * 4;
                const int gn = n0 + row;
                const bool nok = NG ? (gn < N) : true;
                float4 v = make_float4(0.f, 0.f, 0.f, 0.f);
                if (nok && (k0 + ce) < K)
                    v = *(const float4*)((const float*)Bp + (long long)gn * ldb + k0 + ce);
                ushort4 o; o.x = f2bf(v.x); o.y = f2bf(v.y); o.z = f2bf(v.z); o.w = f2bf(v.w);
                *(ushort4*)&Bsm[row][ce] = o;
            }
        }
        __syncthreads();
        #pragma unroll
        for (int kk = 0; kk < 2; kk++) {
            short8 af[4], bfr[4];
            const int koff = kk * 32 + (lane >> 4) * 8;
            #pragma unroll
            for (int i = 0; i < 4; i++)
                af[i] = *(const short8*)&Asm[wr * 64 + i * 16 + (lane & 15)][koff];
            #pragma unroll
            for (int j = 0; j < 4; j++)
                bfr[j] = *(const short8*)&Bsm[wc * 64 + j * 16 + (lane & 15)][koff];
            #pragma unroll
            for (int i = 0; i < 4; i++)
                #pragma unroll
                for (int j = 0; j < 4; j++)
                    acc[i][j] = __builtin_amdgcn_mfma_f32_16x16x32_bf16(af[i], bfr[j], acc[i][j], 0, 0, 0);
        }
        __syncthreads();
    }
    const int cmb = wr * 64 + ((lane >> 4) << 2);
    const int cnb = wc * 64 + (lane & 15);
    #pragma unroll
    for (int i = 0; i < 4; i++) {
        #pragma unroll
        for (int j = 0; j < 4; j++) {
            const int gn = n0 + cnb + j * 16;
            if (NG && gn >= N) continue;
            #pragma unroll
            for (int rr = 0; rr < 4; rr++) {
                const int gm = m0 + cmb + i * 16 + rr;
                float v = acc[i][j][rr];
                if (MODE == 0) {
                    if (bias) v += bias[gn];
                    if (EPI == 1) v = fmaxf(v, 0.f);
                    ((float*)Cp)[(long long)gm * N + gn] = v;
                } else {
                    if (gm < M) {
                        v += bias[gm];
                        const int b = gn / LIN, l = gn - b * LIN;
                        ((unsigned short*)Cp)[((long long)b * COUT + gm) * LIN + l] = f2bf(v);
                    }
                }
            }
        }
    }
}

// ---------------- weight f32 -> bf16 converters ----------------
__global__ void cvt_f2bf(const float* __restrict__ in, unsigned short* __restrict__ out, int n)
{
    int i = (blockIdx.x * 256 + threadIdx.x) * 4;
    if (i + 4 <= n) {
        float4 v = *(const float4*)(in + i);
        ushort4 o; o.x = f2bf(v.x); o.y = f2bf(v.y); o.z = f2bf(v.z); o.w = f2bf(v.w);
        *(ushort4*)(out + i) = o;
    }
}
__global__ void cvt_f2bf_pad(const float* __restrict__ in, unsigned short* __restrict__ out,
                             int rows, int cols, int ldo)
{
    int i = blockIdx.x * 256 + threadIdx.x;
    if (i < rows * ldo) {
        int r = i / ldo, c = i - r * ldo;
        out[i] = (c < cols) ? f2bf(in[r * cols + c]) : (unsigned short)0;
    }
}

// ---------------- wave-per-output GEMV ----------------
template<int ACT>
__global__ __launch_bounds__(256)
void wave_gemv(const float* __restrict__ A, int lda,
               const float* __restrict__ B, int ldb,
               const float* __restrict__ bias,
               float* __restrict__ C, int N, int K)
{
    const int w = threadIdx.x >> 6, lane = threadIdx.x & 63;
    const long long o = (long long)blockIdx.x * 4 + w;
    const int m = (int)(o / N), n = (int)(o - (long long)m * N);
    const float* ar = A + (long long)m * lda;
    const float* br = B + (long long)n * ldb;
    float s = 0.f;
    for (int k = lane; k < K; k += 64) s += ar[k] * br[k];
    s = wave_allsum(s);
    if (lane == 0) {
        float v = s + bias[n];
        if (ACT == 1) v = fmaxf(v, 0.f);
        if (ACT == 2) v = 1.f / (1.f + expf(-v));
        C[o] = v;
    }
}

// ---------------- transpose ----------------
__global__ void transpose_kernel(const float* __restrict__ in, float* __restrict__ out,
                                 int D, int N)
{
    __shared__ float tile[32][33];
    int b = blockIdx.z;
    int d0 = blockIdx.y * 32, n0 = blockIdx.x * 32;
    int tx = threadIdx.x, ty = threadIdx.y;
    for (int i = 0; i < 32; i += 8) {
        int d = d0 + ty + i, n = n0 + tx;
        if (d < D && n < N) tile[ty + i][tx] = in[((long long)b * D + d) * N + n];
    }
    __syncthreads();
    for (int i = 0; i < 32; i += 8) {
        int n = n0 + ty + i, d = d0 + tx;
        if (n < N && d < D) out[((long long)b * N + n) * D + d] = tile[tx][ty + i];
    }
}

// ---------------- audio ----------------
__global__ void audio_kernel(const float* __restrict__ vtf, float* __restrict__ audio)
{
    int b = blockIdx.y, d = blockIdx.x * 256 + threadIdx.x;
    float s = 0.f;
    for (int m = 0; m < COUT; m++) s += vtf[((long long)b * COUT + m) * DD0 + d];
    audio[b * DD0 + d] = s * (1.f / (float)COUT);
}

// ========== att1 QK^T raw scores: sbuf[b][t][208] = mt[t]·vtf[b][m] ==========
__global__ __launch_bounds__(256)
void att1_qk(const float* __restrict__ vtf, const unsigned short* __restrict__ mtbf,
             float* __restrict__ sbuf)
{
    const int b = blockIdx.y, m0 = blockIdx.x * 64;
    const int tid = threadIdx.x, w = tid >> 6, lane = tid & 63;
    const int l15 = lane & 15, kg = (lane >> 4) << 3;
    const int gm = m0 + w * 16 + l15;
    const bool mok = gm < COUT;
    const float* br = vtf + ((long long)b * COUT + gm) * DD0;
    f32x4 c0 = (f32x4){0.f,0.f,0.f,0.f}, c1 = (f32x4){0.f,0.f,0.f,0.f};
    for (int kt = 0; kt < DD0; kt += 32) {
        const short8 a0 = *(const short8*)(mtbf + (long long)l15 * DD0 + kt + kg);
        const short8 a1 = *(const short8*)(mtbf + (long long)(16 + l15) * DD0 + kt + kg);
        short8 bf = {0,0,0,0,0,0,0,0};
        if (mok) bf = cvt8(*(const float4*)(br + kt + kg), *(const float4*)(br + kt + kg + 4));
        c0 = __builtin_amdgcn_mfma_f32_16x16x32_bf16(a0, bf, c0, 0, 0, 0);
        c1 = __builtin_amdgcn_mfma_f32_16x16x32_bf16(a1, bf, c1, 0, 0, 0);
    }
    if (mok) {
        #pragma unroll
        for (int r = 0; r < 4; r++) {
            const int t0 = ((lane >> 4) << 2) + r;
            sbuf[((long long)b * TT + t0) * 208 + gm] = c0[r];
            sbuf[((long long)b * TT + 16 + t0) * 208 + gm] = c1[r];
        }
    }
}

// ========== att1 softmax: pbuf[b][t][224] bf16 = softmax_m(sbuf[b][t]) ==========
__global__ __launch_bounds__(256)
void att1_soft(const float* __restrict__ sbuf, unsigned short* __restrict__ pbuf)
{
    const int b = blockIdx.y, w = threadIdx.x >> 6, lane = threadIdx.x & 63;
    const int t = blockIdx.x * 4 + w;   // gridDim.x = 8 -> 32 t
    const float* sr = sbuf + ((long long)b * TT + t) * 208;
    float x[4];
    #pragma unroll
    for (int i = 0; i < 4; i++) {
        const int m = lane + 64 * i;
        x[i] = (m < COUT) ? sr[m] : -1e30f;
    }
    float mx = fmaxf(fmaxf(x[0], x[1]), fmaxf(x[2], x[3]));
    mx = wave_allmax(mx);
    float e[4], s = 0.f;
    #pragma unroll
    for (int i = 0; i < 4; i++) {
        const int m = lane + 64 * i;
        e[i] = (m < COUT) ? __expf(x[i] - mx) : 0.f;
        s += e[i];
    }
    s = wave_allsum(s);
    const float inv = 1.f / s;
    unsigned short* pr = pbuf + ((long long)b * TT + t) * 224;
    #pragma unroll
    for (int i = 0; i < 4; i++) {
        const int m = lane + 64 * i;
        if (m < 224) pr[m] = (m < COUT) ? f2bf(e[i] * inv) : (unsigned short)0;
    }
}

// ========== att1 PV: rep[b][t][d] = mt[t][d] + sum_m P[t][m]·vtf[b][m][d] ======
__global__ __launch_bounds__(256)
void att1_pv(const float* __restrict__ vtf, const unsigned short* __restrict__ pbuf,
             const float* __restrict__ mt, float* __restrict__ rep)
{
    __shared__ unsigned short vT[128][36];
    const int b = blockIdx.y, d0 = blockIdx.x * 128;
    const int tid = threadIdx.x, w = tid >> 6, lane = tid & 63;
    const int l15 = lane & 15, kg = (lane >> 4) << 3;
    const float* vb = vtf + (long long)b * COUT * DD0;

    f32x4 acc[2][2];
    acc[0][0] = (f32x4){0.f,0.f,0.f,0.f}; acc[0][1] = (f32x4){0.f,0.f,0.f,0.f};
    acc[1][0] = (f32x4){0.f,0.f,0.f,0.f}; acc[1][1] = (f32x4){0.f,0.f,0.f,0.f};

    for (int kc = 0; kc < 7; kc++) {
        for (int i = tid; i < 32 * 128; i += 256) {
            const int m = i >> 7, dd = i & 127;
            const int gm = kc * 32 + m;
            const float v = (gm < COUT) ? vb[(long long)gm * DD0 + d0 + dd] : 0.f;
            vT[dd][m] = f2bf(v);
        }
        const short8 p0 = *(const short8*)(pbuf + ((long long)b * TT + l15) * 224 + kc * 32 + kg);
        const short8 p1 = *(const short8*)(pbuf + ((long long)b * TT + 16 + l15) * 224 + kc * 32 + kg);
        __syncthreads();
        #pragma unroll
        for (int jl = 0; jl < 2; jl++) {
            const short8 bf = lds_frag(&vT[(w * 2 + jl) * 16 + l15][kg]);
            acc[0][jl] = __builtin_amdgcn_mfma_f32_16x16x32_bf16(p0, bf, acc[0][jl], 0, 0, 0);
            acc[1][jl] = __builtin_amdgcn_mfma_f32_16x16x32_bf16(p1, bf, acc[1][jl], 0, 0, 0);
        }
        __syncthreads();
    }
    #pragma unroll
    for (int j = 0; j < 2; j++) {
        #pragma unroll
        for (int jl = 0; jl < 2; jl++) {
            const int t = j * 16 + ((lane >> 4) << 2);
            const int gd = d0 + (w * 2 + jl) * 16 + l15;
            #pragma unroll
            for (int r = 0; r < 4; r++)
                rep[((long long)b * TT + t + r) * DD0 + gd] = mt[(long long)(t + r) * DD0 + gd] + acc[j][jl][r];
        }
    }
}

// ========== att2 scores: p2[b][n][32] bf16 = softmax_t(xT[b][n]·rep[b][t]) ======
__global__ __launch_bounds__(256)
void att2_scores(const float* __restrict__ xT, const unsigned short* __restrict__ repbf,
                 unsigned short* __restrict__ p2)
{
    const int b = blockIdx.y, m0 = blockIdx.x * 64;
    const int tid = threadIdx.x, w = tid >> 6, lane = tid & 63;
    const int l15 = lane & 15, kg = (lane >> 4) << 3;
    const int arow = m0 + w * 16 + l15;
    const bool rok = arow < NN;
    const float* xrow = xT + ((long long)b * NN + arow) * DD0;
    const unsigned short* rb = repbf + (long long)b * TT * DD0;

    f32x4 acc0 = (f32x4){0.f,0.f,0.f,0.f}, acc1 = (f32x4){0.f,0.f,0.f,0.f};
    for (int kt = 0; kt < DD0; kt += 32) {
        short8 af = {0,0,0,0,0,0,0,0};
        if (rok) af = cvt8(*(const float4*)(xrow + kt + kg), *(const float4*)(xrow + kt + kg + 4));
        const short8 b0 = *(const short8*)(rb + (long long)l15 * DD0 + kt + kg);
        const short8 b1 = *(const short8*)(rb + (long long)(16 + l15) * DD0 + kt + kg);
        acc0 = __builtin_amdgcn_mfma_f32_16x16x32_bf16(af, b0, acc0, 0, 0, 0);
        acc1 = __builtin_amdgcn_mfma_f32_16x16x32_bf16(af, b1, acc1, 0, 0, 0);
    }
    #pragma unroll
    for (int r = 0; r < 4; r++) {
        float m = fmaxf(acc0[r], acc1[r]);
        m = fmaxf(m, __shfl_xor(m, 1, 64));
        m = fmaxf(m, __shfl_xor(m, 2, 64));
        m = fmaxf(m, __shfl_xor(m, 4, 64));
        m = fmaxf(m, __shfl_xor(m, 8, 64));
        const float e0 = __expf(acc0[r] - m), e1 = __expf(acc1[r] - m);
        float s = e0 + e1;
        s += __shfl_xor(s, 1, 64); s += __shfl_xor(s, 2, 64);
        s += __shfl_xor(s, 4, 64); s += __shfl_xor(s, 8, 64);
        const float inv = 1.f / s;
        const int prow = m0 + w * 16 + ((lane >> 4) << 2) + r;
        if (prow < NN) {
            unsigned short* pp = p2 + ((long long)b * NN + prow) * TT;
            pp[l15] = f2bf(e0 * inv);
            pp[l15 + 16] = f2bf(e1 * inv);
        }
    }
}

// ========== att2 PV (VALU, K=32): xT[b][n][d] += ga*sum_t P[n][t]·rep[t][d] ====
__global__ __launch_bounds__(256)
void att2_pv(const unsigned short* __restrict__ p2, const float* __restrict__ rep,
             const float* __restrict__ gav, float* __restrict__ xT)
{
    __shared__ float reps[TT][128];
    __shared__ float ps[64][33];
    const int b = blockIdx.z, n0 = blockIdx.y * 64, d0 = blockIdx.x * 128;
    const int tid = threadIdx.x;
    for (int i = tid; i < TT * 128; i += 256) {
        const int t = i >> 7, d = i & 127;
        reps[t][d] = rep[((long long)b * TT + t) * DD0 + d0 + d];
    }
    for (int i = tid; i < 64 * TT; i += 256) {
        const int n = i >> 5, t = i & 31;
        const int gn = n0 + n;
        ps[n][t] = (gn < NN) ? bf2f(p2[((long long)b * NN + gn) * TT + t]) : 0.f;
    }
    __syncthreads();
    const float ga = gav[0];
    const int d = tid & 127, nh = tid >> 7;
    #pragma unroll 4
    for (int i = 0; i < 32; i++) {
        const int nl = nh * 32 + i;
        const int gn = n0 + nl;
        if (gn >= NN) continue;
        float s = 0.f;
        #pragma unroll
        for (int t = 0; t < TT; t++) s += ps[nl][t] * reps[t][d];
        xT[((long long)b * NN + gn) * DD0 + d0 + d] += ga * s;
    }
}

// ---------------- mvq ----------------
__global__ void mvq_kernel(const float* __restrict__ vq1, const float* __restrict__ aq1,
                           float* __restrict__ mvq)
{
    int b = blockIdx.y, d = blockIdx.x * 256 + threadIdx.x;
    float s = 0.f;
    for (int n = 0; n < NN; n++) s += vq1[((long long)b * NN + n) * DD0 + d];
    mvq[b * DD0 + d] = aq1[b * DD0 + d] * s * (1.f / (float)NN);
}

// ---------------- stmp_dot / stmp_soft ----------------
__global__ __launch_bounds__(256)
void stmp_dot(const float* __restrict__ cq, const float* __restrict__ aq2,
              const float* __restrict__ vsw, const float* __restrict__ vsb,
              float* __restrict__ stb, float* __restrict__ ssig)
{
    const int b = blockIdx.y, tid = threadIdx.x, w = tid >> 6, lane = tid & 63;
    __shared__ float wv[DM];
    for (int i = tid; i < DM; i += 256) wv[i] = aq2[b * DM + i] * vsw[i];
    __syncthreads();
    const int n = blockIdx.x * 4 + w;
    const float* cr = cq + ((long long)b * NN + n) * DM;
    float s = 0.f;
    for (int d = lane; d < DM; d += 64) s += cr[d] * wv[d];
    s = wave_allsum(s);
    if (lane == 0) {
        const float sv = s + vsb[0];
        stb[b * NN + n] = tanhf(sv);
        ssig[b * NN + n] = 1.f / (1.f + expf(-sv));
    }
}

__global__ __launch_bounds__(256)
void stmp_soft(const float* __restrict__ stb, float* __restrict__ spatt)
{
    const int b = blockIdx.x, tid = threadIdx.x;
    __shared__ float sb[4];
    float v = (tid < NN) ? stb[b * NN + tid] : -1e30f;
    float mx = block_max256(v, sb);
    __syncthreads();
    float e = (tid < NN) ? __expf(v - mx) : 0.f;
    float s = block_sum256(e, sb);
    if (tid < NN) spatt[b * NN + tid] = e / s;
}

// ---------------- gating scale + LayerNorm (lnb) ----------------
__global__ __launch_bounds__(256)
void scale_ln_kernel(float* __restrict__ xT, const float* __restrict__ chatt,
                     const float* __restrict__ ssig, const float* __restrict__ g,
                     const float* __restrict__ bb)
{
    int b = blockIdx.y, n = blockIdx.x, tid = threadIdx.x;
    __shared__ float sb[4];
    float* xr = xT + ((long long)b * NN + n) * DD0;
    float ss = ssig[b * NN + n];
    float v[3];
    float lsum = 0.f;
    #pragma unroll
    for (int i = 0; i < 3; i++) {
        int d = tid + i * 256;
        float sc = 0.3f * chatt[b * DD0 + d] + 0.05f * ss + 0.7f;
        v[i] = xr[d] * sc;
        lsum += v[i];
    }
    float mean = block_sum256(lsum, sb) * (1.f / (float)DD0);
    float lvar = 0.f;
    #pragma unroll
    for (int i = 0; i < 3; i++) { float dd = v[i] - mean; lvar += dd * dd; }
    float var = block_sum256(lvar, sb) * (1.f / (float)DD0);
    float inv = rsqrtf(var + EPS);
    #pragma unroll
    for (int i = 0; i < 3; i++) {
        int d = tid + i * 256;
        xr[d] = (v[i] - mean) * inv * g[d] + bb[d];
    }
}

// ---------------- BN stats ----------------
__global__ void bn1stats_kernel(const float* __restrict__ y1, float* __restrict__ stats)
{
    int b = blockIdx.y, n0 = blockIdx.x * 49, tid = threadIdx.x;
    if (tid < DDB) {
        float s = 0.f, q = 0.f;
        for (int n = n0; n < n0 + 49; n++) {
            float v = y1[((long long)b * NN + n) * DDB + tid];
            s += v; q += v * v;
        }
        atomicAdd(&stats[tid], s);
        atomicAdd(&stats[DDB + tid], q);
    }
}

__global__ void bn1apply_kernel(float* __restrict__ y1, const float* __restrict__ stats,
                                const float* __restrict__ g, const float* __restrict__ bb)
{
    long long i = (long long)blockIdx.x * 256 + threadIdx.x;
    if (i >= (long long)BB * NN * DDB) return;
    int e = (int)(i % DDB);
    const float cnt = (float)(BB * NN);
    float mu = stats[e] / cnt;
    float var = stats[DDB + e] / cnt - mu * mu;
    float v = (y1[i] - mu) * rsqrtf(var + EPS) * g[e] + bb[e];
    y1[i] = fmaxf(v, 0.f);
}

__global__ void bn2stats_kernel(const float* __restrict__ y2, float* __restrict__ stats)
{
    int b = blockIdx.y, d = blockIdx.x * 256 + threadIdx.x;
    float s = 0.f, q = 0.f;
    for (int n = 0; n < NN; n++) {
        float v = y2[((long long)b * NN + n) * DD0 + d];
        s += v; q += v * v;
    }
    atomicAdd(&stats[d], s);
    atomicAdd(&stats[DD0 + d], q);
}

// ---------------- BN2 + LN(lnp) + gate ----------------
__global__ __launch_bounds__(256)
void final_kernel(const float* __restrict__ y2, const float* __restrict__ stats2,
                  const float* __restrict__ g2, const float* __restrict__ b2,
                  const float* __restrict__ lg, const float* __restrict__ lb,
                  const float* __restrict__ gate, float* __restrict__ out_tmp)
{
    int b = blockIdx.y, n = blockIdx.x, tid = threadIdx.x;
    __shared__ float sb[4];
    const float* yr = y2 + ((long long)b * NN + n) * DD0;
    const float cnt = (float)(BB * NN);
    float v[3];
    float lsum = 0.f;
    #pragma unroll
    for (int i = 0; i < 3; i++) {
        int d = tid + i * 256;
        float mu = stats2[d] / cnt;
        float var = stats2[DD0 + d] / cnt - mu * mu;
        v[i] = (yr[d] - mu) * rsqrtf(var + EPS) * g2[d] + b2[d];
        lsum += v[i];
    }
    float mean = block_sum256(lsum, sb) * (1.f / (float)DD0);
    float lvar = 0.f;
    #pragma unroll
    for (int i = 0; i < 3; i++) { float dd = v[i] - mean; lvar += dd * dd; }
    float var = block_sum256(lvar, sb) * (1.f / (float)DD0);
    float inv = rsqrtf(var + EPS);
    float gt = gate[0];
    float* orow = out_tmp + ((long long)b * NN + n) * DD0;
    #pragma unroll
    for (int i = 0; i < 3; i++) {
        int d = tid + i * 256;
        orow[d] = ((v[i] - mean) * inv * lg[d] + lb[d]) * gt;
    }
}

// ======================= launch =======================
extern "C" void kernel_launch(void* const* d_in, const int* in_sizes, int n_in,
                              void* d_out, int out_size, void* d_ws, size_t ws_size,
                              hipStream_t stream)
{
    const float* x       = (const float*)d_in[0];
    const float* vis     = (const float*)d_in[1];
    const float* conv_w  = (const float*)d_in[2];
    const float* conv_b  = (const float*)d_in[3];
    const float* fc_w    = (const float*)d_in[4];
    const float* fc_b    = (const float*)d_in[5];
    const float* a1_w    = (const float*)d_in[6];
    const float* a1_b    = (const float*)d_in[7];
    const float* v1_w    = (const float*)d_in[8];
    const float* v1_b    = (const float*)d_in[9];
    const float* btl_w   = (const float*)d_in[10];
    const float* btl_b   = (const float*)d_in[11];
    const float* v2_w    = (const float*)d_in[12];
    const float* v2_b    = (const float*)d_in[13];
    const float* a2_w    = (const float*)d_in[14];
    const float* a2_b    = (const float*)d_in[15];
    const float* vs_w    = (const float*)d_in[16];
    const float* vs_b    = (const float*)d_in[17];
    const float* vc_w    = (const float*)d_in[18];
    const float* vc_b    = (const float*)d_in[19];
    const float* my_tok  = (const float*)d_in[20];
    const float* gate_av = (const float*)d_in[21];
    const float* gate    = (const float*)d_in[22];
    const float* down_w  = (const float*)d_in[23];
    const float* up_w    = (const float*)d_in[24];
    const float* bn1_g   = (const float*)d_in[25];
    const float* bn1_b   = (const float*)d_in[26];
    const float* bn2_g   = (const float*)d_in[27];
    const float* bn2_b   = (const float*)d_in[28];
    const float* lnb_g   = (const float*)d_in[29];
    const float* lnb_b   = (const float*)d_in[30];
    const float* lnp_g   = (const float*)d_in[31];
    const float* lnp_b   = (const float*)d_in[32];

    float* ws = (float*)d_ws;
    unsigned short* vtc_bf = (unsigned short*)(ws + OFF_A);
    float* vq1     = ws + OFF_A;
    float* cq      = ws + OFF_A;
    float* y2      = ws + OFF_A;
    float* vtf     = ws + OFF_B;
    float* out_tmp = ws + OFF_B;
    float* xT      = ws + OFF_XT;
    float* rep     = ws + OFF_REP;
    float* y1      = ws + OFF_Y1;
    unsigned short* wconv = (unsigned short*)(ws + OFF_WCONV);
    unsigned short* wfc   = (unsigned short*)(ws + OFF_WFC);
    unsigned short* wv1   = (unsigned short*)(ws + OFF_WV1);
    unsigned short* wv2   = (unsigned short*)(ws + OFF_WV2);
    unsigned short* wdown = (unsigned short*)(ws + OFF_WDOWN);
    unsigned short* wup   = (unsigned short*)(ws + OFF_WUP);
    float* audio   = ws + OFF_AUDIO;
    float* aq1b    = ws + OFF_AQ1;
    float* mvqb    = ws + OFF_MVQ;
    float* avqb    = ws + OFF_AVQ;
    float* chattb  = ws + OFF_CHATT;
    float* aq2b    = ws + OFF_AQ2;
    float* ssigb   = ws + OFF_SSIG;
    float* stats1  = ws + OFF_STATS;
    float* stats2  = ws + OFF_STATS + 2 * DDB;
    unsigned short* pbuf  = (unsigned short*)(ws + OFF_PBUF);
    float* stbuf   = ws + OFF_STMP;
    unsigned short* xt_bf = (unsigned short*)(ws + OFF_XTBF);
    unsigned short* repbf = (unsigned short*)(ws + OFF_REPBF);
    unsigned short* p2    = (unsigned short*)(ws + OFF_P2);
    unsigned short* mtbf  = (unsigned short*)(ws + OFF_MTBF);
    float* sbuf    = ws + OFF_SBUF;

    float* out   = (float*)d_out;
    float* spatt = out + (long long)BB * DD0 * NN;

    hipMemsetAsync(stats1, 0, (2 * DDB + 2 * DD0) * sizeof(float), stream);

    // 0. weight conversions (f32 -> bf16)
    cvt_f2bf<<<(DD0 * LIN / 4 + 255) / 256, 256, 0, stream>>>(fc_w, wfc, DD0 * LIN);
    cvt_f2bf<<<(DD0 * DD0 / 4 + 255) / 256, 256, 0, stream>>>(v1_w, wv1, DD0 * DD0);
    cvt_f2bf<<<(DM * DD0 / 4 + 255) / 256, 256, 0, stream>>>(v2_w, wv2, DM * DD0);
    cvt_f2bf<<<(DDB * DD0 / 4 + 255) / 256, 256, 0, stream>>>(down_w, wdown, DDB * DD0);
    cvt_f2bf<<<(DD0 * DDB / 4 + 255) / 256, 256, 0, stream>>>(up_w, wup, DD0 * DDB);
    cvt_f2bf<<<(TT * DD0 / 4 + 255) / 256, 256, 0, stream>>>(my_tok, mtbf, TT * DD0);
    cvt_f2bf_pad<<<(COUT * 200 + 255) / 256, 256, 0, stream>>>(conv_w, wconv, COUT, CIN, 200);

    // 1. x -> xT
    transpose_kernel<<<dim3(7, 24, BB), dim3(32, 8), 0, stream>>>(x, xT, DD0, NN);
    // 2. conv (MFMA reg-staged) -> vtc_bf
    gemm_mfma<1, true, false, false, 0, false><<<dim3(NCONV / 128, 2), 256, 0, stream>>>(
        wconv, 200, vis, CIN, conv_b, nullptr, vtc_bf, COUT, NCONV, CIN, 200);
    // 3. fc (global_load_lds GEMM) -> vtf f32
    gemm_gll<0><<<dim3(DD0 / 128, MFLAT / 128), 256, 0, stream>>>(
        vtc_bf, LIN, wfc, LIN, fc_b, vtf, DD0, LIN);
    // 4. audio
    audio_kernel<<<dim3(3, BB), 256, 0, stream>>>(vtf, audio);
    // 5. att1: qk (raw S) -> softmax -> pv
    att1_qk<<<dim3(4, BB), 256, 0, stream>>>(vtf, mtbf, sbuf);
    att1_soft<<<dim3(8, BB), 256, 0, stream>>>(sbuf, pbuf);
    att1_pv<<<dim3(6, BB), 256, 0, stream>>>(vtf, pbuf, my_tok, rep);
    // 6. att2: rep->bf16, scores -> P, PV (VALU)
    cvt_f2bf<<<(BB * TT * DD0 / 4 + 255) / 256, 256, 0, stream>>>(rep, repbf, BB * TT * DD0);
    att2_scores<<<dim3(4, BB), 256, 0, stream>>>(xT, repbf, p2);
    att2_pv<<<dim3(6, 4, BB), 256, 0, stream>>>(p2, rep, gate_av, xT);
    // 6b. xT -> bf16 snapshot for vq1
    cvt_f2bf<<<(MFLAT * DD0 / 4 + 255) / 256, 256, 0, stream>>>(xT, xt_bf, MFLAT * DD0);
    // 7. aq1
    wave_gemv<1><<<BB * DD0 / 4, 256, 0, stream>>>(audio, DD0, a1_w, DD0, a1_b, aq1b, DD0, DD0);
    // 8. vq1 (global_load_lds GEMM) relu
    gemm_gll<1><<<dim3(DD0 / 128, MFLAT / 128), 256, 0, stream>>>(
        xt_bf, DD0, wv1, DD0, v1_b, vq1, DD0, DD0);
    // 9. mvq
    mvq_kernel<<<dim3(3, BB), 256, 0, stream>>>(vq1, aq1b, mvqb);
    // 10. avq
    wave_gemv<1><<<BB * DM / 4, 256, 0, stream>>>(mvqb, DD0, btl_w, DD0, btl_b, avqb, DM, DD0);
    // 11. ch_att
    wave_gemv<2><<<BB * DD0 / 4, 256, 0, stream>>>(avqb, DM, vc_w, DM, vc_b, chattb, DD0, DM);
    // 12. aq2
    wave_gemv<1><<<BB * DM / 4, 256, 0, stream>>>(audio, DD0, a2_w, DD0, a2_b, aq2b, DM, DD0);
    // 13. c_q (MFMA reg-staged) relu, k-scale
    gemm_mfma<0, false, true, true, 1, false><<<dim3(DM / 128, MFLAT / 128), 256, 0, stream>>>(
        xT, DD0, wv2, DD0, v2_b, chattb, cq, MFLAT, DM, DD0, DD0);
    // 14. s_tmp
    stmp_dot<<<dim3(49, BB), 256, 0, stream>>>(cq, aq2b, vs_w, vs_b, stbuf, ssigb);
    stmp_soft<<<BB, 256, 0, stream>>>(stbuf, spatt);
    // 15. scale + ln_before
    scale_ln_kernel<<<dim3(NN, BB), 256, 0, stream>>>(xT, chattb, ssigb, lnb_g, lnb_b);
    // 16. down (MFMA, N=96 guarded)
    gemm_mfma<0, false, true, false, 0, true><<<dim3(1, MFLAT / 128), 256, 0, stream>>>(
        xT, DD0, wdown, DD0, nullptr, nullptr, y1, MFLAT, DDB, DD0, DD0);
    // 17-18. BN1
    bn1stats_kernel<<<dim3(4, BB), 128, 0, stream>>>(y1, stats1);
    bn1apply_kernel<<<(BB * NN * DDB + 255) / 256, 256, 0, stream>>>(y1, stats1, bn1_g, bn1_b);
    // 19. up (MFMA)
    gemm_mfma<0, false, true, false, 0, false><<<dim3(DD0 / 128, MFLAT / 128), 256, 0, stream>>>(
        y1, DDB, wup, DDB, nullptr, nullptr, y2, MFLAT, DD0, DDB, DDB);
    // 20. BN2 stats
    bn2stats_kernel<<<dim3(3, BB), 256, 0, stream>>>(y2, stats2);
    // 21. BN2 + LN + gate
    final_kernel<<<dim3(NN, BB), 256, 0, stream>>>(y2, stats2, bn2_g, bn2_b,
                                                   lnp_g, lnp_b, gate, out_tmp);
    // 22. out_tmp -> out
    transpose_kernel<<<dim3(24, 7, BB), dim3(32, 8), 0, stream>>>(out_tmp, out, NN, DD0);
}